// Round 10
// baseline (296.493 us; speedup 1.0000x reference)
//
#include <hip/hip_runtime.h>
#include <hip/hip_bf16.h>

typedef __hip_bfloat16 bf16;
using f4 = __attribute__((ext_vector_type(4))) float;
using s8 = __attribute__((ext_vector_type(8))) short;
using s4 = __attribute__((ext_vector_type(4))) short;

__device__ __forceinline__ void storeOut(float* p, float v) { *p = v; }
__device__ __forceinline__ void storeOut(bf16* p, float v) { *p = __float2bfloat16(v); }
__device__ __forceinline__ short bfs(float x) { return __builtin_bit_cast(short, __float2bfloat16(x)); }
__device__ __forceinline__ float fbs(short x) { return __bfloat162float(__builtin_bit_cast(bf16, x)); }

constexpr int B_ = 4, T_ = 1024, M_ = 256, C_ = 512, H_ = 8, HD_ = 64, C3_ = 1536;

#define MFMA16(a, b, c) __builtin_amdgcn_mfma_f32_16x16x32_bf16((a), (b), (c), 0, 0, 0)

// ---------------- prep: 5 weight transposes (fp32 KxN -> bf16 NxK) + 2 converts ----------------
__global__ __launch_bounds__(256) void prep_kernel(
    const float* __restrict__ Wqkv_x, const float* __restrict__ Wqkv_y,
    const float* __restrict__ Wgs, const float* __restrict__ Wgc, const float* __restrict__ Wp,
    const float* __restrict__ x, const float* __restrict__ y,
    bf16* __restrict__ WT_x, bf16* __restrict__ WT_y, bf16* __restrict__ WT_gs,
    bf16* __restrict__ WT_gc, bf16* __restrict__ WT_p,
    bf16* __restrict__ x_bf, bf16* __restrict__ y_bf)
{
    __shared__ float Ls[64][65];
    const int tid = threadIdx.x;
    const int bid = blockIdx.x;
    if (bid < 576) {
        const float* W; bf16* WT; int N, t;
        if (bid < 192)      { W = Wqkv_x; WT = WT_x;  N = C3_; t = bid; }
        else if (bid < 384) { W = Wqkv_y; WT = WT_y;  N = C3_; t = bid - 192; }
        else if (bid < 448) { W = Wgs;    WT = WT_gs; N = C_;  t = bid - 384; }
        else if (bid < 512) { W = Wgc;    WT = WT_gc; N = C_;  t = bid - 448; }
        else                { W = Wp;     WT = WT_p;  N = C_;  t = bid - 512; }
        const int K = C_;
        const int tw = N >> 6;
        const int n0 = (t % tw) * 64, k0 = (t / tw) * 64;
        for (int i = tid; i < 1024; i += 256) {
            int kr = i >> 4, ng = i & 15;
            float4 v = *(const float4*)&W[(size_t)(k0 + kr) * N + n0 + ng * 4];
            Ls[ng * 4 + 0][kr] = v.x; Ls[ng * 4 + 1][kr] = v.y;
            Ls[ng * 4 + 2][kr] = v.z; Ls[ng * 4 + 3][kr] = v.w;
        }
        __syncthreads();
        for (int i = tid; i < 512; i += 256) {
            int n = i >> 3, kg = i & 7;
            s8 r;
            #pragma unroll
            for (int j = 0; j < 8; ++j) r[j] = bfs(Ls[n][kg * 8 + j]);
            *(s8*)&WT[(size_t)(n0 + n) * K + k0 + kg * 8] = r;
        }
    } else if (bid < 1600) {
        int i = (bid - 576) * 2048 + tid * 8;
        s8 r;
        #pragma unroll
        for (int j = 0; j < 8; ++j) r[j] = bfs(x[i + j]);
        *(s8*)&x_bf[i] = r;
    } else {
        int i = (bid - 1600) * 2048 + tid * 8;
        s8 r;
        #pragma unroll
        for (int j = 0; j < 8; ++j) r[j] = bfs(y[i + j]);
        *(s8*)&y_bf[i] = r;
    }
}

// ---------------- qw = bf16(q_x * w4xy), layout (B*T, C) ----------------
__global__ __launch_bounds__(256) void qw_kernel(
    const bf16* __restrict__ qkv_x, const float* __restrict__ w4xy, bf16* __restrict__ qw)
{
    int o = (blockIdx.x * 256 + threadIdx.x) * 8;
    int row = o >> 9, c = o & 511;
    const bf16* src = qkv_x + (size_t)row * C3_ + c;
    s8 r;
    #pragma unroll
    for (int j = 0; j < 8; ++j) r[j] = bfs(__bfloat162float(src[j]) * w4xy[c + j]);
    *(s8*)&qw[o] = r;
}

// ---------------- LDS-staged MFMA GEMM ----------------
template <typename OT>
__global__ __launch_bounds__(256) void gemm_staged_kernel(
    const bf16* __restrict__ A, const bf16* __restrict__ WT, const float* __restrict__ bias,
    OT* __restrict__ Cmat, int N, int K)
{
    __shared__ short Asb[128][72];
    __shared__ short Bsb[64][72];
    const int tid = threadIdx.x;
    const int wave = tid >> 6, lane = tid & 63;
    const int quad = lane >> 4, l16 = lane & 15;
    const int n0 = blockIdx.x * 64, m0 = blockIdx.y * 128;
    f4 acc[2][4];
    #pragma unroll
    for (int mt = 0; mt < 2; ++mt)
        #pragma unroll
        for (int nt = 0; nt < 4; ++nt) acc[mt][nt] = (f4)0.f;

    for (int k0 = 0; k0 < K; k0 += 64) {
        #pragma unroll
        for (int tl = 0; tl < 4; ++tl) {
            int g = tid + tl * 256, row = g >> 3, grp = g & 7;
            *(s8*)&Asb[row][grp * 8] = *(const s8*)&A[(size_t)(m0 + row) * K + k0 + grp * 8];
        }
        #pragma unroll
        for (int tl = 0; tl < 2; ++tl) {
            int g = tid + tl * 256, n = g >> 3, grp = g & 7;
            *(s8*)&Bsb[n][grp * 8] = *(const s8*)&WT[(size_t)(n0 + n) * K + k0 + grp * 8];
        }
        __syncthreads();
        #pragma unroll
        for (int ks = 0; ks < 2; ++ks) {
            s8 a0 = *(const s8*)&Asb[wave * 32 + l16][ks * 32 + quad * 8];
            s8 a1 = *(const s8*)&Asb[wave * 32 + 16 + l16][ks * 32 + quad * 8];
            #pragma unroll
            for (int nt = 0; nt < 4; ++nt) {
                s8 bv = *(const s8*)&Bsb[nt * 16 + l16][ks * 32 + quad * 8];
                acc[0][nt] = MFMA16(a0, bv, acc[0][nt]);
                acc[1][nt] = MFMA16(a1, bv, acc[1][nt]);
            }
        }
        __syncthreads();
    }
    #pragma unroll
    for (int mt = 0; mt < 2; ++mt)
        #pragma unroll
        for (int nt = 0; nt < 4; ++nt) {
            int col = n0 + nt * 16 + l16;
            float bb = bias[col];
            #pragma unroll
            for (int reg = 0; reg < 4; ++reg) {
                int row = m0 + wave * 32 + mt * 16 + quad * 4 + reg;
                storeOut(&Cmat[(size_t)row * N + col], acc[mt][nt][reg] + bb);
            }
        }
}

// ---------------- merged catt1/catt2 ----------------
__global__ __launch_bounds__(256) void catt12m_kernel(
    const bf16* __restrict__ qkv_x, const bf16* __restrict__ qkv_y,
    const float* __restrict__ w4x, const float* __restrict__ w4y,
    float* __restrict__ catt1b, float* __restrict__ catt2b)
{
    int i = blockIdx.x * 256 + threadIdx.x;
    const bf16* row; const float* w; float* out; int oi;
    if (i < 32768) {
        int bh = i >> 10, t = i & 1023, b = bh >> 3, h = bh & 7;
        row = qkv_x + (size_t)(b * T_ + t) * C3_ + h * HD_;
        w = w4x + h * HD_; out = catt1b; oi = i;
    } else {
        int j = i - 32768;
        int bh = j >> 8, m = j & 255, b = bh >> 3, h = bh & 7;
        row = qkv_y + (size_t)(b * M_ + m) * C3_ + h * HD_;
        w = w4y + h * HD_; out = catt2b; oi = j;
    }
    float s = 0.f;
    #pragma unroll
    for (int d = 0; d < HD_; ++d) s = fmaf(__bfloat162float(row[d]), w[d], s);
    out[oi] = s;
}

// ---------------- catt = catt1 + catt2 + 0.125 * qw @ ky^T ----------------
__global__ __launch_bounds__(256) void catt3_kernel(
    const bf16* __restrict__ qw, const bf16* __restrict__ qkv_y,
    const float* __restrict__ catt1, const float* __restrict__ catt2,
    float* __restrict__ catt)
{
    const int tid = threadIdx.x;
    const int wave = tid >> 6, lane = tid & 63;
    const int quad = lane >> 4, l16 = lane & 15;
    const int bh = blockIdx.z, b = bh >> 3, h = bh & 7;
    const int t0 = blockIdx.y * 64, m0 = blockIdx.x * 64;
    f4 sc[4];
    #pragma unroll
    for (int nt = 0; nt < 4; ++nt) sc[nt] = (f4)0.f;
    const bf16* ap = qw + (size_t)(b * T_ + t0 + wave * 16 + l16) * C_ + h * HD_ + quad * 8;
    const bf16* bp = qkv_y + (size_t)(b * M_ + m0 + l16) * C3_ + C_ + h * HD_ + quad * 8;
    #pragma unroll
    for (int k0 = 0; k0 < 64; k0 += 32) {
        s8 a = *(const s8*)(ap + k0);
        #pragma unroll
        for (int nt = 0; nt < 4; ++nt) {
            s8 bv = *(const s8*)(bp + (size_t)nt * 16 * C3_ + k0);
            sc[nt] = MFMA16(a, bv, sc[nt]);
        }
    }
    #pragma unroll
    for (int nt = 0; nt < 4; ++nt) {
        int m = m0 + nt * 16 + l16;
        float c2 = catt2[bh * M_ + m];
        #pragma unroll
        for (int reg = 0; reg < 4; ++reg) {
            int t = t0 + wave * 16 + quad * 4 + reg;
            catt[((size_t)bh * T_ + t) * M_ + m] =
                sc[nt][reg] * 0.125f + catt1[bh * T_ + t] + c2;
        }
    }
}

// ---------------- col softmax sums ----------------
__global__ __launch_bounds__(256) void colpart_kernel(
    const float* __restrict__ catt, float* __restrict__ psum)
{
    const int ch = blockIdx.x, bh = blockIdx.y, m = threadIdx.x;
    const float* p = catt + ((size_t)bh * T_ + ch * 64) * M_ + m;
    float s = 0.f;
    for (int t = 0; t < 64; ++t) s += __expf(p[t * M_]);
    psum[(bh * 16 + ch) * M_ + m] = s;
}

__global__ __launch_bounds__(256) void colfin_kernel(
    const float* __restrict__ psum, float* __restrict__ colinv, float* __restrict__ colsum)
{
    const int bh = blockIdx.x, m = threadIdx.x;
    float s = 0.f;
    #pragma unroll
    for (int ch = 0; ch < 16; ++ch) s += psum[(bh * 16 + ch) * M_ + m];
    colinv[bh * M_ + m] = 1.f / s;
    colsum[bh * M_ + m] = s;
}

// ---------------- row softmax -> Z = e*rowinv*sqrt(colinv) (bf16) + rowsum ----------------
__global__ __launch_bounds__(256) void rowsoft_kernel(
    const float* __restrict__ catt, const float* __restrict__ colinv,
    bf16* __restrict__ zmat, float* __restrict__ rowsum_)
{
    const int wave = threadIdx.x >> 6, lane = threadIdx.x & 63;
    const int row = blockIdx.x * 4 + wave;
    const int bh = row >> 10;
    const float* p = catt + (size_t)row * M_;
    float e[4];
    float s = 0.f;
    #pragma unroll
    for (int j = 0; j < 4; ++j) { e[j] = __expf(p[j * 64 + lane]); s += e[j]; }
    for (int off = 1; off < 64; off <<= 1) s += __shfl_xor(s, off);
    float inv = 1.f / s;
    if (lane == 0) rowsum_[row] = s;
    #pragma unroll
    for (int j = 0; j < 4; ++j) {
        int m = j * 64 + lane;
        zmat[(size_t)row * M_ + m] = __float2bfloat16(e[j] * inv * sqrtf(colinv[bh * M_ + m]));
    }
}

// ---------------- merged V transposes: v_x -> vTx; v_y*sqrt(colsum) -> vTy ----------------
__global__ __launch_bounds__(256) void vtransm_kernel(
    const bf16* __restrict__ qkv_x, const bf16* __restrict__ qkv_y,
    const float* __restrict__ colsum, bf16* __restrict__ vTx, bf16* __restrict__ vTy)
{
    __shared__ short Ls[64][68];
    const int tid = threadIdx.x;
    int bid = blockIdx.x;
    if (bid < 512) {
        const int bh = bid >> 4, t0 = (bid & 15) * 64;
        const int b = bh >> 3, h = bh & 7;
        for (int i = tid; i < 4096; i += 256) {
            int tl = i >> 6, d = i & 63;
            Ls[d][tl] = __builtin_bit_cast(short,
                qkv_x[(size_t)(b * T_ + t0 + tl) * C3_ + 2 * C_ + h * HD_ + d]);
        }
        __syncthreads();
        for (int i = tid; i < 4096; i += 256) {
            int d = i >> 6, tl = i & 63;
            vTx[((size_t)bh * 64 + d) * T_ + t0 + tl] = __builtin_bit_cast(bf16, Ls[d][tl]);
        }
    } else {
        bid -= 512;
        const int bh = bid >> 2, t0 = (bid & 3) * 64;
        const int b = bh >> 3, h = bh & 7;
        for (int i = tid; i < 4096; i += 256) {
            int tl = i >> 6, d = i & 63;
            float v = __bfloat162float(
                qkv_y[(size_t)(b * M_ + t0 + tl) * C3_ + 2 * C_ + h * HD_ + d]);
            Ls[d][tl] = bfs(v * sqrtf(colsum[bh * M_ + t0 + tl]));
        }
        __syncthreads();
        for (int i = tid; i < 4096; i += 256) {
            int d = i >> 6, tl = i & 63;
            vTy[((size_t)bh * 64 + d) * M_ + t0 + tl] = __builtin_bit_cast(bf16, Ls[d][tl]);
        }
    }
}

// ---------------- split-K flash: chain (Z symmetric) + self, partial outputs ----------------
// Entry e -> (jt, g): segments of <=4 key tiles. Partial layout per entry (8448 shorts):
// ocp[64][64] bf16 | osp[64][64] bf16 | lc[64] f32 | ls[64] f32.
// seg g==0 additionally computes ocv = Z @ v'' and writes it to cval (fp32).
__global__ __launch_bounds__(256) void flashsp_kernel(
    const bf16* __restrict__ zmat, const bf16* __restrict__ vTx,
    const bf16* __restrict__ vTy, const bf16* __restrict__ qkv_x,
    const float* __restrict__ rowsum_, short* __restrict__ partial,
    float* __restrict__ cval)
{
    __shared__ short Kc[64][264];
    __shared__ short Ksf[64][72];
    __shared__ short Vb[64][72];
    __shared__ short Ps[4][16][68];
    const int tid = threadIdx.x;
    const int wave = tid >> 6, lane = tid & 63;
    const int quad = lane >> 4, l16 = lane & 15;
    const int bh = blockIdx.y, b = bh >> 3, h = bh & 7;
    const int e = blockIdx.x;
    int jt, g;
    if (e < 4)       { jt = e;                 g = 0; }
    else if (e < 12) { jt = 4 + ((e - 4) >> 1);  g = (e - 4) & 1; }
    else if (e < 24) { jt = 8 + (e - 12) / 3;    g = (e - 12) % 3; }
    else             { jt = 12 + ((e - 24) >> 2); g = (e - 24) & 3; }
    const int t0 = jt * 64;
    const int st_lo = g * 4;
    const int st_hi = min(st_lo + 3, jt);

    // Q fragments
    s8 qc[8], qs[2];
    {
        const bf16* qp = zmat + (size_t)(bh * T_ + t0 + wave * 16 + l16) * M_ + quad * 8;
        #pragma unroll
        for (int f = 0; f < 8; ++f) qc[f] = *(const s8*)(qp + f * 32);
        const bf16* qsp = qkv_x + (size_t)(b * T_ + t0 + wave * 16 + l16) * C3_ + h * HD_ + quad * 8;
        qs[0] = *(const s8*)qsp;
        qs[1] = *(const s8*)(qsp + 32);
    }

    // seg0: ocv = Z @ v''  -> cval (fp32)
    if (g == 0) {
        f4 ocv[4];
        #pragma unroll
        for (int dt = 0; dt < 4; ++dt) ocv[dt] = (f4)0.f;
        const bf16* vb = vTy + (size_t)(bh * 64 + l16) * M_ + quad * 8;
        #pragma unroll
        for (int f = 0; f < 8; ++f)
            #pragma unroll
            for (int dt = 0; dt < 4; ++dt) {
                s8 bv = *(const s8*)(vb + (size_t)dt * 16 * M_ + f * 32);
                ocv[dt] = MFMA16(qc[f], bv, ocv[dt]);
            }
        #pragma unroll
        for (int reg = 0; reg < 4; ++reg) {
            const int t = t0 + wave * 16 + quad * 4 + reg;
            #pragma unroll
            for (int dt = 0; dt < 4; ++dt)
                cval[(size_t)(b * T_ + t) * C_ + h * HD_ + dt * 16 + l16] = ocv[dt][reg];
        }
    }

    f4 oc[4], os_[4];
    float lc[4] = {0.f, 0.f, 0.f, 0.f}, ls_[4] = {0.f, 0.f, 0.f, 0.f};
    #pragma unroll
    for (int dt = 0; dt < 4; ++dt) { oc[dt] = (f4)0.f; os_[dt] = (f4)0.f; }

    // prologue: stage tile st_lo
    {
        const int sb = st_lo * 64;
        #pragma unroll
        for (int tl = 0; tl < 8; ++tl) {
            int g2 = tid + tl * 256, row = g2 >> 5, grp = g2 & 31;
            *(s8*)&Kc[row][grp * 8] = *(const s8*)&zmat[(size_t)(bh * T_ + sb + row) * M_ + grp * 8];
        }
        #pragma unroll
        for (int tl = 0; tl < 2; ++tl) {
            int g2 = tid + tl * 256, row = g2 >> 3, grp = g2 & 7;
            *(s8*)&Ksf[row][grp * 8] =
                *(const s8*)&qkv_x[(size_t)(b * T_ + sb + row) * C3_ + C_ + h * HD_ + grp * 8];
            *(s8*)&Vb[row][grp * 8] = *(const s8*)&vTx[(size_t)(bh * 64 + row) * T_ + sb + grp * 8];
        }
    }
    __syncthreads();

    for (int st = st_lo; st <= st_hi; ++st) {
        const int s0 = st * 64;
        const bool pf = st < st_hi;
        s8 kcp[8], ksp[2], vp[2];
        if (pf) {
            const int sn = s0 + 64;
            #pragma unroll
            for (int tl = 0; tl < 8; ++tl) {
                int g2 = tid + tl * 256, row = g2 >> 5, grp = g2 & 31;
                kcp[tl] = *(const s8*)&zmat[(size_t)(bh * T_ + sn + row) * M_ + grp * 8];
            }
            #pragma unroll
            for (int tl = 0; tl < 2; ++tl) {
                int g2 = tid + tl * 256, row = g2 >> 3, grp = g2 & 7;
                ksp[tl] = *(const s8*)&qkv_x[(size_t)(b * T_ + sn + row) * C3_ + C_ + h * HD_ + grp * 8];
                vp[tl] = *(const s8*)&vTx[(size_t)(bh * 64 + row) * T_ + sn + grp * 8];
            }
        }
        // per-key rowsum (chain logit scale)
        float rs[4];
        #pragma unroll
        for (int nt = 0; nt < 4; ++nt) rs[nt] = rowsum_[bh * T_ + s0 + nt * 16 + l16];
        // chain QK^T (Z x Z)
        f4 sc[4];
        #pragma unroll
        for (int nt = 0; nt < 4; ++nt) sc[nt] = (f4)0.f;
        #pragma unroll
        for (int f = 0; f < 8; ++f)
            #pragma unroll
            for (int nt = 0; nt < 4; ++nt) {
                s8 bv = *(const s8*)&Kc[nt * 16 + l16][f * 32 + quad * 8];
                sc[nt] = MFMA16(qc[f], bv, sc[nt]);
            }
        // self QK^T
        f4 ss[4];
        #pragma unroll
        for (int nt = 0; nt < 4; ++nt) ss[nt] = (f4)0.f;
        #pragma unroll
        for (int f = 0; f < 2; ++f)
            #pragma unroll
            for (int nt = 0; nt < 4; ++nt) {
                s8 bv = *(const s8*)&Ksf[nt * 16 + l16][f * 32 + quad * 8];
                ss[nt] = MFMA16(qs[f], bv, ss[nt]);
            }
        // chain softmax -> Ps, PV
        #pragma unroll
        for (int reg = 0; reg < 4; ++reg) {
            const int t_g = t0 + wave * 16 + quad * 4 + reg;
            #pragma unroll
            for (int nt = 0; nt < 4; ++nt) {
                float p = (s0 + nt * 16 + l16 <= t_g)
                          ? __expf(sc[nt][reg] * rs[nt] * 0.0625f) : 0.f;
                lc[reg] += p;
                Ps[wave][quad * 4 + reg][nt * 16 + l16] = bfs(p);
            }
        }
        #pragma unroll
        for (int ks = 0; ks < 2; ++ks) {
            const short* pp = &Ps[wave][l16][ks * 32 + quad * 8];
            s4 alo = *(const s4*)pp;
            s4 ahi = *(const s4*)(pp + 4);
            s8 a;
            a[0] = alo[0]; a[1] = alo[1]; a[2] = alo[2]; a[3] = alo[3];
            a[4] = ahi[0]; a[5] = ahi[1]; a[6] = ahi[2]; a[7] = ahi[3];
            #pragma unroll
            for (int dt = 0; dt < 4; ++dt) {
                s8 bv = *(const s8*)&Vb[dt * 16 + l16][ks * 32 + quad * 8];
                oc[dt] = MFMA16(a, bv, oc[dt]);
            }
        }
        // self softmax -> Ps, PV
        #pragma unroll
        for (int reg = 0; reg < 4; ++reg) {
            const int t_g = t0 + wave * 16 + quad * 4 + reg;
            #pragma unroll
            for (int nt = 0; nt < 4; ++nt) {
                float p = (s0 + nt * 16 + l16 <= t_g) ? __expf(ss[nt][reg] * 0.125f) : 0.f;
                ls_[reg] += p;
                Ps[wave][quad * 4 + reg][nt * 16 + l16] = bfs(p);
            }
        }
        #pragma unroll
        for (int ks = 0; ks < 2; ++ks) {
            const short* pp = &Ps[wave][l16][ks * 32 + quad * 8];
            s4 alo = *(const s4*)pp;
            s4 ahi = *(const s4*)(pp + 4);
            s8 a;
            a[0] = alo[0]; a[1] = alo[1]; a[2] = alo[2]; a[3] = alo[3];
            a[4] = ahi[0]; a[5] = ahi[1]; a[6] = ahi[2]; a[7] = ahi[3];
            #pragma unroll
            for (int dt = 0; dt < 4; ++dt) {
                s8 bv = *(const s8*)&Vb[dt * 16 + l16][ks * 32 + quad * 8];
                os_[dt] = MFMA16(a, bv, os_[dt]);
            }
        }
        __syncthreads();
        if (pf) {
            #pragma unroll
            for (int tl = 0; tl < 8; ++tl) {
                int g2 = tid + tl * 256, row = g2 >> 5, grp = g2 & 31;
                *(s8*)&Kc[row][grp * 8] = kcp[tl];
            }
            #pragma unroll
            for (int tl = 0; tl < 2; ++tl) {
                int g2 = tid + tl * 256, row = g2 >> 3, grp = g2 & 7;
                *(s8*)&Ksf[row][grp * 8] = ksp[tl];
                *(s8*)&Vb[row][grp * 8] = vp[tl];
            }
        }
        __syncthreads();
    }

    // store partials
    short* pb = partial + (size_t)(bh * 40 + e) * 8448;
    float* lcp = (float*)(pb + 8192);
    float* lsp = (float*)(pb + 8320);
    #pragma unroll
    for (int reg = 0; reg < 4; ++reg) {
        const int row = wave * 16 + quad * 4 + reg;
        #pragma unroll
        for (int dt = 0; dt < 4; ++dt) {
            pb[row * 64 + dt * 16 + l16] = bfs(oc[dt][reg]);
            pb[4096 + row * 64 + dt * 16 + l16] = bfs(os_[dt][reg]);
        }
        float l1 = lc[reg], l2 = ls_[reg];
        l1 += __shfl_xor(l1, 1); l1 += __shfl_xor(l1, 2);
        l1 += __shfl_xor(l1, 4); l1 += __shfl_xor(l1, 8);
        l2 += __shfl_xor(l2, 1); l2 += __shfl_xor(l2, 2);
        l2 += __shfl_xor(l2, 4); l2 += __shfl_xor(l2, 8);
        if (l16 == 0) { lcp[row] = l1; lsp[row] = l2; }
    }
}

// ---------------- combine: sum partials, normalize, add x + ocv -> cval/sval (+bf16) ----------------
__global__ __launch_bounds__(256) void combine_kernel(
    const short* __restrict__ partial, const float* __restrict__ x,
    float* __restrict__ cval, bf16* __restrict__ cval_bf,
    float* __restrict__ sval, bf16* __restrict__ sval_bf)
{
    const int tid = threadIdx.x;
    const int jt = blockIdx.x, bh = blockIdx.y, b = bh >> 3, h = bh & 7;
    const int nseg = (jt >> 2) + 1;
    const int e0 = (jt < 4) ? jt : (jt < 8) ? 4 + 2 * (jt - 4)
                 : (jt < 12) ? 12 + 3 * (jt - 8) : 24 + 4 * (jt - 12);
    const int t_loc = tid >> 2, d0 = (tid & 3) * 16;
    float oc[16], os[16];
    #pragma unroll
    for (int j = 0; j < 16; ++j) { oc[j] = 0.f; os[j] = 0.f; }
    float lc = 0.f, ls = 0.f;
    for (int g = 0; g < nseg; ++g) {
        const short* pb = partial + (size_t)(bh * 40 + e0 + g) * 8448;
        s8 c0 = *(const s8*)&pb[t_loc * 64 + d0];
        s8 c1 = *(const s8*)&pb[t_loc * 64 + d0 + 8];
        s8 s0 = *(const s8*)&pb[4096 + t_loc * 64 + d0];
        s8 s1 = *(const s8*)&pb[4096 + t_loc * 64 + d0 + 8];
        #pragma unroll
        for (int j = 0; j < 8; ++j) {
            oc[j] += fbs(c0[j]); oc[8 + j] += fbs(c1[j]);
            os[j] += fbs(s0[j]); os[8 + j] += fbs(s1[j]);
        }
        lc += ((const float*)(pb + 8192))[t_loc];
        ls += ((const float*)(pb + 8320))[t_loc];
    }
    const float icl = 1.f / lc, isl = 1.f / ls;
    const size_t idx0 = (size_t)(b * T_ + jt * 64 + t_loc) * C_ + h * HD_ + d0;
    #pragma unroll
    for (int j = 0; j < 16; ++j) {
        float cv = cval[idx0 + j] + x[idx0 + j] + oc[j] * icl;
        cval[idx0 + j] = cv;
        cval_bf[idx0 + j] = __float2bfloat16(cv);
        float sv = os[j] * isl;
        sval[idx0 + j] = sv;
        sval_bf[idx0 + j] = __float2bfloat16(sv);
    }
}

// ---------------- fused dual gate GEMM + sigmoid + combine -> gated bf16 ----------------
__global__ __launch_bounds__(256) void gatefuse_kernel(
    const bf16* __restrict__ svalb, const bf16* __restrict__ cvalb,
    const bf16* __restrict__ WTgs, const bf16* __restrict__ WTgc,
    const float* __restrict__ bgs, const float* __restrict__ bgc,
    const float* __restrict__ cval, const float* __restrict__ sval,
    bf16* __restrict__ gated)
{
    __shared__ short Sb[128][72], Cb[128][72], W1b[64][72], W2b[64][72];
    const int tid = threadIdx.x;
    const int wave = tid >> 6, lane = tid & 63;
    const int quad = lane >> 4, l16 = lane & 15;
    const int n0 = blockIdx.x * 64, m0 = blockIdx.y * 128;
    f4 aS[2][4], aC[2][4];
    #pragma unroll
    for (int mt = 0; mt < 2; ++mt)
        #pragma unroll
        for (int nt = 0; nt < 4; ++nt) { aS[mt][nt] = (f4)0.f; aC[mt][nt] = (f4)0.f; }

    for (int k0 = 0; k0 < C_; k0 += 64) {
        #pragma unroll
        for (int tl = 0; tl < 4; ++tl) {
            int g = tid + tl * 256, row = g >> 3, grp = g & 7;
            *(s8*)&Sb[row][grp * 8] = *(const s8*)&svalb[(size_t)(m0 + row) * C_ + k0 + grp * 8];
            *(s8*)&Cb[row][grp * 8] = *(const s8*)&cvalb[(size_t)(m0 + row) * C_ + k0 + grp * 8];
        }
        #pragma unroll
        for (int tl = 0; tl < 2; ++tl) {
            int g = tid + tl * 256, n = g >> 3, grp = g & 7;
            *(s8*)&W1b[n][grp * 8] = *(const s8*)&WTgs[(size_t)(n0 + n) * C_ + k0 + grp * 8];
            *(s8*)&W2b[n][grp * 8] = *(const s8*)&WTgc[(size_t)(n0 + n) * C_ + k0 + grp * 8];
        }
        __syncthreads();
        #pragma unroll
        for (int ks = 0; ks < 2; ++ks) {
            s8 s0f = *(const s8*)&Sb[wave * 32 + l16][ks * 32 + quad * 8];
            s8 s1f = *(const s8*)&Sb[wave * 32 + 16 + l16][ks * 32 + quad * 8];
            s8 c0f = *(const s8*)&Cb[wave * 32 + l16][ks * 32 + quad * 8];
            s8 c1f = *(const s8*)&Cb[wave * 32 + 16 + l16][ks * 32 + quad * 8];
            #pragma unroll
            for (int nt = 0; nt < 4; ++nt) {
                s8 w1 = *(const s8*)&W1b[nt * 16 + l16][ks * 32 + quad * 8];
                s8 w2 = *(const s8*)&W2b[nt * 16 + l16][ks * 32 + quad * 8];
                aS[0][nt] = MFMA16(s0f, w1, aS[0][nt]);
                aS[1][nt] = MFMA16(s1f, w1, aS[1][nt]);
                aC[0][nt] = MFMA16(c0f, w2, aC[0][nt]);
                aC[1][nt] = MFMA16(c1f, w2, aC[1][nt]);
            }
        }
        __syncthreads();
    }
    #pragma unroll
    for (int mt = 0; mt < 2; ++mt)
        #pragma unroll
        for (int nt = 0; nt < 4; ++nt) {
            int col = n0 + nt * 16 + l16;
            float b1 = bgs[col], b2 = bgc[col];
            #pragma unroll
            for (int reg = 0; reg < 4; ++reg) {
                int row = m0 + wave * 32 + mt * 16 + quad * 4 + reg;
                size_t idx = (size_t)row * C_ + col;
                float gs = 1.f / (1.f + __expf(-(aS[mt][nt][reg] + b1)));
                float gc = 1.f / (1.f + __expf(-(aC[mt][nt][reg] + b2)));
                gated[idx] = __float2bfloat16(gs * cval[idx] + gc * sval[idx]);
            }
        }
}

extern "C" void kernel_launch(void* const* d_in, const int* in_sizes, int n_in,
                              void* d_out, int out_size, void* d_ws, size_t ws_size,
                              hipStream_t stream)
{
    const float* x      = (const float*)d_in[0];
    const float* y      = (const float*)d_in[1];
    // d_in[2]: attn_x_mask — structurally causal tril, computed inline
    const float* Wqkv_x = (const float*)d_in[3];
    const float* bqkv_x = (const float*)d_in[4];
    const float* Wqkv_y = (const float*)d_in[5];
    const float* bqkv_y = (const float*)d_in[6];
    const float* w4x    = (const float*)d_in[7];
    const float* w4y    = (const float*)d_in[8];
    const float* w4xy   = (const float*)d_in[9];
    const float* Wgs    = (const float*)d_in[10];
    const float* bgs    = (const float*)d_in[11];
    const float* Wgc    = (const float*)d_in[12];
    const float* bgc    = (const float*)d_in[13];
    const float* Wp     = (const float*)d_in[14];
    const float* bp     = (const float*)d_in[15];

    // Workspace (f-word offsets; max 114.1 MB < R4-proven 115.6 MB)
    float* ws = (float*)d_ws;
    bf16*  qkv_x_bf = (bf16*)(ws + 0);           // 6,291,456 bf16
    bf16*  qkv_y_bf = (bf16*)(ws + 3145728);     // 1,572,864 bf16
    float* catt     = ws + 3932160;              // 8,388,608 f (dead after rowsoft)
    short* partial  = (short*)(ws + 3932160);    //   reuse: 1280 x 8448 shorts (5.41M w)
    bf16*  cval_bf  = (bf16*)(ws + 9338880);     //   reuse catt tail (written by combine)
    bf16*  gated_bf = (bf16*)(ws + 10387456);    //   reuse catt tail
    bf16*  zmat     = (bf16*)(ws + 12320768);    // 8,388,608 bf16 (written at rowsoft)
    bf16*  x_bf     = zmat;                      //   pre-QKV reuse
    bf16*  y_bf     = (bf16*)(ws + 13369344);    //   pre-QKV reuse
    bf16*  vTx_bf   = (bf16*)(ws + 20709376);    // 2,097,152 bf16
    bf16*  vTy_bf   = (bf16*)(ws + 21757952);    // 524,288 bf16 (v_y * sqrt(colsum))
    float* cval     = ws + 22020096;             // 2,097,152 f
    float* psum_    = cval;                      //   pre-cval reuse (colpart)
    float* sval     = ws + 24117248;             // 2,097,152 f
    bf16*  qw_bf    = (bf16*)(ws + 26214400);    // 2,097,152 bf16 (dead after catt3)
    bf16*  sval_bf  = qw_bf;                     //   reuse (written by combine)
    bf16*  WT_x     = (bf16*)(ws + 27262976);    // 786,432 bf16
    bf16*  WT_y     = (bf16*)(ws + 27656192);
    bf16*  WT_gs    = (bf16*)(ws + 28049408);    // 262,144 bf16
    bf16*  WT_gc    = (bf16*)(ws + 28180480);
    bf16*  WT_p     = (bf16*)(ws + 28311552);
    float* catt1b   = ws + 28442624;             // 32,768 f
    float* catt2b   = ws + 28475392;             //  8,192 f
    float* colinv   = ws + 28483584;             //  8,192 f
    float* rowsum_  = ws + 28491776;             // 32,768 f
    float* colsum_  = ws + 28524544;             //  8,192 f (end: 114.1 MB)

    // 0: prep (5 transposes + 2 converts)
    prep_kernel<<<1856, 256, 0, stream>>>(
        Wqkv_x, Wqkv_y, Wgs, Wgc, Wp, x, y,
        WT_x, WT_y, WT_gs, WT_gc, WT_p, x_bf, y_bf);

    // 1-2: QKV projections
    gemm_staged_kernel<bf16><<<dim3(24, 32), 256, 0, stream>>>(x_bf, WT_x, bqkv_x, qkv_x_bf, C3_, C_);
    gemm_staged_kernel<bf16><<<dim3(24, 8), 256, 0, stream>>>(y_bf, WT_y, bqkv_y, qkv_y_bf, C3_, C_);

    // 3-5: attention logits
    catt12m_kernel<<<160, 256, 0, stream>>>(qkv_x_bf, qkv_y_bf, w4x, w4y, catt1b, catt2b);
    qw_kernel<<<1024, 256, 0, stream>>>(qkv_x_bf, w4xy, qw_bf);
    catt3_kernel<<<dim3(4, 16, 32), 256, 0, stream>>>(qw_bf, qkv_y_bf, catt1b, catt2b, catt);

    // 6-7: softmaxes -> Z (symmetric chain operand), rowsum, colinv/colsum
    colpart_kernel<<<dim3(16, 32), 256, 0, stream>>>(catt, psum_);
    colfin_kernel<<<32, 256, 0, stream>>>(psum_, colinv, colsum_);
    rowsoft_kernel<<<8192, 256, 0, stream>>>(catt, colinv, zmat, rowsum_);

    // 8: V transposes (vTy pre-scaled by sqrt(colsum))
    vtransm_kernel<<<640, 256, 0, stream>>>(qkv_x_bf, qkv_y_bf, colsum_, vTx_bf, vTy_bf);

    // 9: split-K flash (chain Z·Zᵀ·rowsum + self), partials + ocv->cval
    flashsp_kernel<<<dim3(40, 32), 256, 0, stream>>>(
        zmat, vTx_bf, vTy_bf, qkv_x_bf, rowsum_, partial, cval);

    // 10: combine partials -> cval/sval (+bf16)
    combine_kernel<<<dim3(16, 32), 256, 0, stream>>>(
        partial, x, cval, cval_bf, sval, sval_bf);

    // 11: fused gates -> gated bf16
    gatefuse_kernel<<<dim3(8, 32), 256, 0, stream>>>(
        sval_bf, cval_bf, WT_gs, WT_gc, bgs, bgc, cval, sval, gated_bf);

    // 12: out = gated @ Wp + bp
    gemm_staged_kernel<float><<<dim3(8, 32), 256, 0, stream>>>(
        gated_bf, WT_p, bp, (float*)d_out, C_, C_);
}

// Round 11
// 293.004 us; speedup vs baseline: 1.0119x; 1.0119x over previous
//
#include <hip/hip_runtime.h>
#include <hip/hip_bf16.h>

typedef __hip_bfloat16 bf16;
using f4 = __attribute__((ext_vector_type(4))) float;
using s8 = __attribute__((ext_vector_type(8))) short;
using s4v = __attribute__((ext_vector_type(4))) short;

__device__ __forceinline__ void storeOut(float* p, float v) { *p = v; }
__device__ __forceinline__ void storeOut(bf16* p, float v) { *p = __float2bfloat16(v); }
__device__ __forceinline__ short bfs(float x) { return __builtin_bit_cast(short, __float2bfloat16(x)); }

constexpr int B_ = 4, T_ = 1024, M_ = 256, C_ = 512, H_ = 8, HD_ = 64, C3_ = 1536;

#define MFMA16(a, b, c) __builtin_amdgcn_mfma_f32_16x16x32_bf16((a), (b), (c), 0, 0, 0)
#define MFMA8(a, b, c)  __builtin_amdgcn_mfma_f32_16x16x32_fp8_fp8((a), (b), (c), 0, 0, 0)

#if __has_builtin(__builtin_amdgcn_cvt_pk_fp8_f32)
__device__ __forceinline__ unsigned int pk4_fp8(float a, float b, float c, float d) {
    int r = __builtin_amdgcn_cvt_pk_fp8_f32(a, b, 0, false);
    r = __builtin_amdgcn_cvt_pk_fp8_f32(c, d, r, true);
    return (unsigned int)r;
}
#else
__device__ __forceinline__ unsigned char enc8(float x) {
    if (!(x >= 0.015625f)) return 0;          // FTZ subnormals (nonneg inputs)
    if (x > 448.f) x = 448.f;
    unsigned u = __builtin_bit_cast(unsigned, x);
    u += 0x7FFFF + ((u >> 20) & 1);           // RNE to 3 mantissa bits
    int ee = (int)((u >> 23) & 0xFF) - 127 + 7;
    unsigned m = (u >> 20) & 7;
    if (ee >= 15 && !(ee == 15 && m <= 6)) return 0x7E;
    return (unsigned char)((ee << 3) | m);
}
__device__ __forceinline__ unsigned int pk4_fp8(float a, float b, float c, float d) {
    return (unsigned)enc8(a) | ((unsigned)enc8(b) << 8) |
           ((unsigned)enc8(c) << 16) | ((unsigned)enc8(d) << 24);
}
#endif

// ---------------- prep: 5 weight transposes + 2 input converts ----------------
__global__ __launch_bounds__(256) void prep_kernel(
    const float* __restrict__ Wqkv_x, const float* __restrict__ Wqkv_y,
    const float* __restrict__ Wgs, const float* __restrict__ Wgc, const float* __restrict__ Wp,
    const float* __restrict__ x, const float* __restrict__ y,
    bf16* __restrict__ WT_x, bf16* __restrict__ WT_y, bf16* __restrict__ WT_gs,
    bf16* __restrict__ WT_gc, bf16* __restrict__ WT_p,
    bf16* __restrict__ x_bf, bf16* __restrict__ y_bf)
{
    __shared__ float Ls[64][65];
    const int tid = threadIdx.x;
    const int bid = blockIdx.x;
    if (bid < 576) {
        const float* W; bf16* WT; int N, t;
        if (bid < 192)      { W = Wqkv_x; WT = WT_x;  N = C3_; t = bid; }
        else if (bid < 384) { W = Wqkv_y; WT = WT_y;  N = C3_; t = bid - 192; }
        else if (bid < 448) { W = Wgs;    WT = WT_gs; N = C_;  t = bid - 384; }
        else if (bid < 512) { W = Wgc;    WT = WT_gc; N = C_;  t = bid - 448; }
        else                { W = Wp;     WT = WT_p;  N = C_;  t = bid - 512; }
        const int K = C_;
        const int tw = N >> 6;
        const int n0 = (t % tw) * 64, k0 = (t / tw) * 64;
        for (int i = tid; i < 1024; i += 256) {
            int kr = i >> 4, ng = i & 15;
            float4 v = *(const float4*)&W[(size_t)(k0 + kr) * N + n0 + ng * 4];
            Ls[ng * 4 + 0][kr] = v.x; Ls[ng * 4 + 1][kr] = v.y;
            Ls[ng * 4 + 2][kr] = v.z; Ls[ng * 4 + 3][kr] = v.w;
        }
        __syncthreads();
        for (int i = tid; i < 512; i += 256) {
            int n = i >> 3, kg = i & 7;
            s8 r;
            #pragma unroll
            for (int j = 0; j < 8; ++j) r[j] = bfs(Ls[n][kg * 8 + j]);
            *(s8*)&WT[(size_t)(n0 + n) * K + k0 + kg * 8] = r;
        }
    } else if (bid < 1600) {
        int i = (bid - 576) * 2048 + tid * 8;
        s8 r;
        #pragma unroll
        for (int j = 0; j < 8; ++j) r[j] = bfs(x[i + j]);
        *(s8*)&x_bf[i] = r;
    } else {
        int i = (bid - 1600) * 2048 + tid * 8;
        s8 r;
        #pragma unroll
        for (int j = 0; j < 8; ++j) r[j] = bfs(y[i + j]);
        *(s8*)&y_bf[i] = r;
    }
}

// ---------------- qw = bf16(q_x * w4xy) ----------------
__global__ __launch_bounds__(256) void qw_kernel(
    const bf16* __restrict__ qkv_x, const float* __restrict__ w4xy, bf16* __restrict__ qw)
{
    int o = (blockIdx.x * 256 + threadIdx.x) * 8;
    int row = o >> 9, c = o & 511;
    const bf16* src = qkv_x + (size_t)row * C3_ + c;
    s8 r;
    #pragma unroll
    for (int j = 0; j < 8; ++j) r[j] = bfs(__bfloat162float(src[j]) * w4xy[c + j]);
    *(s8*)&qw[o] = r;
}

// ---------------- LDS-staged MFMA GEMM ----------------
template <typename OT>
__global__ __launch_bounds__(256) void gemm_staged_kernel(
    const bf16* __restrict__ A, const bf16* __restrict__ WT, const float* __restrict__ bias,
    OT* __restrict__ Cmat, int N, int K)
{
    __shared__ short Asb[128][72];
    __shared__ short Bsb[64][72];
    const int tid = threadIdx.x;
    const int wave = tid >> 6, lane = tid & 63;
    const int quad = lane >> 4, l16 = lane & 15;
    const int n0 = blockIdx.x * 64, m0 = blockIdx.y * 128;
    f4 acc[2][4];
    #pragma unroll
    for (int mt = 0; mt < 2; ++mt)
        #pragma unroll
        for (int nt = 0; nt < 4; ++nt) acc[mt][nt] = (f4)0.f;

    for (int k0 = 0; k0 < K; k0 += 64) {
        #pragma unroll
        for (int tl = 0; tl < 4; ++tl) {
            int g = tid + tl * 256, row = g >> 3, grp = g & 7;
            *(s8*)&Asb[row][grp * 8] = *(const s8*)&A[(size_t)(m0 + row) * K + k0 + grp * 8];
        }
        #pragma unroll
        for (int tl = 0; tl < 2; ++tl) {
            int g = tid + tl * 256, n = g >> 3, grp = g & 7;
            *(s8*)&Bsb[n][grp * 8] = *(const s8*)&WT[(size_t)(n0 + n) * K + k0 + grp * 8];
        }
        __syncthreads();
        #pragma unroll
        for (int ks = 0; ks < 2; ++ks) {
            s8 a0 = *(const s8*)&Asb[wave * 32 + l16][ks * 32 + quad * 8];
            s8 a1 = *(const s8*)&Asb[wave * 32 + 16 + l16][ks * 32 + quad * 8];
            #pragma unroll
            for (int nt = 0; nt < 4; ++nt) {
                s8 bv = *(const s8*)&Bsb[nt * 16 + l16][ks * 32 + quad * 8];
                acc[0][nt] = MFMA16(a0, bv, acc[0][nt]);
                acc[1][nt] = MFMA16(a1, bv, acc[1][nt]);
            }
        }
        __syncthreads();
    }
    #pragma unroll
    for (int mt = 0; mt < 2; ++mt)
        #pragma unroll
        for (int nt = 0; nt < 4; ++nt) {
            int col = n0 + nt * 16 + l16;
            float bb = bias[col];
            #pragma unroll
            for (int reg = 0; reg < 4; ++reg) {
                int row = m0 + wave * 32 + mt * 16 + quad * 4 + reg;
                storeOut(&Cmat[(size_t)row * N + col], acc[mt][nt][reg] + bb);
            }
        }
}

// ---------------- merged catt1/catt2 ----------------
__global__ __launch_bounds__(256) void catt12m_kernel(
    const bf16* __restrict__ qkv_x, const bf16* __restrict__ qkv_y,
    const float* __restrict__ w4x, const float* __restrict__ w4y,
    float* __restrict__ catt1b, float* __restrict__ catt2b)
{
    int i = blockIdx.x * 256 + threadIdx.x;
    const bf16* row; const float* w; float* out; int oi;
    if (i < 32768) {
        int bh = i >> 10, t = i & 1023, b = bh >> 3, h = bh & 7;
        row = qkv_x + (size_t)(b * T_ + t) * C3_ + h * HD_;
        w = w4x + h * HD_; out = catt1b; oi = i;
    } else {
        int j = i - 32768;
        int bh = j >> 8, m = j & 255, b = bh >> 3, h = bh & 7;
        row = qkv_y + (size_t)(b * M_ + m) * C3_ + h * HD_;
        w = w4y + h * HD_; out = catt2b; oi = j;
    }
    float s = 0.f;
    #pragma unroll
    for (int d = 0; d < HD_; ++d) s = fmaf(__bfloat162float(row[d]), w[d], s);
    out[oi] = s;
}

// ---------------- catt3: logits + FUSED column partial sums ----------------
__global__ __launch_bounds__(256) void catt3_kernel(
    const bf16* __restrict__ qw, const bf16* __restrict__ qkv_y,
    const float* __restrict__ catt1, const float* __restrict__ catt2,
    float* __restrict__ catt, float* __restrict__ psum)
{
    __shared__ float redc[4][64];
    const int tid = threadIdx.x;
    const int wave = tid >> 6, lane = tid & 63;
    const int quad = lane >> 4, l16 = lane & 15;
    const int bh = blockIdx.z, b = bh >> 3, h = bh & 7;
    const int t0 = blockIdx.y * 64, m0 = blockIdx.x * 64;
    f4 sc[4];
    #pragma unroll
    for (int nt = 0; nt < 4; ++nt) sc[nt] = (f4)0.f;
    const bf16* ap = qw + (size_t)(b * T_ + t0 + wave * 16 + l16) * C_ + h * HD_ + quad * 8;
    const bf16* bp = qkv_y + (size_t)(b * M_ + m0 + l16) * C3_ + C_ + h * HD_ + quad * 8;
    #pragma unroll
    for (int k0 = 0; k0 < 64; k0 += 32) {
        s8 a = *(const s8*)(ap + k0);
        #pragma unroll
        for (int nt = 0; nt < 4; ++nt) {
            s8 bv = *(const s8*)(bp + (size_t)nt * 16 * C3_ + k0);
            sc[nt] = MFMA16(a, bv, sc[nt]);
        }
    }
    float csloc[4];
    #pragma unroll
    for (int nt = 0; nt < 4; ++nt) {
        int m = m0 + nt * 16 + l16;
        float c2 = catt2[bh * M_ + m];
        float es = 0.f;
        #pragma unroll
        for (int reg = 0; reg < 4; ++reg) {
            int t = t0 + wave * 16 + quad * 4 + reg;
            float v = sc[nt][reg] * 0.125f + catt1[bh * T_ + t] + c2;
            catt[((size_t)bh * T_ + t) * M_ + m] = v;
            es += __expf(v);
        }
        es += __shfl_xor(es, 16);
        es += __shfl_xor(es, 32);
        csloc[nt] = es;
    }
    if (quad == 0) {
        #pragma unroll
        for (int nt = 0; nt < 4; ++nt) redc[wave][nt * 16 + l16] = csloc[nt];
    }
    __syncthreads();
    if (tid < 64) {
        float s = redc[0][tid] + redc[1][tid] + redc[2][tid] + redc[3][tid];
        psum[((size_t)bh * 16 + (t0 >> 6)) * M_ + m0 + tid] = s;
    }
}

// ---------------- colfin: 16 chunk partials -> colinv ----------------
__global__ __launch_bounds__(256) void colfin_kernel(
    const float* __restrict__ psum, float* __restrict__ colinv)
{
    const int bh = blockIdx.x, m = threadIdx.x;
    float s = 0.f;
    #pragma unroll
    for (int ch = 0; ch < 16; ++ch) s += psum[(bh * 16 + ch) * M_ + m];
    colinv[bh * M_ + m] = 1.f / s;
}

// ---------------- row softmax -> x2y bf16 AND z fp8 (x128) + rowsum ----------------
__global__ __launch_bounds__(256) void rowsoft_kernel(
    const float* __restrict__ catt, const float* __restrict__ colinv,
    bf16* __restrict__ x2y, unsigned char* __restrict__ zmat8, float* __restrict__ rowsum_)
{
    const int wave = threadIdx.x >> 6, lane = threadIdx.x & 63;
    const int row = blockIdx.x * 4 + wave;
    const int bh = row >> 10;
    const float* p = catt + (size_t)row * M_;
    float4 v = *(const float4*)&p[lane * 4];
    float e0 = __expf(v.x), e1 = __expf(v.y), e2 = __expf(v.z), e3 = __expf(v.w);
    float s = e0 + e1 + e2 + e3;
    for (int off = 1; off < 64; off <<= 1) s += __shfl_xor(s, off);
    float ri = 1.f / s;
    if (lane == 0) rowsum_[row] = s;
    float4 ci = *(const float4*)&colinv[bh * M_ + lane * 4];
    s4v xo;
    xo[0] = bfs(e0 * ri); xo[1] = bfs(e1 * ri);
    xo[2] = bfs(e2 * ri); xo[3] = bfs(e3 * ri);
    *(s4v*)&x2y[(size_t)row * M_ + lane * 4] = xo;
    unsigned int z4 = pk4_fp8(e0 * ri * sqrtf(ci.x) * 128.f, e1 * ri * sqrtf(ci.y) * 128.f,
                              e2 * ri * sqrtf(ci.z) * 128.f, e3 * ri * sqrtf(ci.w) * 128.f);
    *(unsigned int*)&zmat8[(size_t)row * M_ + lane * 4] = z4;
}

// ---------------- merged V transposes ----------------
__global__ __launch_bounds__(256) void vtransm_kernel(
    const bf16* __restrict__ qkv_x, const bf16* __restrict__ qkv_y,
    bf16* __restrict__ vTx, bf16* __restrict__ vTy)
{
    __shared__ short Ls[64][68];
    const int tid = threadIdx.x;
    int bid = blockIdx.x;
    const bf16* qkv; bf16* vT; int Nrows, bh, t0;
    if (bid < 512) { qkv = qkv_x; vT = vTx; Nrows = T_; bh = bid >> 4; t0 = (bid & 15) * 64; }
    else { bid -= 512; qkv = qkv_y; vT = vTy; Nrows = M_; bh = bid >> 2; t0 = (bid & 3) * 64; }
    const int b = bh >> 3, h = bh & 7;
    for (int i = tid; i < 4096; i += 256) {
        int tl = i >> 6, d = i & 63;
        Ls[d][tl] = __builtin_bit_cast(short,
            qkv[(size_t)(b * Nrows + t0 + tl) * C3_ + 2 * C_ + h * HD_ + d]);
    }
    __syncthreads();
    for (int i = tid; i < 4096; i += 256) {
        int d = i >> 6, tl = i & 63;
        vT[((size_t)bh * 64 + d) * Nrows + t0 + tl] = __builtin_bit_cast(bf16, Ls[d][tl]);
    }
}

// ---------------- flash4: merged chain(fp8) + self(bf16) + fused cval ----------------
// R9 flash3 structure (2 barriers/tile, VGPR prefetch, complementary-jt swizzle,
// no-max softmax) with chain K in fp8 e4m3 (Z scaled x128): LDS 60.9->44.5 KB
// => 3 blocks/CU. Chain logit = sc * rowsum/(16*128^2).
__global__ __launch_bounds__(256, 3) void flash4_kernel(
    const unsigned char* __restrict__ zmat8, const bf16* __restrict__ x2y,
    const bf16* __restrict__ vTx, const bf16* __restrict__ vTy,
    const bf16* __restrict__ qkv_x, const float* __restrict__ x,
    const float* __restrict__ rowsum_,
    float* __restrict__ cval, bf16* __restrict__ cval_bf,
    float* __restrict__ sval, bf16* __restrict__ sval_bf)
{
    __shared__ unsigned char Kc8[64][272];
    __shared__ short Ksf[64][72];
    __shared__ short Vb[64][72];
    __shared__ short Ps[4][16][68];
    const int tid = threadIdx.x;
    const int wave = tid >> 6, lane = tid & 63;
    const int quad = lane >> 4, l16 = lane & 15;
    const int bh = blockIdx.y, b = bh >> 3, h = bh & 7;
    const int jt = (blockIdx.y < 16) ? (int)blockIdx.x : 15 - (int)blockIdx.x;
    const int t0 = jt * 64;
    const int nst = jt + 1;

    // chain Q fragments (fp8) + self Q (bf16)
    long qc[8];
    {
        const unsigned char* qp = zmat8 + ((size_t)(bh * T_) + t0 + wave * 16 + l16) * M_ + quad * 8;
        #pragma unroll
        for (int f = 0; f < 8; ++f) qc[f] = *(const long*)(qp + f * 32);
    }
    s8 qs[2];
    {
        const bf16* qsp = qkv_x + (size_t)(b * T_ + t0 + wave * 16 + l16) * C3_ + h * HD_ + quad * 8;
        qs[0] = *(const s8*)qsp;
        qs[1] = *(const s8*)(qsp + 32);
    }

    // fused cval: ocv = x2y @ vTy with short-lived bf16 Q frags (full accuracy)
    f4 ocv[4];
    #pragma unroll
    for (int dt = 0; dt < 4; ++dt) ocv[dt] = (f4)0.f;
    {
        const bf16* qbp = x2y + (size_t)(bh * T_ + t0 + wave * 16 + l16) * M_ + quad * 8;
        const bf16* vb = vTy + (size_t)(bh * 64 + l16) * M_ + quad * 8;
        #pragma unroll
        for (int f = 0; f < 8; ++f) {
            s8 qb = *(const s8*)(qbp + f * 32);
            #pragma unroll
            for (int dt = 0; dt < 4; ++dt) {
                s8 bv = *(const s8*)(vb + (size_t)dt * 16 * M_ + f * 32);
                ocv[dt] = MFMA16(qb, bv, ocv[dt]);
            }
        }
    }

    f4 oc[4], os_[4];
    float lc[4] = {0.f, 0.f, 0.f, 0.f}, ls_[4] = {0.f, 0.f, 0.f, 0.f};
    #pragma unroll
    for (int dt = 0; dt < 4; ++dt) { oc[dt] = (f4)0.f; os_[dt] = (f4)0.f; }

    // prologue: stage tile 0
    #pragma unroll
    for (int tl = 0; tl < 4; ++tl) {
        int g = tid + tl * 256, row = g >> 4, grp = g & 15;
        *(uint4*)&Kc8[row][grp * 16] =
            *(const uint4*)&zmat8[((size_t)(bh * T_) + row) * M_ + grp * 16];
    }
    #pragma unroll
    for (int tl = 0; tl < 2; ++tl) {
        int g = tid + tl * 256, row = g >> 3, grp = g & 7;
        *(s8*)&Ksf[row][grp * 8] =
            *(const s8*)&qkv_x[(size_t)(b * T_ + row) * C3_ + C_ + h * HD_ + grp * 8];
        *(s8*)&Vb[row][grp * 8] = *(const s8*)&vTx[(size_t)(bh * 64 + row) * T_ + grp * 8];
    }
    __syncthreads();

    for (int st = 0; st < nst; ++st) {
        const int s0 = st * 64;
        const bool pf = (st + 1) < nst;
        uint4 kcp[4];
        s8 ksp[2], vp[2];
        if (pf) {
            const int sn = s0 + 64;
            #pragma unroll
            for (int tl = 0; tl < 4; ++tl) {
                int g = tid + tl * 256, row = g >> 4, grp = g & 15;
                kcp[tl] = *(const uint4*)&zmat8[((size_t)(bh * T_) + sn + row) * M_ + grp * 16];
            }
            #pragma unroll
            for (int tl = 0; tl < 2; ++tl) {
                int g = tid + tl * 256, row = g >> 3, grp = g & 7;
                ksp[tl] = *(const s8*)&qkv_x[(size_t)(b * T_ + sn + row) * C3_ + C_ + h * HD_ + grp * 8];
                vp[tl] = *(const s8*)&vTx[(size_t)(bh * 64 + row) * T_ + sn + grp * 8];
            }
        }
        // per-key chain scale: rowsum(s) / (16 * 128^2)
        float rsf[4];
        #pragma unroll
        for (int nt = 0; nt < 4; ++nt)
            rsf[nt] = rowsum_[bh * T_ + s0 + nt * 16 + l16] * (1.f / 262144.f);
        // chain QK^T (fp8)
        f4 sc[4];
        #pragma unroll
        for (int nt = 0; nt < 4; ++nt) sc[nt] = (f4)0.f;
        #pragma unroll
        for (int f = 0; f < 8; ++f)
            #pragma unroll
            for (int nt = 0; nt < 4; ++nt) {
                long bv = *(const long*)&Kc8[nt * 16 + l16][f * 32 + quad * 8];
                sc[nt] = MFMA8(qc[f], bv, sc[nt]);
            }
        // self QK^T (bf16)
        f4 ss[4];
        #pragma unroll
        for (int nt = 0; nt < 4; ++nt) ss[nt] = (f4)0.f;
        #pragma unroll
        for (int f = 0; f < 2; ++f)
            #pragma unroll
            for (int nt = 0; nt < 4; ++nt) {
                s8 bv = *(const s8*)&Ksf[nt * 16 + l16][f * 32 + quad * 8];
                ss[nt] = MFMA16(qs[f], bv, ss[nt]);
            }
        // chain softmax -> Ps, PV
        #pragma unroll
        for (int reg = 0; reg < 4; ++reg) {
            const int t_g = t0 + wave * 16 + quad * 4 + reg;
            #pragma unroll
            for (int nt = 0; nt < 4; ++nt) {
                float p = (s0 + nt * 16 + l16 <= t_g) ? __expf(sc[nt][reg] * rsf[nt]) : 0.f;
                lc[reg] += p;
                Ps[wave][quad * 4 + reg][nt * 16 + l16] = bfs(p);
            }
        }
        #pragma unroll
        for (int ks = 0; ks < 2; ++ks) {
            const short* pp = &Ps[wave][l16][ks * 32 + quad * 8];
            s4v alo = *(const s4v*)pp;
            s4v ahi = *(const s4v*)(pp + 4);
            s8 a;
            a[0] = alo[0]; a[1] = alo[1]; a[2] = alo[2]; a[3] = alo[3];
            a[4] = ahi[0]; a[5] = ahi[1]; a[6] = ahi[2]; a[7] = ahi[3];
            #pragma unroll
            for (int dt = 0; dt < 4; ++dt) {
                s8 bv = *(const s8*)&Vb[dt * 16 + l16][ks * 32 + quad * 8];
                oc[dt] = MFMA16(a, bv, oc[dt]);
            }
        }
        // self softmax -> Ps, PV
        #pragma unroll
        for (int reg = 0; reg < 4; ++reg) {
            const int t_g = t0 + wave * 16 + quad * 4 + reg;
            #pragma unroll
            for (int nt = 0; nt < 4; ++nt) {
                float p = (s0 + nt * 16 + l16 <= t_g) ? __expf(ss[nt][reg] * 0.125f) : 0.f;
                ls_[reg] += p;
                Ps[wave][quad * 4 + reg][nt * 16 + l16] = bfs(p);
            }
        }
        #pragma unroll
        for (int ks = 0; ks < 2; ++ks) {
            const short* pp = &Ps[wave][l16][ks * 32 + quad * 8];
            s4v alo = *(const s4v*)pp;
            s4v ahi = *(const s4v*)(pp + 4);
            s8 a;
            a[0] = alo[0]; a[1] = alo[1]; a[2] = alo[2]; a[3] = alo[3];
            a[4] = ahi[0]; a[5] = ahi[1]; a[6] = ahi[2]; a[7] = ahi[3];
            #pragma unroll
            for (int dt = 0; dt < 4; ++dt) {
                s8 bv = *(const s8*)&Vb[dt * 16 + l16][ks * 32 + quad * 8];
                os_[dt] = MFMA16(a, bv, os_[dt]);
            }
        }
        __syncthreads();
        if (pf) {
            #pragma unroll
            for (int tl = 0; tl < 4; ++tl) {
                int g = tid + tl * 256, row = g >> 4, grp = g & 15;
                *(uint4*)&Kc8[row][grp * 16] = kcp[tl];
            }
            #pragma unroll
            for (int tl = 0; tl < 2; ++tl) {
                int g = tid + tl * 256, row = g >> 3, grp = g & 7;
                *(s8*)&Ksf[row][grp * 8] = ksp[tl];
                *(s8*)&Vb[row][grp * 8] = vp[tl];
            }
        }
        __syncthreads();
    }

    #pragma unroll
    for (int reg = 0; reg < 4; ++reg) {
        float l1 = lc[reg], l2 = ls_[reg];
        l1 += __shfl_xor(l1, 1); l1 += __shfl_xor(l1, 2);
        l1 += __shfl_xor(l1, 4); l1 += __shfl_xor(l1, 8);
        l2 += __shfl_xor(l2, 1); l2 += __shfl_xor(l2, 2);
        l2 += __shfl_xor(l2, 4); l2 += __shfl_xor(l2, 8);
        const float i1 = 1.f / l1, i2 = 1.f / l2;
        const int t = t0 + wave * 16 + quad * 4 + reg;
        #pragma unroll
        for (int dt = 0; dt < 4; ++dt) {
            size_t idx = (size_t)(b * T_ + t) * C_ + h * HD_ + dt * 16 + l16;
            float cv = ocv[dt][reg] + oc[dt][reg] * i1 + x[idx];
            cval[idx] = cv;
            cval_bf[idx] = __float2bfloat16(cv);
            float sv = os_[dt][reg] * i2;
            sval[idx] = sv;
            sval_bf[idx] = __float2bfloat16(sv);
        }
    }
}

// ---------------- fused dual gate GEMM + sigmoid + combine ----------------
__global__ __launch_bounds__(256) void gatefuse_kernel(
    const bf16* __restrict__ svalb, const bf16* __restrict__ cvalb,
    const bf16* __restrict__ WTgs, const bf16* __restrict__ WTgc,
    const float* __restrict__ bgs, const float* __restrict__ bgc,
    const float* __restrict__ cval, const float* __restrict__ sval,
    bf16* __restrict__ gated)
{
    __shared__ short Sb[128][72], Cb[128][72], W1b[64][72], W2b[64][72];
    const int tid = threadIdx.x;
    const int wave = tid >> 6, lane = tid & 63;
    const int quad = lane >> 4, l16 = lane & 15;
    const int n0 = blockIdx.x * 64, m0 = blockIdx.y * 128;
    f4 aS[2][4], aC[2][4];
    #pragma unroll
    for (int mt = 0; mt < 2; ++mt)
        #pragma unroll
        for (int nt = 0; nt < 4; ++nt) { aS[mt][nt] = (f4)0.f; aC[mt][nt] = (f4)0.f; }

    for (int k0 = 0; k0 < C_; k0 += 64) {
        #pragma unroll
        for (int tl = 0; tl < 4; ++tl) {
            int g = tid + tl * 256, row = g >> 3, grp = g & 7;
            *(s8*)&Sb[row][grp * 8] = *(const s8*)&svalb[(size_t)(m0 + row) * C_ + k0 + grp * 8];
            *(s8*)&Cb[row][grp * 8] = *(const s8*)&cvalb[(size_t)(m0 + row) * C_ + k0 + grp * 8];
        }
        #pragma unroll
        for (int tl = 0; tl < 2; ++tl) {
            int g = tid + tl * 256, n = g >> 3, grp = g & 7;
            *(s8*)&W1b[n][grp * 8] = *(const s8*)&WTgs[(size_t)(n0 + n) * C_ + k0 + grp * 8];
            *(s8*)&W2b[n][grp * 8] = *(const s8*)&WTgc[(size_t)(n0 + n) * C_ + k0 + grp * 8];
        }
        __syncthreads();
        #pragma unroll
        for (int ks = 0; ks < 2; ++ks) {
            s8 s0f = *(const s8*)&Sb[wave * 32 + l16][ks * 32 + quad * 8];
            s8 s1f = *(const s8*)&Sb[wave * 32 + 16 + l16][ks * 32 + quad * 8];
            s8 c0f = *(const s8*)&Cb[wave * 32 + l16][ks * 32 + quad * 8];
            s8 c1f = *(const s8*)&Cb[wave * 32 + 16 + l16][ks * 32 + quad * 8];
            #pragma unroll
            for (int nt = 0; nt < 4; ++nt) {
                s8 w1 = *(const s8*)&W1b[nt * 16 + l16][ks * 32 + quad * 8];
                s8 w2 = *(const s8*)&W2b[nt * 16 + l16][ks * 32 + quad * 8];
                aS[0][nt] = MFMA16(s0f, w1, aS[0][nt]);
                aS[1][nt] = MFMA16(s1f, w1, aS[1][nt]);
                aC[0][nt] = MFMA16(c0f, w2, aC[0][nt]);
                aC[1][nt] = MFMA16(c1f, w2, aC[1][nt]);
            }
        }
        __syncthreads();
    }
    #pragma unroll
    for (int mt = 0; mt < 2; ++mt)
        #pragma unroll
        for (int nt = 0; nt < 4; ++nt) {
            int col = n0 + nt * 16 + l16;
            float b1 = bgs[col], b2 = bgc[col];
            #pragma unroll
            for (int reg = 0; reg < 4; ++reg) {
                int row = m0 + wave * 32 + mt * 16 + quad * 4 + reg;
                size_t idx = (size_t)row * C_ + col;
                float gs = 1.f / (1.f + __expf(-(aS[mt][nt][reg] + b1)));
                float gc = 1.f / (1.f + __expf(-(aC[mt][nt][reg] + b2)));
                gated[idx] = __float2bfloat16(gs * cval[idx] + gc * sval[idx]);
            }
        }
}

extern "C" void kernel_launch(void* const* d_in, const int* in_sizes, int n_in,
                              void* d_out, int out_size, void* d_ws, size_t ws_size,
                              hipStream_t stream)
{
    const float* x      = (const float*)d_in[0];
    const float* y      = (const float*)d_in[1];
    // d_in[2]: attn_x_mask — structurally causal tril, computed inline
    const float* Wqkv_x = (const float*)d_in[3];
    const float* bqkv_x = (const float*)d_in[4];
    const float* Wqkv_y = (const float*)d_in[5];
    const float* bqkv_y = (const float*)d_in[6];
    const float* w4x    = (const float*)d_in[7];
    const float* w4y    = (const float*)d_in[8];
    const float* w4xy   = (const float*)d_in[9];
    const float* Wgs    = (const float*)d_in[10];
    const float* bgs    = (const float*)d_in[11];
    const float* Wgc    = (const float*)d_in[12];
    const float* bgc    = (const float*)d_in[13];
    const float* Wp     = (const float*)d_in[14];
    const float* bp     = (const float*)d_in[15];

    // Workspace (f-word offsets; 114.1 MB, R10-proven footprint)
    float* ws = (float*)d_ws;
    bf16*  qkv_x_bf = (bf16*)(ws + 0);           // 6,291,456 bf16
    bf16*  qkv_y_bf = (bf16*)(ws + 3145728);     // 1,572,864 bf16
    float* catt     = ws + 3932160;              // 8,388,608 f (dead after rowsoft)
    bf16*  gated_bf = (bf16*)(ws + 3932160);     //   reuse
    bf16*  cval_bf  = (bf16*)(ws + 5242880);     //   reuse
    bf16*  x2y_bf   = (bf16*)(ws + 12320768);    // 8,388,608 bf16 (rowsoft)
    bf16*  x_bf     = x2y_bf;                    //   pre-QKV reuse
    bf16*  y_bf     = (bf16*)(ws + 13369344);    //   pre-QKV reuse
    unsigned char* zmat8 = (unsigned char*)(ws + 16515072); // 8,388,608 B fp8 (rowsoft)
    bf16*  vTx_bf   = (bf16*)(ws + 20709376);    // 2,097,152 bf16
    bf16*  vTy_bf   = (bf16*)(ws + 21757952);    // 524,288 bf16
    float* cval     = ws + 22020096;             // 2,097,152 f
    float* psum_    = cval;                      //   pre-cval reuse (catt3 colsums)
    float* sval     = ws + 24117248;             // 2,097,152 f
    bf16*  qw_bf    = (bf16*)(ws + 26214400);    // 2,097,152 bf16 (dead after catt3)
    bf16*  sval_bf  = qw_bf;                     //   reuse
    bf16*  WT_x     = (bf16*)(ws + 27262976);
    bf16*  WT_y     = (bf16*)(ws + 27656192);
    bf16*  WT_gs    = (bf16*)(ws + 28049408);
    bf16*  WT_gc    = (bf16*)(ws + 28180480);
    bf16*  WT_p     = (bf16*)(ws + 28311552);
    float* catt1b   = ws + 28442624;             // 32,768 f
    float* catt2b   = ws + 28475392;             //  8,192 f
    float* colinv   = ws + 28483584;             //  8,192 f
    float* rowsum_  = ws + 28491776;             // 32,768 f

    // 0: prep
    prep_kernel<<<1856, 256, 0, stream>>>(
        Wqkv_x, Wqkv_y, Wgs, Wgc, Wp, x, y,
        WT_x, WT_y, WT_gs, WT_gc, WT_p, x_bf, y_bf);

    // 1-2: QKV projections
    gemm_staged_kernel<bf16><<<dim3(24, 32), 256, 0, stream>>>(x_bf, WT_x, bqkv_x, qkv_x_bf, C3_, C_);
    gemm_staged_kernel<bf16><<<dim3(24, 8), 256, 0, stream>>>(y_bf, WT_y, bqkv_y, qkv_y_bf, C3_, C_);

    // 3-5: attention logits (+ fused column sums)
    catt12m_kernel<<<160, 256, 0, stream>>>(qkv_x_bf, qkv_y_bf, w4x, w4y, catt1b, catt2b);
    qw_kernel<<<1024, 256, 0, stream>>>(qkv_x_bf, w4xy, qw_bf);
    catt3_kernel<<<dim3(4, 16, 32), 256, 0, stream>>>(qw_bf, qkv_y_bf, catt1b, catt2b, catt, psum_);

    // 6-7: softmaxes
    colfin_kernel<<<32, 256, 0, stream>>>(psum_, colinv);
    rowsoft_kernel<<<8192, 256, 0, stream>>>(catt, colinv, x2y_bf, zmat8, rowsum_);

    // 8: V transposes
    vtransm_kernel<<<640, 256, 0, stream>>>(qkv_x_bf, qkv_y_bf, vTx_bf, vTy_bf);

    // 9: merged flash (fp8 chain) — cval = x + x2y@v_y + chain; sval = self
    flash4_kernel<<<dim3(16, 32), 256, 0, stream>>>(
        zmat8, x2y_bf, vTx_bf, vTy_bf, qkv_x_bf, x, rowsum_,
        cval, cval_bf, sval, sval_bf);

    // 10: fused gates
    gatefuse_kernel<<<dim3(8, 32), 256, 0, stream>>>(
        sval_bf, cval_bf, WT_gs, WT_gc, bgs, bgc, cval, sval, gated_bf);

    // 11: out = gated @ Wp + bp
    gemm_staged_kernel<float><<<dim3(8, 32), 256, 0, stream>>>(
        gated_bf, WT_p, bp, (float*)d_out, C_, C_);
}

// Round 13
// 262.842 us; speedup vs baseline: 1.1280x; 1.1148x over previous
//
#include <hip/hip_runtime.h>
#include <hip/hip_bf16.h>

typedef __hip_bfloat16 bf16;
using f4 = __attribute__((ext_vector_type(4))) float;
using s8 = __attribute__((ext_vector_type(8))) short;
using s4 = __attribute__((ext_vector_type(4))) short;

__device__ __forceinline__ void storeOut(float* p, float v) { *p = v; }
__device__ __forceinline__ void storeOut(bf16* p, float v) { *p = __float2bfloat16(v); }
__device__ __forceinline__ short bfs(float x) { return __builtin_bit_cast(short, __float2bfloat16(x)); }

constexpr int B_ = 4, T_ = 1024, M_ = 256, C_ = 512, H_ = 8, HD_ = 64, C3_ = 1536;

#define MFMA16(a, b, c) __builtin_amdgcn_mfma_f32_16x16x32_bf16((a), (b), (c), 0, 0, 0)

// ---------------- prep: 5 weight transposes (fp32 KxN -> bf16 NxK) + 2 converts ----------------
__global__ __launch_bounds__(256) void prep_kernel(
    const float* __restrict__ Wqkv_x, const float* __restrict__ Wqkv_y,
    const float* __restrict__ Wgs, const float* __restrict__ Wgc, const float* __restrict__ Wp,
    const float* __restrict__ x, const float* __restrict__ y,
    bf16* __restrict__ WT_x, bf16* __restrict__ WT_y, bf16* __restrict__ WT_gs,
    bf16* __restrict__ WT_gc, bf16* __restrict__ WT_p,
    bf16* __restrict__ x_bf, bf16* __restrict__ y_bf)
{
    __shared__ float Ls[64][65];
    const int tid = threadIdx.x;
    const int bid = blockIdx.x;
    if (bid < 576) {
        const float* W; bf16* WT; int N, t;
        if (bid < 192)      { W = Wqkv_x; WT = WT_x;  N = C3_; t = bid; }
        else if (bid < 384) { W = Wqkv_y; WT = WT_y;  N = C3_; t = bid - 192; }
        else if (bid < 448) { W = Wgs;    WT = WT_gs; N = C_;  t = bid - 384; }
        else if (bid < 512) { W = Wgc;    WT = WT_gc; N = C_;  t = bid - 448; }
        else                { W = Wp;     WT = WT_p;  N = C_;  t = bid - 512; }
        const int K = C_;
        const int tw = N >> 6;
        const int n0 = (t % tw) * 64, k0 = (t / tw) * 64;
        for (int i = tid; i < 1024; i += 256) {
            int kr = i >> 4, ng = i & 15;
            float4 v = *(const float4*)&W[(size_t)(k0 + kr) * N + n0 + ng * 4];
            Ls[ng * 4 + 0][kr] = v.x; Ls[ng * 4 + 1][kr] = v.y;
            Ls[ng * 4 + 2][kr] = v.z; Ls[ng * 4 + 3][kr] = v.w;
        }
        __syncthreads();
        for (int i = tid; i < 512; i += 256) {
            int n = i >> 3, kg = i & 7;
            s8 r;
            #pragma unroll
            for (int j = 0; j < 8; ++j) r[j] = bfs(Ls[n][kg * 8 + j]);
            *(s8*)&WT[(size_t)(n0 + n) * K + k0 + kg * 8] = r;
        }
    } else if (bid < 1600) {
        int i = (bid - 576) * 2048 + tid * 8;
        s8 r;
        #pragma unroll
        for (int j = 0; j < 8; ++j) r[j] = bfs(x[i + j]);
        *(s8*)&x_bf[i] = r;
    } else {
        int i = (bid - 1600) * 2048 + tid * 8;
        s8 r;
        #pragma unroll
        for (int j = 0; j < 8; ++j) r[j] = bfs(y[i + j]);
        *(s8*)&y_bf[i] = r;
    }
}

// ---------------- qw = bf16(q_x * w4xy), layout (B*T, C) ----------------
__global__ __launch_bounds__(256) void qw_kernel(
    const bf16* __restrict__ qkv_x, const float* __restrict__ w4xy, bf16* __restrict__ qw)
{
    int o = (blockIdx.x * 256 + threadIdx.x) * 8;
    int row = o >> 9, c = o & 511;
    const bf16* src = qkv_x + (size_t)row * C3_ + c;
    s8 r;
    #pragma unroll
    for (int j = 0; j < 8; ++j) r[j] = bfs(__bfloat162float(src[j]) * w4xy[c + j]);
    *(s8*)&qw[o] = r;
}

// ---------------- LDS-staged MFMA GEMM: C = A(MxK bf16) @ WT^T + bias ----------------
template <typename OT>
__global__ __launch_bounds__(256) void gemm_staged_kernel(
    const bf16* __restrict__ A, const bf16* __restrict__ WT, const float* __restrict__ bias,
    OT* __restrict__ Cmat, int N, int K)
{
    __shared__ short Asb[128][72];
    __shared__ short Bsb[64][72];
    const int tid = threadIdx.x;
    const int wave = tid >> 6, lane = tid & 63;
    const int quad = lane >> 4, l16 = lane & 15;
    const int n0 = blockIdx.x * 64, m0 = blockIdx.y * 128;
    f4 acc[2][4];
    #pragma unroll
    for (int mt = 0; mt < 2; ++mt)
        #pragma unroll
        for (int nt = 0; nt < 4; ++nt) acc[mt][nt] = (f4)0.f;

    for (int k0 = 0; k0 < K; k0 += 64) {
        #pragma unroll
        for (int tl = 0; tl < 4; ++tl) {
            int g = tid + tl * 256, row = g >> 3, grp = g & 7;
            *(s8*)&Asb[row][grp * 8] = *(const s8*)&A[(size_t)(m0 + row) * K + k0 + grp * 8];
        }
        #pragma unroll
        for (int tl = 0; tl < 2; ++tl) {
            int g = tid + tl * 256, n = g >> 3, grp = g & 7;
            *(s8*)&Bsb[n][grp * 8] = *(const s8*)&WT[(size_t)(n0 + n) * K + k0 + grp * 8];
        }
        __syncthreads();
        #pragma unroll
        for (int ks = 0; ks < 2; ++ks) {
            s8 a0 = *(const s8*)&Asb[wave * 32 + l16][ks * 32 + quad * 8];
            s8 a1 = *(const s8*)&Asb[wave * 32 + 16 + l16][ks * 32 + quad * 8];
            #pragma unroll
            for (int nt = 0; nt < 4; ++nt) {
                s8 bv = *(const s8*)&Bsb[nt * 16 + l16][ks * 32 + quad * 8];
                acc[0][nt] = MFMA16(a0, bv, acc[0][nt]);
                acc[1][nt] = MFMA16(a1, bv, acc[1][nt]);
            }
        }
        __syncthreads();
    }
    #pragma unroll
    for (int mt = 0; mt < 2; ++mt)
        #pragma unroll
        for (int nt = 0; nt < 4; ++nt) {
            int col = n0 + nt * 16 + l16;
            float bb = bias[col];
            #pragma unroll
            for (int reg = 0; reg < 4; ++reg) {
                int row = m0 + wave * 32 + mt * 16 + quad * 4 + reg;
                storeOut(&Cmat[(size_t)row * N + col], acc[mt][nt][reg] + bb);
            }
        }
}

// ---------------- merged catt1/catt2 ----------------
__global__ __launch_bounds__(256) void catt12m_kernel(
    const bf16* __restrict__ qkv_x, const bf16* __restrict__ qkv_y,
    const float* __restrict__ w4x, const float* __restrict__ w4y,
    float* __restrict__ catt1b, float* __restrict__ catt2b)
{
    int i = blockIdx.x * 256 + threadIdx.x;   // 0..40959
    const bf16* row; const float* w; float* out; int oi;
    if (i < 32768) {
        int bh = i >> 10, t = i & 1023, b = bh >> 3, h = bh & 7;
        row = qkv_x + (size_t)(b * T_ + t) * C3_ + h * HD_;
        w = w4x + h * HD_; out = catt1b; oi = i;
    } else {
        int j = i - 32768;
        int bh = j >> 8, m = j & 255, b = bh >> 3, h = bh & 7;
        row = qkv_y + (size_t)(b * M_ + m) * C3_ + h * HD_;
        w = w4y + h * HD_; out = catt2b; oi = j;
    }
    float s = 0.f;
    #pragma unroll
    for (int d = 0; d < HD_; ++d) s = fmaf(__bfloat162float(row[d]), w[d], s);
    out[oi] = s;
}

// ---------------- catt3: logits + FUSED column partial sums (proven in R11) ----------------
__global__ __launch_bounds__(256) void catt3_kernel(
    const bf16* __restrict__ qw, const bf16* __restrict__ qkv_y,
    const float* __restrict__ catt1, const float* __restrict__ catt2,
    float* __restrict__ catt, float* __restrict__ psum)
{
    __shared__ float redc[4][64];
    const int tid = threadIdx.x;
    const int wave = tid >> 6, lane = tid & 63;
    const int quad = lane >> 4, l16 = lane & 15;
    const int bh = blockIdx.z, b = bh >> 3, h = bh & 7;
    const int t0 = blockIdx.y * 64, m0 = blockIdx.x * 64;
    f4 sc[4];
    #pragma unroll
    for (int nt = 0; nt < 4; ++nt) sc[nt] = (f4)0.f;
    const bf16* ap = qw + (size_t)(b * T_ + t0 + wave * 16 + l16) * C_ + h * HD_ + quad * 8;
    const bf16* bp = qkv_y + (size_t)(b * M_ + m0 + l16) * C3_ + C_ + h * HD_ + quad * 8;
    #pragma unroll
    for (int k0 = 0; k0 < 64; k0 += 32) {
        s8 a = *(const s8*)(ap + k0);
        #pragma unroll
        for (int nt = 0; nt < 4; ++nt) {
            s8 bv = *(const s8*)(bp + (size_t)nt * 16 * C3_ + k0);
            sc[nt] = MFMA16(a, bv, sc[nt]);
        }
    }
    float csloc[4];
    #pragma unroll
    for (int nt = 0; nt < 4; ++nt) {
        int m = m0 + nt * 16 + l16;
        float c2 = catt2[bh * M_ + m];
        float es = 0.f;
        #pragma unroll
        for (int reg = 0; reg < 4; ++reg) {
            int t = t0 + wave * 16 + quad * 4 + reg;
            float v = sc[nt][reg] * 0.125f + catt1[bh * T_ + t] + c2;
            catt[((size_t)bh * T_ + t) * M_ + m] = v;
            es += __expf(v);
        }
        es += __shfl_xor(es, 16);
        es += __shfl_xor(es, 32);
        csloc[nt] = es;
    }
    if (quad == 0) {
        #pragma unroll
        for (int nt = 0; nt < 4; ++nt) redc[wave][nt * 16 + l16] = csloc[nt];
    }
    __syncthreads();
    if (tid < 64) {
        float s = redc[0][tid] + redc[1][tid] + redc[2][tid] + redc[3][tid];
        psum[((size_t)bh * 16 + (t0 >> 6)) * M_ + m0 + tid] = s;
    }
}

// ---------------- colfin: 16 chunk partials -> colinv ----------------
__global__ __launch_bounds__(256) void colfin_kernel(
    const float* __restrict__ psum, float* __restrict__ colinv)
{
    const int bh = blockIdx.x, m = threadIdx.x;
    float s = 0.f;
    #pragma unroll
    for (int ch = 0; ch < 16; ++ch) s += psum[(bh * 16 + ch) * M_ + m];
    colinv[bh * M_ + m] = 1.f / s;
}

// ---------------- fused row softmax -> x2y bf16 AND y2x bf16 ----------------
__global__ __launch_bounds__(256) void rowsoft_kernel(
    const float* __restrict__ catt, const float* __restrict__ colinv,
    bf16* __restrict__ x2y, bf16* __restrict__ y2x)
{
    const int wave = threadIdx.x >> 6, lane = threadIdx.x & 63;
    const int row = blockIdx.x * 4 + wave;
    const int bh = row >> 10;
    const float* p = catt + (size_t)row * M_;
    float e[4];
    float s = 0.f;
    #pragma unroll
    for (int j = 0; j < 4; ++j) { e[j] = __expf(p[j * 64 + lane]); s += e[j]; }
    for (int off = 1; off < 64; off <<= 1) s += __shfl_xor(s, off);
    float inv = 1.f / s;
    #pragma unroll
    for (int j = 0; j < 4; ++j) {
        int m = j * 64 + lane;
        x2y[(size_t)row * M_ + m] = __float2bfloat16(e[j] * inv);
        y2x[(size_t)row * M_ + m] = __float2bfloat16(e[j] * colinv[bh * M_ + m]);
    }
}

// ---------------- merged V transposes: v_x -> vTx, v_y -> vTy ----------------
__global__ __launch_bounds__(256) void vtransm_kernel(
    const bf16* __restrict__ qkv_x, const bf16* __restrict__ qkv_y,
    bf16* __restrict__ vTx, bf16* __restrict__ vTy)
{
    __shared__ short Ls[64][68];
    const int tid = threadIdx.x;
    int bid = blockIdx.x;
    const bf16* qkv; bf16* vT; int Nrows, bh, t0;
    if (bid < 512) { qkv = qkv_x; vT = vTx; Nrows = T_; bh = bid >> 4; t0 = (bid & 15) * 64; }
    else { bid -= 512; qkv = qkv_y; vT = vTy; Nrows = M_; bh = bid >> 2; t0 = (bid & 3) * 64; }
    const int b = bh >> 3, h = bh & 7;
    for (int i = tid; i < 4096; i += 256) {
        int tl = i >> 6, d = i & 63;
        Ls[d][tl] = __builtin_bit_cast(short,
            qkv[(size_t)(b * Nrows + t0 + tl) * C3_ + 2 * C_ + h * HD_ + d]);
    }
    __syncthreads();
    for (int i = tid; i < 4096; i += 256) {
        int d = i >> 6, tl = i & 63;
        vT[((size_t)bh * 64 + d) * Nrows + t0 + tl] = __builtin_bit_cast(bf16, Ls[d][tl]);
    }
}

// ---------------- merged flash: chain + self attention + fused cval (R9-proven) ----------------
__global__ __launch_bounds__(256) void flash3_kernel(
    const bf16* __restrict__ x2y, const bf16* __restrict__ y2x,
    const bf16* __restrict__ vTx, const bf16* __restrict__ vTy,
    const bf16* __restrict__ qkv_x, const float* __restrict__ x,
    float* __restrict__ cval, bf16* __restrict__ cval_bf,
    float* __restrict__ sval, bf16* __restrict__ sval_bf)
{
    __shared__ short Kc[64][264];     // chain K (64 keys x 256)
    __shared__ short Ksf[64][72];     // self K (64 keys x 64)
    __shared__ short Vb[64][72];      // V^T (64 d x 64 s)
    __shared__ short Ps[4][16][68];   // wave-private P
    const int tid = threadIdx.x;
    const int wave = tid >> 6, lane = tid & 63;
    const int quad = lane >> 4, l16 = lane & 15;
    const int bh = blockIdx.y, b = bh >> 3, h = bh & 7;
    const int jt = (blockIdx.y < 16) ? (int)blockIdx.x : 15 - (int)blockIdx.x;
    const int t0 = jt * 64;
    const int nst = jt + 1;

    // Q fragments in registers
    s8 qc[8], qs[2];
    {
        const bf16* qp = x2y + (size_t)(bh * T_ + t0 + wave * 16 + l16) * M_ + quad * 8;
        #pragma unroll
        for (int f = 0; f < 8; ++f) qc[f] = *(const s8*)(qp + f * 32);
        const bf16* qsp = qkv_x + (size_t)(b * T_ + t0 + wave * 16 + l16) * C3_ + h * HD_ + quad * 8;
        qs[0] = *(const s8*)qsp;
        qs[1] = *(const s8*)(qsp + 32);
    }

    // fused cval: ocv = x2y(regs) @ vTy
    f4 ocv[4];
    #pragma unroll
    for (int dt = 0; dt < 4; ++dt) ocv[dt] = (f4)0.f;
    {
        const bf16* vb = vTy + (size_t)(bh * 64 + l16) * M_ + quad * 8;
        #pragma unroll
        for (int f = 0; f < 8; ++f)
            #pragma unroll
            for (int dt = 0; dt < 4; ++dt) {
                s8 bv = *(const s8*)(vb + (size_t)dt * 16 * M_ + f * 32);
                ocv[dt] = MFMA16(qc[f], bv, ocv[dt]);
            }
    }

    f4 oc[4], os_[4];
    float lc[4] = {0.f, 0.f, 0.f, 0.f}, ls_[4] = {0.f, 0.f, 0.f, 0.f};
    #pragma unroll
    for (int dt = 0; dt < 4; ++dt) { oc[dt] = (f4)0.f; os_[dt] = (f4)0.f; }

    // prologue: stage tile 0
    #pragma unroll
    for (int tl = 0; tl < 8; ++tl) {
        int g = tid + tl * 256, row = g >> 5, grp = g & 31;
        *(s8*)&Kc[row][grp * 8] = *(const s8*)&y2x[(size_t)(bh * T_ + row) * M_ + grp * 8];
    }
    #pragma unroll
    for (int tl = 0; tl < 2; ++tl) {
        int g = tid + tl * 256, row = g >> 3, grp = g & 7;
        *(s8*)&Ksf[row][grp * 8] =
            *(const s8*)&qkv_x[(size_t)(b * T_ + row) * C3_ + C_ + h * HD_ + grp * 8];
        *(s8*)&Vb[row][grp * 8] = *(const s8*)&vTx[(size_t)(bh * 64 + row) * T_ + grp * 8];
    }
    __syncthreads();

    for (int st = 0; st < nst; ++st) {
        const int s0 = st * 64;
        const bool pf = (st + 1) < nst;
        s8 kcp[8], ksp[2], vp[2];
        if (pf) {
            const int sn = s0 + 64;
            #pragma unroll
            for (int tl = 0; tl < 8; ++tl) {
                int g = tid + tl * 256, row = g >> 5, grp = g & 31;
                kcp[tl] = *(const s8*)&y2x[(size_t)(bh * T_ + sn + row) * M_ + grp * 8];
            }
            #pragma unroll
            for (int tl = 0; tl < 2; ++tl) {
                int g = tid + tl * 256, row = g >> 3, grp = g & 7;
                ksp[tl] = *(const s8*)&qkv_x[(size_t)(b * T_ + sn + row) * C3_ + C_ + h * HD_ + grp * 8];
                vp[tl] = *(const s8*)&vTx[(size_t)(bh * 64 + row) * T_ + sn + grp * 8];
            }
        }
        // chain QK^T
        f4 sc[4];
        #pragma unroll
        for (int nt = 0; nt < 4; ++nt) sc[nt] = (f4)0.f;
        #pragma unroll
        for (int f = 0; f < 8; ++f)
            #pragma unroll
            for (int nt = 0; nt < 4; ++nt) {
                s8 bv = *(const s8*)&Kc[nt * 16 + l16][f * 32 + quad * 8];
                sc[nt] = MFMA16(qc[f], bv, sc[nt]);
            }
        // self QK^T
        f4 ss[4];
        #pragma unroll
        for (int nt = 0; nt < 4; ++nt) ss[nt] = (f4)0.f;
        #pragma unroll
        for (int f = 0; f < 2; ++f)
            #pragma unroll
            for (int nt = 0; nt < 4; ++nt) {
                s8 bv = *(const s8*)&Ksf[nt * 16 + l16][f * 32 + quad * 8];
                ss[nt] = MFMA16(qs[f], bv, ss[nt]);
            }
        // chain softmax -> Ps, PV
        #pragma unroll
        for (int reg = 0; reg < 4; ++reg) {
            const int t_g = t0 + wave * 16 + quad * 4 + reg;
            #pragma unroll
            for (int nt = 0; nt < 4; ++nt) {
                float p = (s0 + nt * 16 + l16 <= t_g) ? __expf(sc[nt][reg] * (1.f / 16.f)) : 0.f;
                lc[reg] += p;
                Ps[wave][quad * 4 + reg][nt * 16 + l16] = bfs(p);
            }
        }
        #pragma unroll
        for (int ks = 0; ks < 2; ++ks) {
            const short* pp = &Ps[wave][l16][ks * 32 + quad * 8];
            s4 alo = *(const s4*)pp;
            s4 ahi = *(const s4*)(pp + 4);
            s8 a;
            a[0] = alo[0]; a[1] = alo[1]; a[2] = alo[2]; a[3] = alo[3];
            a[4] = ahi[0]; a[5] = ahi[1]; a[6] = ahi[2]; a[7] = ahi[3];
            #pragma unroll
            for (int dt = 0; dt < 4; ++dt) {
                s8 bv = *(const s8*)&Vb[dt * 16 + l16][ks * 32 + quad * 8];
                oc[dt] = MFMA16(a, bv, oc[dt]);
            }
        }
        // self softmax -> Ps (overwrite; wave-private ordering), PV
        #pragma unroll
        for (int reg = 0; reg < 4; ++reg) {
            const int t_g = t0 + wave * 16 + quad * 4 + reg;
            #pragma unroll
            for (int nt = 0; nt < 4; ++nt) {
                float p = (s0 + nt * 16 + l16 <= t_g) ? __expf(ss[nt][reg] * 0.125f) : 0.f;
                ls_[reg] += p;
                Ps[wave][quad * 4 + reg][nt * 16 + l16] = bfs(p);
            }
        }
        #pragma unroll
        for (int ks = 0; ks < 2; ++ks) {
            const short* pp = &Ps[wave][l16][ks * 32 + quad * 8];
            s4 alo = *(const s4*)pp;
            s4 ahi = *(const s4*)(pp + 4);
            s8 a;
            a[0] = alo[0]; a[1] = alo[1]; a[2] = alo[2]; a[3] = alo[3];
            a[4] = ahi[0]; a[5] = ahi[1]; a[6] = ahi[2]; a[7] = ahi[3];
            #pragma unroll
            for (int dt = 0; dt < 4; ++dt) {
                s8 bv = *(const s8*)&Vb[dt * 16 + l16][ks * 32 + quad * 8];
                os_[dt] = MFMA16(a, bv, os_[dt]);
            }
        }
        __syncthreads();   // all waves done reading Kc/Ksf/Vb
        if (pf) {
            #pragma unroll
            for (int tl = 0; tl < 8; ++tl) {
                int g = tid + tl * 256, row = g >> 5, grp = g & 31;
                *(s8*)&Kc[row][grp * 8] = kcp[tl];
            }
            #pragma unroll
            for (int tl = 0; tl < 2; ++tl) {
                int g = tid + tl * 256, row = g >> 3, grp = g & 7;
                *(s8*)&Ksf[row][grp * 8] = ksp[tl];
                *(s8*)&Vb[row][grp * 8] = vp[tl];
            }
        }
        __syncthreads();   // new tile visible
    }

    #pragma unroll
    for (int reg = 0; reg < 4; ++reg) {
        float l1 = lc[reg], l2 = ls_[reg];
        l1 += __shfl_xor(l1, 1); l1 += __shfl_xor(l1, 2);
        l1 += __shfl_xor(l1, 4); l1 += __shfl_xor(l1, 8);
        l2 += __shfl_xor(l2, 1); l2 += __shfl_xor(l2, 2);
        l2 += __shfl_xor(l2, 4); l2 += __shfl_xor(l2, 8);
        const float i1 = 1.f / l1, i2 = 1.f / l2;
        const int t = t0 + wave * 16 + quad * 4 + reg;
        #pragma unroll
        for (int dt = 0; dt < 4; ++dt) {
            size_t idx = (size_t)(b * T_ + t) * C_ + h * HD_ + dt * 16 + l16;
            float cv = ocv[dt][reg] + oc[dt][reg] * i1 + x[idx];
            cval[idx] = cv;
            cval_bf[idx] = __float2bfloat16(cv);
            float sv = os_[dt][reg] * i2;
            sval[idx] = sv;
            sval_bf[idx] = __float2bfloat16(sv);
        }
    }
}

// ---------------- fused dual gate GEMM + sigmoid + combine -> gated bf16 ----------------
__global__ __launch_bounds__(256) void gatefuse_kernel(
    const bf16* __restrict__ svalb, const bf16* __restrict__ cvalb,
    const bf16* __restrict__ WTgs, const bf16* __restrict__ WTgc,
    const float* __restrict__ bgs, const float* __restrict__ bgc,
    const float* __restrict__ cval, const float* __restrict__ sval,
    bf16* __restrict__ gated)
{
    __shared__ short Sb[128][72], Cb[128][72], W1b[64][72], W2b[64][72];
    const int tid = threadIdx.x;
    const int wave = tid >> 6, lane = tid & 63;
    const int quad = lane >> 4, l16 = lane & 15;
    const int n0 = blockIdx.x * 64, m0 = blockIdx.y * 128;
    f4 aS[2][4], aC[2][4];
    #pragma unroll
    for (int mt = 0; mt < 2; ++mt)
        #pragma unroll
        for (int nt = 0; nt < 4; ++nt) { aS[mt][nt] = (f4)0.f; aC[mt][nt] = (f4)0.f; }

    for (int k0 = 0; k0 < C_; k0 += 64) {
        #pragma unroll
        for (int tl = 0; tl < 4; ++tl) {
            int g = tid + tl * 256, row = g >> 3, grp = g & 7;
            *(s8*)&Sb[row][grp * 8] = *(const s8*)&svalb[(size_t)(m0 + row) * C_ + k0 + grp * 8];
            *(s8*)&Cb[row][grp * 8] = *(const s8*)&cvalb[(size_t)(m0 + row) * C_ + k0 + grp * 8];
        }
        #pragma unroll
        for (int tl = 0; tl < 2; ++tl) {
            int g = tid + tl * 256, n = g >> 3, grp = g & 7;
            *(s8*)&W1b[n][grp * 8] = *(const s8*)&WTgs[(size_t)(n0 + n) * C_ + k0 + grp * 8];
            *(s8*)&W2b[n][grp * 8] = *(const s8*)&WTgc[(size_t)(n0 + n) * C_ + k0 + grp * 8];
        }
        __syncthreads();
        #pragma unroll
        for (int ks = 0; ks < 2; ++ks) {
            s8 s0f = *(const s8*)&Sb[wave * 32 + l16][ks * 32 + quad * 8];
            s8 s1f = *(const s8*)&Sb[wave * 32 + 16 + l16][ks * 32 + quad * 8];
            s8 c0f = *(const s8*)&Cb[wave * 32 + l16][ks * 32 + quad * 8];
            s8 c1f = *(const s8*)&Cb[wave * 32 + 16 + l16][ks * 32 + quad * 8];
            #pragma unroll
            for (int nt = 0; nt < 4; ++nt) {
                s8 w1 = *(const s8*)&W1b[nt * 16 + l16][ks * 32 + quad * 8];
                s8 w2 = *(const s8*)&W2b[nt * 16 + l16][ks * 32 + quad * 8];
                aS[0][nt] = MFMA16(s0f, w1, aS[0][nt]);
                aS[1][nt] = MFMA16(s1f, w1, aS[1][nt]);
                aC[0][nt] = MFMA16(c0f, w2, aC[0][nt]);
                aC[1][nt] = MFMA16(c1f, w2, aC[1][nt]);
            }
        }
        __syncthreads();
    }
    #pragma unroll
    for (int mt = 0; mt < 2; ++mt)
        #pragma unroll
        for (int nt = 0; nt < 4; ++nt) {
            int col = n0 + nt * 16 + l16;
            float b1 = bgs[col], b2 = bgc[col];
            #pragma unroll
            for (int reg = 0; reg < 4; ++reg) {
                int row = m0 + wave * 32 + mt * 16 + quad * 4 + reg;
                size_t idx = (size_t)row * C_ + col;
                float gs = 1.f / (1.f + __expf(-(aS[mt][nt][reg] + b1)));
                float gc = 1.f / (1.f + __expf(-(aC[mt][nt][reg] + b2)));
                gated[idx] = __float2bfloat16(gs * cval[idx] + gc * sval[idx]);
            }
        }
}

extern "C" void kernel_launch(void* const* d_in, const int* in_sizes, int n_in,
                              void* d_out, int out_size, void* d_ws, size_t ws_size,
                              hipStream_t stream)
{
    const float* x      = (const float*)d_in[0];
    const float* y      = (const float*)d_in[1];
    // d_in[2]: attn_x_mask — structurally causal tril, computed inline
    const float* Wqkv_x = (const float*)d_in[3];
    const float* bqkv_x = (const float*)d_in[4];
    const float* Wqkv_y = (const float*)d_in[5];
    const float* bqkv_y = (const float*)d_in[6];
    const float* w4x    = (const float*)d_in[7];
    const float* w4y    = (const float*)d_in[8];
    const float* w4xy   = (const float*)d_in[9];
    const float* Wgs    = (const float*)d_in[10];
    const float* bgs    = (const float*)d_in[11];
    const float* Wgc    = (const float*)d_in[12];
    const float* bgc    = (const float*)d_in[13];
    const float* Wp     = (const float*)d_in[14];
    const float* bp     = (const float*)d_in[15];

    // Workspace (f-word offsets; R9-proven layout)
    float* ws = (float*)d_ws;
    bf16*  qkv_x_bf = (bf16*)(ws + 0);           // 6,291,456 bf16
    bf16*  qkv_y_bf = (bf16*)(ws + 3145728);     // 1,572,864 bf16
    float* catt     = ws + 3932160;              // 8,388,608 f (dead after rowsoft)
    bf16*  gated_bf = (bf16*)(ws + 3932160);     //   reuse
    bf16*  cval_bf  = (bf16*)(ws + 5242880);     //   reuse
    bf16*  x2y_bf   = (bf16*)(ws + 12320768);    // 8,388,608 bf16 (written at rowsoft)
    bf16*  x_bf     = x2y_bf;                    //   pre-QKV reuse
    bf16*  y_bf     = (bf16*)(ws + 13369344);    //   pre-QKV reuse
    bf16*  y2x_bf   = (bf16*)(ws + 16515072);    // 8,388,608 bf16
    bf16*  vTx_bf   = (bf16*)(ws + 20709376);    // 2,097,152 bf16
    bf16*  vTy_bf   = (bf16*)(ws + 21757952);    // 524,288 bf16
    float* cval     = ws + 22020096;             // 2,097,152 f
    float* psum_    = cval;                      //   pre-cval reuse (catt3 colsums)
    float* sval     = ws + 24117248;             // 2,097,152 f
    bf16*  qw_bf    = (bf16*)(ws + 26214400);    // 2,097,152 bf16 (dead after catt3)
    bf16*  sval_bf  = qw_bf;                     //   reuse
    bf16*  WT_x     = (bf16*)(ws + 27262976);    // 786,432 bf16
    bf16*  WT_y     = (bf16*)(ws + 27656192);
    bf16*  WT_gs    = (bf16*)(ws + 28049408);    // 262,144 bf16
    bf16*  WT_gc    = (bf16*)(ws + 28180480);
    bf16*  WT_p     = (bf16*)(ws + 28311552);
    float* catt1b   = ws + 28442624;             // 32,768 f
    float* catt2b   = ws + 28475392;             //  8,192 f
    float* colinv   = ws + 28483584;             //  8,192 f

    // 0: one prep dispatch (5 transposes + 2 converts)
    prep_kernel<<<1856, 256, 0, stream>>>(
        Wqkv_x, Wqkv_y, Wgs, Wgc, Wp, x, y,
        WT_x, WT_y, WT_gs, WT_gc, WT_p, x_bf, y_bf);

    // 1-2: QKV projections
    gemm_staged_kernel<bf16><<<dim3(24, 32), 256, 0, stream>>>(x_bf, WT_x, bqkv_x, qkv_x_bf, C3_, C_);
    gemm_staged_kernel<bf16><<<dim3(24, 8), 256, 0, stream>>>(y_bf, WT_y, bqkv_y, qkv_y_bf, C3_, C_);

    // 3-5: attention logits (+ fused column sums)
    catt12m_kernel<<<160, 256, 0, stream>>>(qkv_x_bf, qkv_y_bf, w4x, w4y, catt1b, catt2b);
    qw_kernel<<<1024, 256, 0, stream>>>(qkv_x_bf, w4xy, qw_bf);
    catt3_kernel<<<dim3(4, 16, 32), 256, 0, stream>>>(qw_bf, qkv_y_bf, catt1b, catt2b, catt, psum_);

    // 6-7: softmaxes
    colfin_kernel<<<32, 256, 0, stream>>>(psum_, colinv);
    rowsoft_kernel<<<8192, 256, 0, stream>>>(catt, colinv, x2y_bf, y2x_bf);

    // 8: V transposes (one dispatch)
    vtransm_kernel<<<640, 256, 0, stream>>>(qkv_x_bf, qkv_y_bf, vTx_bf, vTy_bf);

    // 9: merged flash — cval = x + x2y@v_y + chain-attn; sval = self-attn
    flash3_kernel<<<dim3(16, 32), 256, 0, stream>>>(
        x2y_bf, y2x_bf, vTx_bf, vTy_bf, qkv_x_bf, x, cval, cval_bf, sval, sval_bf);

    // 10: fused gates -> gated bf16
    gatefuse_kernel<<<dim3(8, 32), 256, 0, stream>>>(
        sval_bf, cval_bf, WT_gs, WT_gc, bgs, bgc, cval, sval, gated_bf);

    // 11: out = gated @ Wp + bp
    gemm_staged_kernel<float><<<dim3(8, 32), 256, 0, stream>>>(
        gated_bf, WT_p, bp, (float*)d_out, C_, C_);
}

// Round 14
// 244.250 us; speedup vs baseline: 1.2139x; 1.0761x over previous
//
#include <hip/hip_runtime.h>
#include <hip/hip_bf16.h>

typedef __hip_bfloat16 bf16;
using f4 = __attribute__((ext_vector_type(4))) float;
using s8 = __attribute__((ext_vector_type(8))) short;
using s4 = __attribute__((ext_vector_type(4))) short;

__device__ __forceinline__ void storeOut(float* p, float v) { *p = v; }
__device__ __forceinline__ void storeOut(bf16* p, float v) { *p = __float2bfloat16(v); }
__device__ __forceinline__ short bfs(float x) { return __builtin_bit_cast(short, __float2bfloat16(x)); }

constexpr int B_ = 4, T_ = 1024, M_ = 256, C_ = 512, H_ = 8, HD_ = 64, C3_ = 1536;

#define MFMA16(a, b, c) __builtin_amdgcn_mfma_f32_16x16x32_bf16((a), (b), (c), 0, 0, 0)

// ---------------- prep: 5 weight transposes (fp32 KxN -> bf16 NxK) + 2 converts ----------------
__global__ __launch_bounds__(256) void prep_kernel(
    const float* __restrict__ Wqkv_x, const float* __restrict__ Wqkv_y,
    const float* __restrict__ Wgs, const float* __restrict__ Wgc, const float* __restrict__ Wp,
    const float* __restrict__ x, const float* __restrict__ y,
    bf16* __restrict__ WT_x, bf16* __restrict__ WT_y, bf16* __restrict__ WT_gs,
    bf16* __restrict__ WT_gc, bf16* __restrict__ WT_p,
    bf16* __restrict__ x_bf, bf16* __restrict__ y_bf)
{
    __shared__ float Ls[64][65];
    const int tid = threadIdx.x;
    const int bid = blockIdx.x;
    if (bid < 576) {
        const float* W; bf16* WT; int N, t;
        if (bid < 192)      { W = Wqkv_x; WT = WT_x;  N = C3_; t = bid; }
        else if (bid < 384) { W = Wqkv_y; WT = WT_y;  N = C3_; t = bid - 192; }
        else if (bid < 448) { W = Wgs;    WT = WT_gs; N = C_;  t = bid - 384; }
        else if (bid < 512) { W = Wgc;    WT = WT_gc; N = C_;  t = bid - 448; }
        else                { W = Wp;     WT = WT_p;  N = C_;  t = bid - 512; }
        const int K = C_;
        const int tw = N >> 6;
        const int n0 = (t % tw) * 64, k0 = (t / tw) * 64;
        for (int i = tid; i < 1024; i += 256) {
            int kr = i >> 4, ng = i & 15;
            float4 v = *(const float4*)&W[(size_t)(k0 + kr) * N + n0 + ng * 4];
            Ls[ng * 4 + 0][kr] = v.x; Ls[ng * 4 + 1][kr] = v.y;
            Ls[ng * 4 + 2][kr] = v.z; Ls[ng * 4 + 3][kr] = v.w;
        }
        __syncthreads();
        for (int i = tid; i < 512; i += 256) {
            int n = i >> 3, kg = i & 7;
            s8 r;
            #pragma unroll
            for (int j = 0; j < 8; ++j) r[j] = bfs(Ls[n][kg * 8 + j]);
            *(s8*)&WT[(size_t)(n0 + n) * K + k0 + kg * 8] = r;
        }
    } else if (bid < 1600) {
        int i = (bid - 576) * 2048 + tid * 8;
        s8 r;
        #pragma unroll
        for (int j = 0; j < 8; ++j) r[j] = bfs(x[i + j]);
        *(s8*)&x_bf[i] = r;
    } else {
        int i = (bid - 1600) * 2048 + tid * 8;
        s8 r;
        #pragma unroll
        for (int j = 0; j < 8; ++j) r[j] = bfs(y[i + j]);
        *(s8*)&y_bf[i] = r;
    }
}

// ---------------- qw = bf16(q_x * w4xy), layout (B*T, C) ----------------
__global__ __launch_bounds__(256) void qw_kernel(
    const bf16* __restrict__ qkv_x, const float* __restrict__ w4xy, bf16* __restrict__ qw)
{
    int o = (blockIdx.x * 256 + threadIdx.x) * 8;
    int row = o >> 9, c = o & 511;
    const bf16* src = qkv_x + (size_t)row * C3_ + c;
    s8 r;
    #pragma unroll
    for (int j = 0; j < 8; ++j) r[j] = bfs(__bfloat162float(src[j]) * w4xy[c + j]);
    *(s8*)&qw[o] = r;
}

// ---------------- LDS-staged MFMA GEMM: C = A(MxK bf16) @ WT^T + bias ----------------
template <typename OT>
__global__ __launch_bounds__(256) void gemm_staged_kernel(
    const bf16* __restrict__ A, const bf16* __restrict__ WT, const float* __restrict__ bias,
    OT* __restrict__ Cmat, int N, int K)
{
    __shared__ short Asb[128][72];
    __shared__ short Bsb[64][72];
    const int tid = threadIdx.x;
    const int wave = tid >> 6, lane = tid & 63;
    const int quad = lane >> 4, l16 = lane & 15;
    const int n0 = blockIdx.x * 64, m0 = blockIdx.y * 128;
    f4 acc[2][4];
    #pragma unroll
    for (int mt = 0; mt < 2; ++mt)
        #pragma unroll
        for (int nt = 0; nt < 4; ++nt) acc[mt][nt] = (f4)0.f;

    for (int k0 = 0; k0 < K; k0 += 64) {
        #pragma unroll
        for (int tl = 0; tl < 4; ++tl) {
            int g = tid + tl * 256, row = g >> 3, grp = g & 7;
            *(s8*)&Asb[row][grp * 8] = *(const s8*)&A[(size_t)(m0 + row) * K + k0 + grp * 8];
        }
        #pragma unroll
        for (int tl = 0; tl < 2; ++tl) {
            int g = tid + tl * 256, n = g >> 3, grp = g & 7;
            *(s8*)&Bsb[n][grp * 8] = *(const s8*)&WT[(size_t)(n0 + n) * K + k0 + grp * 8];
        }
        __syncthreads();
        #pragma unroll
        for (int ks = 0; ks < 2; ++ks) {
            s8 a0 = *(const s8*)&Asb[wave * 32 + l16][ks * 32 + quad * 8];
            s8 a1 = *(const s8*)&Asb[wave * 32 + 16 + l16][ks * 32 + quad * 8];
            #pragma unroll
            for (int nt = 0; nt < 4; ++nt) {
                s8 bv = *(const s8*)&Bsb[nt * 16 + l16][ks * 32 + quad * 8];
                acc[0][nt] = MFMA16(a0, bv, acc[0][nt]);
                acc[1][nt] = MFMA16(a1, bv, acc[1][nt]);
            }
        }
        __syncthreads();
    }
    #pragma unroll
    for (int mt = 0; mt < 2; ++mt)
        #pragma unroll
        for (int nt = 0; nt < 4; ++nt) {
            int col = n0 + nt * 16 + l16;
            float bb = bias[col];
            #pragma unroll
            for (int reg = 0; reg < 4; ++reg) {
                int row = m0 + wave * 32 + mt * 16 + quad * 4 + reg;
                storeOut(&Cmat[(size_t)row * N + col], acc[mt][nt][reg] + bb);
            }
        }
}

// ---------------- merged catt1/catt2 ----------------
__global__ __launch_bounds__(256) void catt12m_kernel(
    const bf16* __restrict__ qkv_x, const bf16* __restrict__ qkv_y,
    const float* __restrict__ w4x, const float* __restrict__ w4y,
    float* __restrict__ catt1b, float* __restrict__ catt2b)
{
    int i = blockIdx.x * 256 + threadIdx.x;   // 0..40959
    const bf16* row; const float* w; float* out; int oi;
    if (i < 32768) {
        int bh = i >> 10, t = i & 1023, b = bh >> 3, h = bh & 7;
        row = qkv_x + (size_t)(b * T_ + t) * C3_ + h * HD_;
        w = w4x + h * HD_; out = catt1b; oi = i;
    } else {
        int j = i - 32768;
        int bh = j >> 8, m = j & 255, b = bh >> 3, h = bh & 7;
        row = qkv_y + (size_t)(b * M_ + m) * C3_ + h * HD_;
        w = w4y + h * HD_; out = catt2b; oi = j;
    }
    float s = 0.f;
    #pragma unroll
    for (int d = 0; d < HD_; ++d) s = fmaf(__bfloat162float(row[d]), w[d], s);
    out[oi] = s;
}

// ---------------- catt3: logits + FUSED column partial sums ----------------
__global__ __launch_bounds__(256) void catt3_kernel(
    const bf16* __restrict__ qw, const bf16* __restrict__ qkv_y,
    const float* __restrict__ catt1, const float* __restrict__ catt2,
    float* __restrict__ catt, float* __restrict__ psum)
{
    __shared__ float redc[4][64];
    const int tid = threadIdx.x;
    const int wave = tid >> 6, lane = tid & 63;
    const int quad = lane >> 4, l16 = lane & 15;
    const int bh = blockIdx.z, b = bh >> 3, h = bh & 7;
    const int t0 = blockIdx.y * 64, m0 = blockIdx.x * 64;
    f4 sc[4];
    #pragma unroll
    for (int nt = 0; nt < 4; ++nt) sc[nt] = (f4)0.f;
    const bf16* ap = qw + (size_t)(b * T_ + t0 + wave * 16 + l16) * C_ + h * HD_ + quad * 8;
    const bf16* bp = qkv_y + (size_t)(b * M_ + m0 + l16) * C3_ + C_ + h * HD_ + quad * 8;
    #pragma unroll
    for (int k0 = 0; k0 < 64; k0 += 32) {
        s8 a = *(const s8*)(ap + k0);
        #pragma unroll
        for (int nt = 0; nt < 4; ++nt) {
            s8 bv = *(const s8*)(bp + (size_t)nt * 16 * C3_ + k0);
            sc[nt] = MFMA16(a, bv, sc[nt]);
        }
    }
    float csloc[4];
    #pragma unroll
    for (int nt = 0; nt < 4; ++nt) {
        int m = m0 + nt * 16 + l16;
        float c2 = catt2[bh * M_ + m];
        float es = 0.f;
        #pragma unroll
        for (int reg = 0; reg < 4; ++reg) {
            int t = t0 + wave * 16 + quad * 4 + reg;
            float v = sc[nt][reg] * 0.125f + catt1[bh * T_ + t] + c2;
            catt[((size_t)bh * T_ + t) * M_ + m] = v;
            es += __expf(v);
        }
        es += __shfl_xor(es, 16);
        es += __shfl_xor(es, 32);
        csloc[nt] = es;
    }
    if (quad == 0) {
        #pragma unroll
        for (int nt = 0; nt < 4; ++nt) redc[wave][nt * 16 + l16] = csloc[nt];
    }
    __syncthreads();
    if (tid < 64) {
        float s = redc[0][tid] + redc[1][tid] + redc[2][tid] + redc[3][tid];
        psum[((size_t)bh * 16 + (t0 >> 6)) * M_ + m0 + tid] = s;
    }
}

// ---------------- colfin: 16 chunk partials -> colinv ----------------
__global__ __launch_bounds__(256) void colfin_kernel(
    const float* __restrict__ psum, float* __restrict__ colinv)
{
    const int bh = blockIdx.x, m = threadIdx.x;
    float s = 0.f;
    #pragma unroll
    for (int ch = 0; ch < 16; ++ch) s += psum[(bh * 16 + ch) * M_ + m];
    colinv[bh * M_ + m] = 1.f / s;
}

// ---------------- fused row softmax -> x2y bf16 AND y2x bf16 ----------------
__global__ __launch_bounds__(256) void rowsoft_kernel(
    const float* __restrict__ catt, const float* __restrict__ colinv,
    bf16* __restrict__ x2y, bf16* __restrict__ y2x)
{
    const int wave = threadIdx.x >> 6, lane = threadIdx.x & 63;
    const int row = blockIdx.x * 4 + wave;
    const int bh = row >> 10;
    const float* p = catt + (size_t)row * M_;
    float e[4];
    float s = 0.f;
    #pragma unroll
    for (int j = 0; j < 4; ++j) { e[j] = __expf(p[j * 64 + lane]); s += e[j]; }
    for (int off = 1; off < 64; off <<= 1) s += __shfl_xor(s, off);
    float inv = 1.f / s;
    #pragma unroll
    for (int j = 0; j < 4; ++j) {
        int m = j * 64 + lane;
        x2y[(size_t)row * M_ + m] = __float2bfloat16(e[j] * inv);
        y2x[(size_t)row * M_ + m] = __float2bfloat16(e[j] * colinv[bh * M_ + m]);
    }
}

// ---------------- merged V transposes: v_x -> vTx, v_y -> vTy ----------------
__global__ __launch_bounds__(256) void vtransm_kernel(
    const bf16* __restrict__ qkv_x, const bf16* __restrict__ qkv_y,
    bf16* __restrict__ vTx, bf16* __restrict__ vTy)
{
    __shared__ short Ls[64][68];
    const int tid = threadIdx.x;
    int bid = blockIdx.x;
    const bf16* qkv; bf16* vT; int Nrows, bh, t0;
    if (bid < 512) { qkv = qkv_x; vT = vTx; Nrows = T_; bh = bid >> 4; t0 = (bid & 15) * 64; }
    else { bid -= 512; qkv = qkv_y; vT = vTy; Nrows = M_; bh = bid >> 2; t0 = (bid & 3) * 64; }
    const int b = bh >> 3, h = bh & 7;
    for (int i = tid; i < 4096; i += 256) {
        int tl = i >> 6, d = i & 63;
        Ls[d][tl] = __builtin_bit_cast(short,
            qkv[(size_t)(b * Nrows + t0 + tl) * C3_ + 2 * C_ + h * HD_ + d]);
    }
    __syncthreads();
    for (int i = tid; i < 4096; i += 256) {
        int d = i >> 6, tl = i & 63;
        vT[((size_t)bh * 64 + d) * Nrows + t0 + tl] = __builtin_bit_cast(bf16, Ls[d][tl]);
    }
}

// ---------------- flash6: paired-tile merged flash (512 threads, 8 waves) ----------------
// Block (p, bh) owns BOTH query tiles jt=p (waves 0-3) and jt=15-p (waves 4-7); the
// staged Kc/Ksf/Vb tiles are shared. Every block = exactly 68 wave-tile-units of MFMA
// work -> zero tail imbalance; grid 256 = 1 block/CU. Inactive waves (st > jt) skip
// compute behind a wave-uniform branch but join both barriers. Ps has 8 wave-private
// slots (R9/R13-proven intra-wave write->read ordering).
__global__ __launch_bounds__(512) void flash6_kernel(
    const bf16* __restrict__ x2y, const bf16* __restrict__ y2x,
    const bf16* __restrict__ vTx, const bf16* __restrict__ vTy,
    const bf16* __restrict__ qkv_x, const float* __restrict__ x,
    float* __restrict__ cval, bf16* __restrict__ cval_bf,
    float* __restrict__ sval, bf16* __restrict__ sval_bf)
{
    __shared__ short Kc[64][264];     // chain K (64 keys x 256)
    __shared__ short Ksf[64][72];     // self K (64 keys x 64)
    __shared__ short Vb[64][72];      // V^T (64 d x 64 s)
    __shared__ short Ps[8][16][68];   // wave-private P
    const int tid = threadIdx.x;
    const int wave = tid >> 6, lane = tid & 63;
    const int quad = lane >> 4, l16 = lane & 15;
    const int bh = blockIdx.y, b = bh >> 3, h = bh & 7;
    const int p = blockIdx.x;                    // pair id 0..7
    const int jt = (wave < 4) ? p : (15 - p);    // this wave's query tile
    const int rb = jt * 64 + (wave & 3) * 16;    // wave's 16-row base
    const int nst = 16 - p;                      // shared key-tile loop length

    // Q fragments in registers (wave's own rows)
    s8 qc[8], qs[2];
    {
        const bf16* qp = x2y + (size_t)(bh * T_ + rb + l16) * M_ + quad * 8;
        #pragma unroll
        for (int f = 0; f < 8; ++f) qc[f] = *(const s8*)(qp + f * 32);
        const bf16* qsp = qkv_x + (size_t)(b * T_ + rb + l16) * C3_ + h * HD_ + quad * 8;
        qs[0] = *(const s8*)qsp;
        qs[1] = *(const s8*)(qsp + 32);
    }

    // fused cval: ocv = x2y(regs) @ vTy
    f4 ocv[4];
    #pragma unroll
    for (int dt = 0; dt < 4; ++dt) ocv[dt] = (f4)0.f;
    {
        const bf16* vb = vTy + (size_t)(bh * 64 + l16) * M_ + quad * 8;
        #pragma unroll
        for (int f = 0; f < 8; ++f)
            #pragma unroll
            for (int dt = 0; dt < 4; ++dt) {
                s8 bv = *(const s8*)(vb + (size_t)dt * 16 * M_ + f * 32);
                ocv[dt] = MFMA16(qc[f], bv, ocv[dt]);
            }
    }

    f4 oc[4], os_[4];
    float lc[4] = {0.f, 0.f, 0.f, 0.f}, ls_[4] = {0.f, 0.f, 0.f, 0.f};
    #pragma unroll
    for (int dt = 0; dt < 4; ++dt) { oc[dt] = (f4)0.f; os_[dt] = (f4)0.f; }

    // prologue: stage tile 0 (512 threads)
    #pragma unroll
    for (int tl = 0; tl < 4; ++tl) {
        int g = tid + tl * 512, row = g >> 5, grp = g & 31;
        *(s8*)&Kc[row][grp * 8] = *(const s8*)&y2x[(size_t)(bh * T_ + row) * M_ + grp * 8];
    }
    {
        int row = tid >> 3, grp = tid & 7;
        *(s8*)&Ksf[row][grp * 8] =
            *(const s8*)&qkv_x[(size_t)(b * T_ + row) * C3_ + C_ + h * HD_ + grp * 8];
        *(s8*)&Vb[row][grp * 8] = *(const s8*)&vTx[(size_t)(bh * 64 + row) * T_ + grp * 8];
    }
    __syncthreads();

    for (int st = 0; st < nst; ++st) {
        const int s0 = st * 64;
        const bool pf = (st + 1) < nst;
        s8 kcp[4], ksp, vp;
        if (pf) {
            const int sn = s0 + 64;
            #pragma unroll
            for (int tl = 0; tl < 4; ++tl) {
                int g = tid + tl * 512, row = g >> 5, grp = g & 31;
                kcp[tl] = *(const s8*)&y2x[(size_t)(bh * T_ + sn + row) * M_ + grp * 8];
            }
            int row = tid >> 3, grp = tid & 7;
            ksp = *(const s8*)&qkv_x[(size_t)(b * T_ + sn + row) * C3_ + C_ + h * HD_ + grp * 8];
            vp = *(const s8*)&vTx[(size_t)(bh * 64 + row) * T_ + sn + grp * 8];
        }
        if (st <= jt) {   // wave-uniform: this wave's query tile needs this key tile
            // chain QK^T
            f4 sc[4];
            #pragma unroll
            for (int nt = 0; nt < 4; ++nt) sc[nt] = (f4)0.f;
            #pragma unroll
            for (int f = 0; f < 8; ++f)
                #pragma unroll
                for (int nt = 0; nt < 4; ++nt) {
                    s8 bv = *(const s8*)&Kc[nt * 16 + l16][f * 32 + quad * 8];
                    sc[nt] = MFMA16(qc[f], bv, sc[nt]);
                }
            // self QK^T
            f4 ss[4];
            #pragma unroll
            for (int nt = 0; nt < 4; ++nt) ss[nt] = (f4)0.f;
            #pragma unroll
            for (int f = 0; f < 2; ++f)
                #pragma unroll
                for (int nt = 0; nt < 4; ++nt) {
                    s8 bv = *(const s8*)&Ksf[nt * 16 + l16][f * 32 + quad * 8];
                    ss[nt] = MFMA16(qs[f], bv, ss[nt]);
                }
            // chain softmax -> Ps, PV
            #pragma unroll
            for (int reg = 0; reg < 4; ++reg) {
                const int t_g = rb + quad * 4 + reg;
                #pragma unroll
                for (int nt = 0; nt < 4; ++nt) {
                    float pv = (s0 + nt * 16 + l16 <= t_g) ? __expf(sc[nt][reg] * (1.f / 16.f)) : 0.f;
                    lc[reg] += pv;
                    Ps[wave][quad * 4 + reg][nt * 16 + l16] = bfs(pv);
                }
            }
            #pragma unroll
            for (int ks = 0; ks < 2; ++ks) {
                const short* pp = &Ps[wave][l16][ks * 32 + quad * 8];
                s4 alo = *(const s4*)pp;
                s4 ahi = *(const s4*)(pp + 4);
                s8 a;
                a[0] = alo[0]; a[1] = alo[1]; a[2] = alo[2]; a[3] = alo[3];
                a[4] = ahi[0]; a[5] = ahi[1]; a[6] = ahi[2]; a[7] = ahi[3];
                #pragma unroll
                for (int dt = 0; dt < 4; ++dt) {
                    s8 bv = *(const s8*)&Vb[dt * 16 + l16][ks * 32 + quad * 8];
                    oc[dt] = MFMA16(a, bv, oc[dt]);
                }
            }
            // self softmax -> Ps (overwrite; wave-private ordering), PV
            #pragma unroll
            for (int reg = 0; reg < 4; ++reg) {
                const int t_g = rb + quad * 4 + reg;
                #pragma unroll
                for (int nt = 0; nt < 4; ++nt) {
                    float pv = (s0 + nt * 16 + l16 <= t_g) ? __expf(ss[nt][reg] * 0.125f) : 0.f;
                    ls_[reg] += pv;
                    Ps[wave][quad * 4 + reg][nt * 16 + l16] = bfs(pv);
                }
            }
            #pragma unroll
            for (int ks = 0; ks < 2; ++ks) {
                const short* pp = &Ps[wave][l16][ks * 32 + quad * 8];
                s4 alo = *(const s4*)pp;
                s4 ahi = *(const s4*)(pp + 4);
                s8 a;
                a[0] = alo[0]; a[1] = alo[1]; a[2] = alo[2]; a[3] = alo[3];
                a[4] = ahi[0]; a[5] = ahi[1]; a[6] = ahi[2]; a[7] = ahi[3];
                #pragma unroll
                for (int dt = 0; dt < 4; ++dt) {
                    s8 bv = *(const s8*)&Vb[dt * 16 + l16][ks * 32 + quad * 8];
                    os_[dt] = MFMA16(a, bv, os_[dt]);
                }
            }
        }
        __syncthreads();   // all waves done reading Kc/Ksf/Vb
        if (pf) {
            #pragma unroll
            for (int tl = 0; tl < 4; ++tl) {
                int g = tid + tl * 512, row = g >> 5, grp = g & 31;
                *(s8*)&Kc[row][grp * 8] = kcp[tl];
            }
            int row = tid >> 3, grp = tid & 7;
            *(s8*)&Ksf[row][grp * 8] = ksp;
            *(s8*)&Vb[row][grp * 8] = vp;
        }
        __syncthreads();   // new tile visible
    }

    #pragma unroll
    for (int reg = 0; reg < 4; ++reg) {
        float l1 = lc[reg], l2 = ls_[reg];
        l1 += __shfl_xor(l1, 1); l1 += __shfl_xor(l1, 2);
        l1 += __shfl_xor(l1, 4); l1 += __shfl_xor(l1, 8);
        l2 += __shfl_xor(l2, 1); l2 += __shfl_xor(l2, 2);
        l2 += __shfl_xor(l2, 4); l2 += __shfl_xor(l2, 8);
        const float i1 = 1.f / l1, i2 = 1.f / l2;
        const int t = rb + quad * 4 + reg;
        #pragma unroll
        for (int dt = 0; dt < 4; ++dt) {
            size_t idx = (size_t)(b * T_ + t) * C_ + h * HD_ + dt * 16 + l16;
            float cv = ocv[dt][reg] + oc[dt][reg] * i1 + x[idx];
            cval[idx] = cv;
            cval_bf[idx] = __float2bfloat16(cv);
            float sv = os_[dt][reg] * i2;
            sval[idx] = sv;
            sval_bf[idx] = __float2bfloat16(sv);
        }
    }
}

// ---------------- fused dual gate GEMM + sigmoid + combine -> gated bf16 ----------------
__global__ __launch_bounds__(256) void gatefuse_kernel(
    const bf16* __restrict__ svalb, const bf16* __restrict__ cvalb,
    const bf16* __restrict__ WTgs, const bf16* __restrict__ WTgc,
    const float* __restrict__ bgs, const float* __restrict__ bgc,
    const float* __restrict__ cval, const float* __restrict__ sval,
    bf16* __restrict__ gated)
{
    __shared__ short Sb[128][72], Cb[128][72], W1b[64][72], W2b[64][72];
    const int tid = threadIdx.x;
    const int wave = tid >> 6, lane = tid & 63;
    const int quad = lane >> 4, l16 = lane & 15;
    const int n0 = blockIdx.x * 64, m0 = blockIdx.y * 128;
    f4 aS[2][4], aC[2][4];
    #pragma unroll
    for (int mt = 0; mt < 2; ++mt)
        #pragma unroll
        for (int nt = 0; nt < 4; ++nt) { aS[mt][nt] = (f4)0.f; aC[mt][nt] = (f4)0.f; }

    for (int k0 = 0; k0 < C_; k0 += 64) {
        #pragma unroll
        for (int tl = 0; tl < 4; ++tl) {
            int g = tid + tl * 256, row = g >> 3, grp = g & 7;
            *(s8*)&Sb[row][grp * 8] = *(const s8*)&svalb[(size_t)(m0 + row) * C_ + k0 + grp * 8];
            *(s8*)&Cb[row][grp * 8] = *(const s8*)&cvalb[(size_t)(m0 + row) * C_ + k0 + grp * 8];
        }
        #pragma unroll
        for (int tl = 0; tl < 2; ++tl) {
            int g = tid + tl * 256, n = g >> 3, grp = g & 7;
            *(s8*)&W1b[n][grp * 8] = *(const s8*)&WTgs[(size_t)(n0 + n) * C_ + k0 + grp * 8];
            *(s8*)&W2b[n][grp * 8] = *(const s8*)&WTgc[(size_t)(n0 + n) * C_ + k0 + grp * 8];
        }
        __syncthreads();
        #pragma unroll
        for (int ks = 0; ks < 2; ++ks) {
            s8 s0f = *(const s8*)&Sb[wave * 32 + l16][ks * 32 + quad * 8];
            s8 s1f = *(const s8*)&Sb[wave * 32 + 16 + l16][ks * 32 + quad * 8];
            s8 c0f = *(const s8*)&Cb[wave * 32 + l16][ks * 32 + quad * 8];
            s8 c1f = *(const s8*)&Cb[wave * 32 + 16 + l16][ks * 32 + quad * 8];
            #pragma unroll
            for (int nt = 0; nt < 4; ++nt) {
                s8 w1 = *(const s8*)&W1b[nt * 16 + l16][ks * 32 + quad * 8];
                s8 w2 = *(const s8*)&W2b[nt * 16 + l16][ks * 32 + quad * 8];
                aS[0][nt] = MFMA16(s0f, w1, aS[0][nt]);
                aS[1][nt] = MFMA16(s1f, w1, aS[1][nt]);
                aC[0][nt] = MFMA16(c0f, w2, aC[0][nt]);
                aC[1][nt] = MFMA16(c1f, w2, aC[1][nt]);
            }
        }
        __syncthreads();
    }
    #pragma unroll
    for (int mt = 0; mt < 2; ++mt)
        #pragma unroll
        for (int nt = 0; nt < 4; ++nt) {
            int col = n0 + nt * 16 + l16;
            float b1 = bgs[col], b2 = bgc[col];
            #pragma unroll
            for (int reg = 0; reg < 4; ++reg) {
                int row = m0 + wave * 32 + mt * 16 + quad * 4 + reg;
                size_t idx = (size_t)row * C_ + col;
                float gs = 1.f / (1.f + __expf(-(aS[mt][nt][reg] + b1)));
                float gc = 1.f / (1.f + __expf(-(aC[mt][nt][reg] + b2)));
                gated[idx] = __float2bfloat16(gs * cval[idx] + gc * sval[idx]);
            }
        }
}

extern "C" void kernel_launch(void* const* d_in, const int* in_sizes, int n_in,
                              void* d_out, int out_size, void* d_ws, size_t ws_size,
                              hipStream_t stream)
{
    const float* x      = (const float*)d_in[0];
    const float* y      = (const float*)d_in[1];
    // d_in[2]: attn_x_mask — structurally causal tril, computed inline
    const float* Wqkv_x = (const float*)d_in[3];
    const float* bqkv_x = (const float*)d_in[4];
    const float* Wqkv_y = (const float*)d_in[5];
    const float* bqkv_y = (const float*)d_in[6];
    const float* w4x    = (const float*)d_in[7];
    const float* w4y    = (const float*)d_in[8];
    const float* w4xy   = (const float*)d_in[9];
    const float* Wgs    = (const float*)d_in[10];
    const float* bgs    = (const float*)d_in[11];
    const float* Wgc    = (const float*)d_in[12];
    const float* bgc    = (const float*)d_in[13];
    const float* Wp     = (const float*)d_in[14];
    const float* bp     = (const float*)d_in[15];

    // Workspace (f-word offsets; R9/R13-proven layout)
    float* ws = (float*)d_ws;
    bf16*  qkv_x_bf = (bf16*)(ws + 0);           // 6,291,456 bf16
    bf16*  qkv_y_bf = (bf16*)(ws + 3145728);     // 1,572,864 bf16
    float* catt     = ws + 3932160;              // 8,388,608 f (dead after rowsoft)
    bf16*  gated_bf = (bf16*)(ws + 3932160);     //   reuse
    bf16*  cval_bf  = (bf16*)(ws + 5242880);     //   reuse
    bf16*  x2y_bf   = (bf16*)(ws + 12320768);    // 8,388,608 bf16 (written at rowsoft)
    bf16*  x_bf     = x2y_bf;                    //   pre-QKV reuse
    bf16*  y_bf     = (bf16*)(ws + 13369344);    //   pre-QKV reuse
    bf16*  y2x_bf   = (bf16*)(ws + 16515072);    // 8,388,608 bf16
    bf16*  vTx_bf   = (bf16*)(ws + 20709376);    // 2,097,152 bf16
    bf16*  vTy_bf   = (bf16*)(ws + 21757952);    // 524,288 bf16
    float* cval     = ws + 22020096;             // 2,097,152 f
    float* psum_    = cval;                      //   pre-cval reuse (catt3 colsums)
    float* sval     = ws + 24117248;             // 2,097,152 f
    bf16*  qw_bf    = (bf16*)(ws + 26214400);    // 2,097,152 bf16 (dead after catt3)
    bf16*  sval_bf  = qw_bf;                     //   reuse
    bf16*  WT_x     = (bf16*)(ws + 27262976);    // 786,432 bf16
    bf16*  WT_y     = (bf16*)(ws + 27656192);
    bf16*  WT_gs    = (bf16*)(ws + 28049408);    // 262,144 bf16
    bf16*  WT_gc    = (bf16*)(ws + 28180480);
    bf16*  WT_p     = (bf16*)(ws + 28311552);
    float* catt1b   = ws + 28442624;             // 32,768 f
    float* catt2b   = ws + 28475392;             //  8,192 f
    float* colinv   = ws + 28483584;             //  8,192 f

    // 0: one prep dispatch (5 transposes + 2 converts)
    prep_kernel<<<1856, 256, 0, stream>>>(
        Wqkv_x, Wqkv_y, Wgs, Wgc, Wp, x, y,
        WT_x, WT_y, WT_gs, WT_gc, WT_p, x_bf, y_bf);

    // 1-2: QKV projections
    gemm_staged_kernel<bf16><<<dim3(24, 32), 256, 0, stream>>>(x_bf, WT_x, bqkv_x, qkv_x_bf, C3_, C_);
    gemm_staged_kernel<bf16><<<dim3(24, 8), 256, 0, stream>>>(y_bf, WT_y, bqkv_y, qkv_y_bf, C3_, C_);

    // 3-5: attention logits (+ fused column sums)
    catt12m_kernel<<<160, 256, 0, stream>>>(qkv_x_bf, qkv_y_bf, w4x, w4y, catt1b, catt2b);
    qw_kernel<<<1024, 256, 0, stream>>>(qkv_x_bf, w4xy, qw_bf);
    catt3_kernel<<<dim3(4, 16, 32), 256, 0, stream>>>(qw_bf, qkv_y_bf, catt1b, catt2b, catt, psum_);

    // 6-7: softmaxes
    colfin_kernel<<<32, 256, 0, stream>>>(psum_, colinv);
    rowsoft_kernel<<<8192, 256, 0, stream>>>(catt, colinv, x2y_bf, y2x_bf);

    // 8: V transposes (one dispatch)
    vtransm_kernel<<<640, 256, 0, stream>>>(qkv_x_bf, qkv_y_bf, vTx_bf, vTy_bf);

    // 9: paired-tile merged flash — cval = x + x2y@v_y + chain-attn; sval = self-attn
    flash6_kernel<<<dim3(8, 32), 512, 0, stream>>>(
        x2y_bf, y2x_bf, vTx_bf, vTy_bf, qkv_x_bf, x, cval, cval_bf, sval, sval_bf);

    // 10: fused gates -> gated bf16
    gatefuse_kernel<<<dim3(8, 32), 256, 0, stream>>>(
        sval_bf, cval_bf, WT_gs, WT_gc, bgs, bgc, cval, sval, gated_bf);

    // 11: out = gated @ Wp + bp
    gemm_staged_kernel<float><<<dim3(8, 32), 256, 0, stream>>>(
        gated_bf, WT_p, bp, (float*)d_out, C_, C_);
}

// Round 15
// 241.284 us; speedup vs baseline: 1.2288x; 1.0123x over previous
//
#include <hip/hip_runtime.h>
#include <hip/hip_bf16.h>

typedef __hip_bfloat16 bf16;
using f4 = __attribute__((ext_vector_type(4))) float;
using s8 = __attribute__((ext_vector_type(8))) short;
using s4 = __attribute__((ext_vector_type(4))) short;

__device__ __forceinline__ void storeOut(float* p, float v) { *p = v; }
__device__ __forceinline__ void storeOut(bf16* p, float v) { *p = __float2bfloat16(v); }
__device__ __forceinline__ short bfs(float x) { return __builtin_bit_cast(short, __float2bfloat16(x)); }

constexpr int B_ = 4, T_ = 1024, M_ = 256, C_ = 512, H_ = 8, HD_ = 64, C3_ = 1536;

#define MFMA16(a, b, c) __builtin_amdgcn_mfma_f32_16x16x32_bf16((a), (b), (c), 0, 0, 0)

// ---------------- prep: 5 weight transposes (fp32 KxN -> bf16 NxK) + 2 converts ----------------
__global__ __launch_bounds__(256) void prep_kernel(
    const float* __restrict__ Wqkv_x, const float* __restrict__ Wqkv_y,
    const float* __restrict__ Wgs, const float* __restrict__ Wgc, const float* __restrict__ Wp,
    const float* __restrict__ x, const float* __restrict__ y,
    bf16* __restrict__ WT_x, bf16* __restrict__ WT_y, bf16* __restrict__ WT_gs,
    bf16* __restrict__ WT_gc, bf16* __restrict__ WT_p,
    bf16* __restrict__ x_bf, bf16* __restrict__ y_bf)
{
    __shared__ float Ls[64][65];
    const int tid = threadIdx.x;
    const int bid = blockIdx.x;
    if (bid < 576) {
        const float* W; bf16* WT; int N, t;
        if (bid < 192)      { W = Wqkv_x; WT = WT_x;  N = C3_; t = bid; }
        else if (bid < 384) { W = Wqkv_y; WT = WT_y;  N = C3_; t = bid - 192; }
        else if (bid < 448) { W = Wgs;    WT = WT_gs; N = C_;  t = bid - 384; }
        else if (bid < 512) { W = Wgc;    WT = WT_gc; N = C_;  t = bid - 448; }
        else                { W = Wp;     WT = WT_p;  N = C_;  t = bid - 512; }
        const int K = C_;
        const int tw = N >> 6;
        const int n0 = (t % tw) * 64, k0 = (t / tw) * 64;
        for (int i = tid; i < 1024; i += 256) {
            int kr = i >> 4, ng = i & 15;
            float4 v = *(const float4*)&W[(size_t)(k0 + kr) * N + n0 + ng * 4];
            Ls[ng * 4 + 0][kr] = v.x; Ls[ng * 4 + 1][kr] = v.y;
            Ls[ng * 4 + 2][kr] = v.z; Ls[ng * 4 + 3][kr] = v.w;
        }
        __syncthreads();
        for (int i = tid; i < 512; i += 256) {
            int n = i >> 3, kg = i & 7;
            s8 r;
            #pragma unroll
            for (int j = 0; j < 8; ++j) r[j] = bfs(Ls[n][kg * 8 + j]);
            *(s8*)&WT[(size_t)(n0 + n) * K + k0 + kg * 8] = r;
        }
    } else if (bid < 1600) {
        int i = (bid - 576) * 2048 + tid * 8;
        s8 r;
        #pragma unroll
        for (int j = 0; j < 8; ++j) r[j] = bfs(x[i + j]);
        *(s8*)&x_bf[i] = r;
    } else {
        int i = (bid - 1600) * 2048 + tid * 8;
        s8 r;
        #pragma unroll
        for (int j = 0; j < 8; ++j) r[j] = bfs(y[i + j]);
        *(s8*)&y_bf[i] = r;
    }
}

// ---------------- merged catt1/catt2 + qw (one dispatch; all elementwise over qkv) ----------------
__global__ __launch_bounds__(256) void qwcatt_kernel(
    const bf16* __restrict__ qkv_x, const bf16* __restrict__ qkv_y,
    const float* __restrict__ w4x, const float* __restrict__ w4y,
    const float* __restrict__ w4xy,
    float* __restrict__ catt1b, float* __restrict__ catt2b, bf16* __restrict__ qw)
{
    const int bid = blockIdx.x;
    const int tid = threadIdx.x;
    if (bid < 160) {
        int i = bid * 256 + tid;   // 0..40959
        const bf16* row; const float* w; float* out; int oi;
        if (i < 32768) {
            int bh = i >> 10, t = i & 1023, b = bh >> 3, h = bh & 7;
            row = qkv_x + (size_t)(b * T_ + t) * C3_ + h * HD_;
            w = w4x + h * HD_; out = catt1b; oi = i;
        } else {
            int j = i - 32768;
            int bh = j >> 8, m = j & 255, b = bh >> 3, h = bh & 7;
            row = qkv_y + (size_t)(b * M_ + m) * C3_ + h * HD_;
            w = w4y + h * HD_; out = catt2b; oi = j;
        }
        float s = 0.f;
        #pragma unroll
        for (int d = 0; d < HD_; ++d) s = fmaf(__bfloat162float(row[d]), w[d], s);
        out[oi] = s;
    } else {
        int o = ((bid - 160) * 256 + tid) * 8;
        int row = o >> 9, c = o & 511;
        const bf16* src = qkv_x + (size_t)row * C3_ + c;
        s8 r;
        #pragma unroll
        for (int j = 0; j < 8; ++j) r[j] = bfs(__bfloat162float(src[j]) * w4xy[c + j]);
        *(s8*)&qw[o] = r;
    }
}

// ---------------- LDS-staged MFMA GEMM: C = A(MxK bf16) @ WT^T + bias ----------------
template <typename OT>
__global__ __launch_bounds__(256) void gemm_staged_kernel(
    const bf16* __restrict__ A, const bf16* __restrict__ WT, const float* __restrict__ bias,
    OT* __restrict__ Cmat, int N, int K)
{
    __shared__ short Asb[128][72];
    __shared__ short Bsb[64][72];
    const int tid = threadIdx.x;
    const int wave = tid >> 6, lane = tid & 63;
    const int quad = lane >> 4, l16 = lane & 15;
    const int n0 = blockIdx.x * 64, m0 = blockIdx.y * 128;
    f4 acc[2][4];
    #pragma unroll
    for (int mt = 0; mt < 2; ++mt)
        #pragma unroll
        for (int nt = 0; nt < 4; ++nt) acc[mt][nt] = (f4)0.f;

    for (int k0 = 0; k0 < K; k0 += 64) {
        #pragma unroll
        for (int tl = 0; tl < 4; ++tl) {
            int g = tid + tl * 256, row = g >> 3, grp = g & 7;
            *(s8*)&Asb[row][grp * 8] = *(const s8*)&A[(size_t)(m0 + row) * K + k0 + grp * 8];
        }
        #pragma unroll
        for (int tl = 0; tl < 2; ++tl) {
            int g = tid + tl * 256, n = g >> 3, grp = g & 7;
            *(s8*)&Bsb[n][grp * 8] = *(const s8*)&WT[(size_t)(n0 + n) * K + k0 + grp * 8];
        }
        __syncthreads();
        #pragma unroll
        for (int ks = 0; ks < 2; ++ks) {
            s8 a0 = *(const s8*)&Asb[wave * 32 + l16][ks * 32 + quad * 8];
            s8 a1 = *(const s8*)&Asb[wave * 32 + 16 + l16][ks * 32 + quad * 8];
            #pragma unroll
            for (int nt = 0; nt < 4; ++nt) {
                s8 bv = *(const s8*)&Bsb[nt * 16 + l16][ks * 32 + quad * 8];
                acc[0][nt] = MFMA16(a0, bv, acc[0][nt]);
                acc[1][nt] = MFMA16(a1, bv, acc[1][nt]);
            }
        }
        __syncthreads();
    }
    #pragma unroll
    for (int mt = 0; mt < 2; ++mt)
        #pragma unroll
        for (int nt = 0; nt < 4; ++nt) {
            int col = n0 + nt * 16 + l16;
            float bb = bias[col];
            #pragma unroll
            for (int reg = 0; reg < 4; ++reg) {
                int row = m0 + wave * 32 + mt * 16 + quad * 4 + reg;
                storeOut(&Cmat[(size_t)row * N + col], acc[mt][nt][reg] + bb);
            }
        }
}

// ---------------- catt3: logits + FUSED column partial sums ----------------
__global__ __launch_bounds__(256) void catt3_kernel(
    const bf16* __restrict__ qw, const bf16* __restrict__ qkv_y,
    const float* __restrict__ catt1, const float* __restrict__ catt2,
    float* __restrict__ catt, float* __restrict__ psum)
{
    __shared__ float redc[4][64];
    const int tid = threadIdx.x;
    const int wave = tid >> 6, lane = tid & 63;
    const int quad = lane >> 4, l16 = lane & 15;
    const int bh = blockIdx.z, b = bh >> 3, h = bh & 7;
    const int t0 = blockIdx.y * 64, m0 = blockIdx.x * 64;
    f4 sc[4];
    #pragma unroll
    for (int nt = 0; nt < 4; ++nt) sc[nt] = (f4)0.f;
    const bf16* ap = qw + (size_t)(b * T_ + t0 + wave * 16 + l16) * C_ + h * HD_ + quad * 8;
    const bf16* bp = qkv_y + (size_t)(b * M_ + m0 + l16) * C3_ + C_ + h * HD_ + quad * 8;
    #pragma unroll
    for (int k0 = 0; k0 < 64; k0 += 32) {
        s8 a = *(const s8*)(ap + k0);
        #pragma unroll
        for (int nt = 0; nt < 4; ++nt) {
            s8 bv = *(const s8*)(bp + (size_t)nt * 16 * C3_ + k0);
            sc[nt] = MFMA16(a, bv, sc[nt]);
        }
    }
    float csloc[4];
    #pragma unroll
    for (int nt = 0; nt < 4; ++nt) {
        int m = m0 + nt * 16 + l16;
        float c2 = catt2[bh * M_ + m];
        float es = 0.f;
        #pragma unroll
        for (int reg = 0; reg < 4; ++reg) {
            int t = t0 + wave * 16 + quad * 4 + reg;
            float v = sc[nt][reg] * 0.125f + catt1[bh * T_ + t] + c2;
            catt[((size_t)bh * T_ + t) * M_ + m] = v;
            es += __expf(v);
        }
        es += __shfl_xor(es, 16);
        es += __shfl_xor(es, 32);
        csloc[nt] = es;
    }
    if (quad == 0) {
        #pragma unroll
        for (int nt = 0; nt < 4; ++nt) redc[wave][nt * 16 + l16] = csloc[nt];
    }
    __syncthreads();
    if (tid < 64) {
        float s = redc[0][tid] + redc[1][tid] + redc[2][tid] + redc[3][tid];
        psum[((size_t)bh * 16 + (t0 >> 6)) * M_ + m0 + tid] = s;
    }
}

// ---------------- colfin: 16 chunk partials -> colinv ----------------
__global__ __launch_bounds__(256) void colfin_kernel(
    const float* __restrict__ psum, float* __restrict__ colinv)
{
    const int bh = blockIdx.x, m = threadIdx.x;
    float s = 0.f;
    #pragma unroll
    for (int ch = 0; ch < 16; ++ch) s += psum[(bh * 16 + ch) * M_ + m];
    colinv[bh * M_ + m] = 1.f / s;
}

// ---------------- fused row softmax -> x2y bf16 AND y2x bf16 ----------------
__global__ __launch_bounds__(256) void rowsoft_kernel(
    const float* __restrict__ catt, const float* __restrict__ colinv,
    bf16* __restrict__ x2y, bf16* __restrict__ y2x)
{
    const int wave = threadIdx.x >> 6, lane = threadIdx.x & 63;
    const int row = blockIdx.x * 4 + wave;
    const int bh = row >> 10;
    const float* p = catt + (size_t)row * M_;
    float e[4];
    float s = 0.f;
    #pragma unroll
    for (int j = 0; j < 4; ++j) { e[j] = __expf(p[j * 64 + lane]); s += e[j]; }
    for (int off = 1; off < 64; off <<= 1) s += __shfl_xor(s, off);
    float inv = 1.f / s;
    #pragma unroll
    for (int j = 0; j < 4; ++j) {
        int m = j * 64 + lane;
        x2y[(size_t)row * M_ + m] = __float2bfloat16(e[j] * inv);
        y2x[(size_t)row * M_ + m] = __float2bfloat16(e[j] * colinv[bh * M_ + m]);
    }
}

// ---------------- merged V transposes: v_x -> vTx, v_y -> vTy ----------------
__global__ __launch_bounds__(256) void vtransm_kernel(
    const bf16* __restrict__ qkv_x, const bf16* __restrict__ qkv_y,
    bf16* __restrict__ vTx, bf16* __restrict__ vTy)
{
    __shared__ short Ls[64][68];
    const int tid = threadIdx.x;
    int bid = blockIdx.x;
    const bf16* qkv; bf16* vT; int Nrows, bh, t0;
    if (bid < 512) { qkv = qkv_x; vT = vTx; Nrows = T_; bh = bid >> 4; t0 = (bid & 15) * 64; }
    else { bid -= 512; qkv = qkv_y; vT = vTy; Nrows = M_; bh = bid >> 2; t0 = (bid & 3) * 64; }
    const int b = bh >> 3, h = bh & 7;
    for (int i = tid; i < 4096; i += 256) {
        int tl = i >> 6, d = i & 63;
        Ls[d][tl] = __builtin_bit_cast(short,
            qkv[(size_t)(b * Nrows + t0 + tl) * C3_ + 2 * C_ + h * HD_ + d]);
    }
    __syncthreads();
    for (int i = tid; i < 4096; i += 256) {
        int d = i >> 6, tl = i & 63;
        vT[((size_t)bh * 64 + d) * Nrows + t0 + tl] = __builtin_bit_cast(bf16, Ls[d][tl]);
    }
}

// ---------------- flash6: paired-tile merged flash (512 threads, 8 waves) ----------------
// R14-proven structure; grid TRANSPOSED to (bh, p) so the 8 same-bh blocks get linear
// ids bh+32p (equal mod 8) -> co-located on one XCD under round-robin dispatch; per-XCD
// y2x working set 4 bh x 524 KB ~ 2.1 MB fits the 4 MB L2 (kills the 6x HBM re-read).
__global__ __launch_bounds__(512) void flash6_kernel(
    const bf16* __restrict__ x2y, const bf16* __restrict__ y2x,
    const bf16* __restrict__ vTx, const bf16* __restrict__ vTy,
    const bf16* __restrict__ qkv_x, const float* __restrict__ x,
    float* __restrict__ cval, bf16* __restrict__ cval_bf,
    float* __restrict__ sval, bf16* __restrict__ sval_bf)
{
    __shared__ short Kc[64][264];     // chain K (64 keys x 256)
    __shared__ short Ksf[64][72];     // self K (64 keys x 64)
    __shared__ short Vb[64][72];      // V^T (64 d x 64 s)
    __shared__ short Ps[8][16][68];   // wave-private P
    const int tid = threadIdx.x;
    const int wave = tid >> 6, lane = tid & 63;
    const int quad = lane >> 4, l16 = lane & 15;
    const int bh = blockIdx.x, b = bh >> 3, h = bh & 7;   // x = bh (XCD swizzle)
    const int p = blockIdx.y;                    // pair id 0..7
    const int jt = (wave < 4) ? p : (15 - p);    // this wave's query tile
    const int rb = jt * 64 + (wave & 3) * 16;    // wave's 16-row base
    const int nst = 16 - p;                      // shared key-tile loop length

    // Q fragments in registers (wave's own rows)
    s8 qc[8], qs[2];
    {
        const bf16* qp = x2y + (size_t)(bh * T_ + rb + l16) * M_ + quad * 8;
        #pragma unroll
        for (int f = 0; f < 8; ++f) qc[f] = *(const s8*)(qp + f * 32);
        const bf16* qsp = qkv_x + (size_t)(b * T_ + rb + l16) * C3_ + h * HD_ + quad * 8;
        qs[0] = *(const s8*)qsp;
        qs[1] = *(const s8*)(qsp + 32);
    }

    // fused cval: ocv = x2y(regs) @ vTy
    f4 ocv[4];
    #pragma unroll
    for (int dt = 0; dt < 4; ++dt) ocv[dt] = (f4)0.f;
    {
        const bf16* vb = vTy + (size_t)(bh * 64 + l16) * M_ + quad * 8;
        #pragma unroll
        for (int f = 0; f < 8; ++f)
            #pragma unroll
            for (int dt = 0; dt < 4; ++dt) {
                s8 bv = *(const s8*)(vb + (size_t)dt * 16 * M_ + f * 32);
                ocv[dt] = MFMA16(qc[f], bv, ocv[dt]);
            }
    }

    f4 oc[4], os_[4];
    float lc[4] = {0.f, 0.f, 0.f, 0.f}, ls_[4] = {0.f, 0.f, 0.f, 0.f};
    #pragma unroll
    for (int dt = 0; dt < 4; ++dt) { oc[dt] = (f4)0.f; os_[dt] = (f4)0.f; }

    // prologue: stage tile 0 (512 threads)
    #pragma unroll
    for (int tl = 0; tl < 4; ++tl) {
        int g = tid + tl * 512, row = g >> 5, grp = g & 31;
        *(s8*)&Kc[row][grp * 8] = *(const s8*)&y2x[(size_t)(bh * T_ + row) * M_ + grp * 8];
    }
    {
        int row = tid >> 3, grp = tid & 7;
        *(s8*)&Ksf[row][grp * 8] =
            *(const s8*)&qkv_x[(size_t)(b * T_ + row) * C3_ + C_ + h * HD_ + grp * 8];
        *(s8*)&Vb[row][grp * 8] = *(const s8*)&vTx[(size_t)(bh * 64 + row) * T_ + grp * 8];
    }
    __syncthreads();

    for (int st = 0; st < nst; ++st) {
        const int s0 = st * 64;
        const bool pf = (st + 1) < nst;
        s8 kcp[4], ksp, vp;
        if (pf) {
            const int sn = s0 + 64;
            #pragma unroll
            for (int tl = 0; tl < 4; ++tl) {
                int g = tid + tl * 512, row = g >> 5, grp = g & 31;
                kcp[tl] = *(const s8*)&y2x[(size_t)(bh * T_ + sn + row) * M_ + grp * 8];
            }
            int row = tid >> 3, grp = tid & 7;
            ksp = *(const s8*)&qkv_x[(size_t)(b * T_ + sn + row) * C3_ + C_ + h * HD_ + grp * 8];
            vp = *(const s8*)&vTx[(size_t)(bh * 64 + row) * T_ + sn + grp * 8];
        }
        if (st <= jt) {   // wave-uniform: this wave's query tile needs this key tile
            // chain QK^T
            f4 sc[4];
            #pragma unroll
            for (int nt = 0; nt < 4; ++nt) sc[nt] = (f4)0.f;
            #pragma unroll
            for (int f = 0; f < 8; ++f)
                #pragma unroll
                for (int nt = 0; nt < 4; ++nt) {
                    s8 bv = *(const s8*)&Kc[nt * 16 + l16][f * 32 + quad * 8];
                    sc[nt] = MFMA16(qc[f], bv, sc[nt]);
                }
            // self QK^T
            f4 ss[4];
            #pragma unroll
            for (int nt = 0; nt < 4; ++nt) ss[nt] = (f4)0.f;
            #pragma unroll
            for (int f = 0; f < 2; ++f)
                #pragma unroll
                for (int nt = 0; nt < 4; ++nt) {
                    s8 bv = *(const s8*)&Ksf[nt * 16 + l16][f * 32 + quad * 8];
                    ss[nt] = MFMA16(qs[f], bv, ss[nt]);
                }
            // chain softmax -> Ps, PV
            #pragma unroll
            for (int reg = 0; reg < 4; ++reg) {
                const int t_g = rb + quad * 4 + reg;
                #pragma unroll
                for (int nt = 0; nt < 4; ++nt) {
                    float pv = (s0 + nt * 16 + l16 <= t_g) ? __expf(sc[nt][reg] * (1.f / 16.f)) : 0.f;
                    lc[reg] += pv;
                    Ps[wave][quad * 4 + reg][nt * 16 + l16] = bfs(pv);
                }
            }
            #pragma unroll
            for (int ks = 0; ks < 2; ++ks) {
                const short* pp = &Ps[wave][l16][ks * 32 + quad * 8];
                s4 alo = *(const s4*)pp;
                s4 ahi = *(const s4*)(pp + 4);
                s8 a;
                a[0] = alo[0]; a[1] = alo[1]; a[2] = alo[2]; a[3] = alo[3];
                a[4] = ahi[0]; a[5] = ahi[1]; a[6] = ahi[2]; a[7] = ahi[3];
                #pragma unroll
                for (int dt = 0; dt < 4; ++dt) {
                    s8 bv = *(const s8*)&Vb[dt * 16 + l16][ks * 32 + quad * 8];
                    oc[dt] = MFMA16(a, bv, oc[dt]);
                }
            }
            // self softmax -> Ps (overwrite; wave-private ordering), PV
            #pragma unroll
            for (int reg = 0; reg < 4; ++reg) {
                const int t_g = rb + quad * 4 + reg;
                #pragma unroll
                for (int nt = 0; nt < 4; ++nt) {
                    float pv = (s0 + nt * 16 + l16 <= t_g) ? __expf(ss[nt][reg] * 0.125f) : 0.f;
                    ls_[reg] += pv;
                    Ps[wave][quad * 4 + reg][nt * 16 + l16] = bfs(pv);
                }
            }
            #pragma unroll
            for (int ks = 0; ks < 2; ++ks) {
                const short* pp = &Ps[wave][l16][ks * 32 + quad * 8];
                s4 alo = *(const s4*)pp;
                s4 ahi = *(const s4*)(pp + 4);
                s8 a;
                a[0] = alo[0]; a[1] = alo[1]; a[2] = alo[2]; a[3] = alo[3];
                a[4] = ahi[0]; a[5] = ahi[1]; a[6] = ahi[2]; a[7] = ahi[3];
                #pragma unroll
                for (int dt = 0; dt < 4; ++dt) {
                    s8 bv = *(const s8*)&Vb[dt * 16 + l16][ks * 32 + quad * 8];
                    os_[dt] = MFMA16(a, bv, os_[dt]);
                }
            }
        }
        __syncthreads();   // all waves done reading Kc/Ksf/Vb
        if (pf) {
            #pragma unroll
            for (int tl = 0; tl < 4; ++tl) {
                int g = tid + tl * 512, row = g >> 5, grp = g & 31;
                *(s8*)&Kc[row][grp * 8] = kcp[tl];
            }
            int row = tid >> 3, grp = tid & 7;
            *(s8*)&Ksf[row][grp * 8] = ksp;
            *(s8*)&Vb[row][grp * 8] = vp;
        }
        __syncthreads();   // new tile visible
    }

    #pragma unroll
    for (int reg = 0; reg < 4; ++reg) {
        float l1 = lc[reg], l2 = ls_[reg];
        l1 += __shfl_xor(l1, 1); l1 += __shfl_xor(l1, 2);
        l1 += __shfl_xor(l1, 4); l1 += __shfl_xor(l1, 8);
        l2 += __shfl_xor(l2, 1); l2 += __shfl_xor(l2, 2);
        l2 += __shfl_xor(l2, 4); l2 += __shfl_xor(l2, 8);
        const float i1 = 1.f / l1, i2 = 1.f / l2;
        const int t = rb + quad * 4 + reg;
        #pragma unroll
        for (int dt = 0; dt < 4; ++dt) {
            size_t idx = (size_t)(b * T_ + t) * C_ + h * HD_ + dt * 16 + l16;
            float cv = ocv[dt][reg] + oc[dt][reg] * i1 + x[idx];
            cval[idx] = cv;
            cval_bf[idx] = __float2bfloat16(cv);
            float sv = os_[dt][reg] * i2;
            sval[idx] = sv;
            sval_bf[idx] = __float2bfloat16(sv);
        }
    }
}

// ---------------- fused dual gate GEMM + sigmoid + combine -> gated bf16 ----------------
__global__ __launch_bounds__(256) void gatefuse_kernel(
    const bf16* __restrict__ svalb, const bf16* __restrict__ cvalb,
    const bf16* __restrict__ WTgs, const bf16* __restrict__ WTgc,
    const float* __restrict__ bgs, const float* __restrict__ bgc,
    const float* __restrict__ cval, const float* __restrict__ sval,
    bf16* __restrict__ gated)
{
    __shared__ short Sb[128][72], Cb[128][72], W1b[64][72], W2b[64][72];
    const int tid = threadIdx.x;
    const int wave = tid >> 6, lane = tid & 63;
    const int quad = lane >> 4, l16 = lane & 15;
    const int n0 = blockIdx.x * 64, m0 = blockIdx.y * 128;
    f4 aS[2][4], aC[2][4];
    #pragma unroll
    for (int mt = 0; mt < 2; ++mt)
        #pragma unroll
        for (int nt = 0; nt < 4; ++nt) { aS[mt][nt] = (f4)0.f; aC[mt][nt] = (f4)0.f; }

    for (int k0 = 0; k0 < C_; k0 += 64) {
        #pragma unroll
        for (int tl = 0; tl < 4; ++tl) {
            int g = tid + tl * 256, row = g >> 3, grp = g & 7;
            *(s8*)&Sb[row][grp * 8] = *(const s8*)&svalb[(size_t)(m0 + row) * C_ + k0 + grp * 8];
            *(s8*)&Cb[row][grp * 8] = *(const s8*)&cvalb[(size_t)(m0 + row) * C_ + k0 + grp * 8];
        }
        #pragma unroll
        for (int tl = 0; tl < 2; ++tl) {
            int g = tid + tl * 256, n = g >> 3, grp = g & 7;
            *(s8*)&W1b[n][grp * 8] = *(const s8*)&WTgs[(size_t)(n0 + n) * C_ + k0 + grp * 8];
            *(s8*)&W2b[n][grp * 8] = *(const s8*)&WTgc[(size_t)(n0 + n) * C_ + k0 + grp * 8];
        }
        __syncthreads();
        #pragma unroll
        for (int ks = 0; ks < 2; ++ks) {
            s8 s0f = *(const s8*)&Sb[wave * 32 + l16][ks * 32 + quad * 8];
            s8 s1f = *(const s8*)&Sb[wave * 32 + 16 + l16][ks * 32 + quad * 8];
            s8 c0f = *(const s8*)&Cb[wave * 32 + l16][ks * 32 + quad * 8];
            s8 c1f = *(const s8*)&Cb[wave * 32 + 16 + l16][ks * 32 + quad * 8];
            #pragma unroll
            for (int nt = 0; nt < 4; ++nt) {
                s8 w1 = *(const s8*)&W1b[nt * 16 + l16][ks * 32 + quad * 8];
                s8 w2 = *(const s8*)&W2b[nt * 16 + l16][ks * 32 + quad * 8];
                aS[0][nt] = MFMA16(s0f, w1, aS[0][nt]);
                aS[1][nt] = MFMA16(s1f, w1, aS[1][nt]);
                aC[0][nt] = MFMA16(c0f, w2, aC[0][nt]);
                aC[1][nt] = MFMA16(c1f, w2, aC[1][nt]);
            }
        }
        __syncthreads();
    }
    #pragma unroll
    for (int mt = 0; mt < 2; ++mt)
        #pragma unroll
        for (int nt = 0; nt < 4; ++nt) {
            int col = n0 + nt * 16 + l16;
            float b1 = bgs[col], b2 = bgc[col];
            #pragma unroll
            for (int reg = 0; reg < 4; ++reg) {
                int row = m0 + wave * 32 + mt * 16 + quad * 4 + reg;
                size_t idx = (size_t)row * C_ + col;
                float gs = 1.f / (1.f + __expf(-(aS[mt][nt][reg] + b1)));
                float gc = 1.f / (1.f + __expf(-(aC[mt][nt][reg] + b2)));
                gated[idx] = __float2bfloat16(gs * cval[idx] + gc * sval[idx]);
            }
        }
}

extern "C" void kernel_launch(void* const* d_in, const int* in_sizes, int n_in,
                              void* d_out, int out_size, void* d_ws, size_t ws_size,
                              hipStream_t stream)
{
    const float* x      = (const float*)d_in[0];
    const float* y      = (const float*)d_in[1];
    // d_in[2]: attn_x_mask — structurally causal tril, computed inline
    const float* Wqkv_x = (const float*)d_in[3];
    const float* bqkv_x = (const float*)d_in[4];
    const float* Wqkv_y = (const float*)d_in[5];
    const float* bqkv_y = (const float*)d_in[6];
    const float* w4x    = (const float*)d_in[7];
    const float* w4y    = (const float*)d_in[8];
    const float* w4xy   = (const float*)d_in[9];
    const float* Wgs    = (const float*)d_in[10];
    const float* bgs    = (const float*)d_in[11];
    const float* Wgc    = (const float*)d_in[12];
    const float* bgc    = (const float*)d_in[13];
    const float* Wp     = (const float*)d_in[14];
    const float* bp     = (const float*)d_in[15];

    // Workspace (f-word offsets; R9/R13/R14-proven layout)
    float* ws = (float*)d_ws;
    bf16*  qkv_x_bf = (bf16*)(ws + 0);           // 6,291,456 bf16
    bf16*  qkv_y_bf = (bf16*)(ws + 3145728);     // 1,572,864 bf16
    float* catt     = ws + 3932160;              // 8,388,608 f (dead after rowsoft)
    bf16*  gated_bf = (bf16*)(ws + 3932160);     //   reuse
    bf16*  cval_bf  = (bf16*)(ws + 5242880);     //   reuse
    bf16*  x2y_bf   = (bf16*)(ws + 12320768);    // 8,388,608 bf16 (written at rowsoft)
    bf16*  x_bf     = x2y_bf;                    //   pre-QKV reuse
    bf16*  y_bf     = (bf16*)(ws + 13369344);    //   pre-QKV reuse
    bf16*  y2x_bf   = (bf16*)(ws + 16515072);    // 8,388,608 bf16
    bf16*  vTx_bf   = (bf16*)(ws + 20709376);    // 2,097,152 bf16
    bf16*  vTy_bf   = (bf16*)(ws + 21757952);    // 524,288 bf16
    float* cval     = ws + 22020096;             // 2,097,152 f
    float* psum_    = cval;                      //   pre-cval reuse (catt3 colsums)
    float* sval     = ws + 24117248;             // 2,097,152 f
    bf16*  qw_bf    = (bf16*)(ws + 26214400);    // 2,097,152 bf16 (dead after catt3)
    bf16*  sval_bf  = qw_bf;                     //   reuse
    bf16*  WT_x     = (bf16*)(ws + 27262976);    // 786,432 bf16
    bf16*  WT_y     = (bf16*)(ws + 27656192);
    bf16*  WT_gs    = (bf16*)(ws + 28049408);    // 262,144 bf16
    bf16*  WT_gc    = (bf16*)(ws + 28180480);
    bf16*  WT_p     = (bf16*)(ws + 28311552);
    float* catt1b   = ws + 28442624;             // 32,768 f
    float* catt2b   = ws + 28475392;             //  8,192 f
    float* colinv   = ws + 28483584;             //  8,192 f

    // 0: one prep dispatch (5 transposes + 2 converts)
    prep_kernel<<<1856, 256, 0, stream>>>(
        Wqkv_x, Wqkv_y, Wgs, Wgc, Wp, x, y,
        WT_x, WT_y, WT_gs, WT_gc, WT_p, x_bf, y_bf);

    // 1-2: QKV projections
    gemm_staged_kernel<bf16><<<dim3(24, 32), 256, 0, stream>>>(x_bf, WT_x, bqkv_x, qkv_x_bf, C3_, C_);
    gemm_staged_kernel<bf16><<<dim3(24, 8), 256, 0, stream>>>(y_bf, WT_y, bqkv_y, qkv_y_bf, C3_, C_);

    // 3-4: attention logit pieces (catt1/catt2/qw in ONE dispatch), then catt3 + col sums
    qwcatt_kernel<<<1184, 256, 0, stream>>>(
        qkv_x_bf, qkv_y_bf, w4x, w4y, w4xy, catt1b, catt2b, qw_bf);
    catt3_kernel<<<dim3(4, 16, 32), 256, 0, stream>>>(qw_bf, qkv_y_bf, catt1b, catt2b, catt, psum_);

    // 5-6: softmaxes
    colfin_kernel<<<32, 256, 0, stream>>>(psum_, colinv);
    rowsoft_kernel<<<8192, 256, 0, stream>>>(catt, colinv, x2y_bf, y2x_bf);

    // 7: V transposes (one dispatch)
    vtransm_kernel<<<640, 256, 0, stream>>>(qkv_x_bf, qkv_y_bf, vTx_bf, vTy_bf);

    // 8: paired-tile merged flash, XCD-swizzled grid (bh fastest -> same-bh blocks share an XCD)
    flash6_kernel<<<dim3(32, 8), 512, 0, stream>>>(
        x2y_bf, y2x_bf, vTx_bf, vTy_bf, qkv_x_bf, x, cval, cval_bf, sval, sval_bf);

    // 9: fused gates -> gated bf16
    gatefuse_kernel<<<dim3(8, 32), 256, 0, stream>>>(
        sval_bf, cval_bf, WT_gs, WT_gc, bgs, bgc, cval, sval, gated_bf);

    // 10: out = gated @ Wp + bp
    gemm_staged_kernel<float><<<dim3(8, 32), 256, 0, stream>>>(
        gated_bf, WT_p, bp, (float*)d_out, C_, C_);
}

// Round 16
// 231.387 us; speedup vs baseline: 1.2814x; 1.0428x over previous
//
#include <hip/hip_runtime.h>
#include <hip/hip_bf16.h>

typedef __hip_bfloat16 bf16;
using f4 = __attribute__((ext_vector_type(4))) float;
using s8 = __attribute__((ext_vector_type(8))) short;
using s4 = __attribute__((ext_vector_type(4))) short;

__device__ __forceinline__ void storeOut(float* p, float v) { *p = v; }
__device__ __forceinline__ void storeOut(bf16* p, float v) { *p = __float2bfloat16(v); }
__device__ __forceinline__ short bfs(float x) { return __builtin_bit_cast(short, __float2bfloat16(x)); }

constexpr int B_ = 4, T_ = 1024, M_ = 256, C_ = 512, H_ = 8, HD_ = 64, C3_ = 1536;

#define MFMA16(a, b, c) __builtin_amdgcn_mfma_f32_16x16x32_bf16((a), (b), (c), 0, 0, 0)

// ---------------- prep: 5 weight transposes (fp32 KxN -> bf16 NxK) + 2 converts ----------------
__global__ __launch_bounds__(256) void prep_kernel(
    const float* __restrict__ Wqkv_x, const float* __restrict__ Wqkv_y,
    const float* __restrict__ Wgs, const float* __restrict__ Wgc, const float* __restrict__ Wp,
    const float* __restrict__ x, const float* __restrict__ y,
    bf16* __restrict__ WT_x, bf16* __restrict__ WT_y, bf16* __restrict__ WT_gs,
    bf16* __restrict__ WT_gc, bf16* __restrict__ WT_p,
    bf16* __restrict__ x_bf, bf16* __restrict__ y_bf)
{
    __shared__ float Ls[64][65];
    const int tid = threadIdx.x;
    const int bid = blockIdx.x;
    if (bid < 576) {
        const float* W; bf16* WT; int N, t;
        if (bid < 192)      { W = Wqkv_x; WT = WT_x;  N = C3_; t = bid; }
        else if (bid < 384) { W = Wqkv_y; WT = WT_y;  N = C3_; t = bid - 192; }
        else if (bid < 448) { W = Wgs;    WT = WT_gs; N = C_;  t = bid - 384; }
        else if (bid < 512) { W = Wgc;    WT = WT_gc; N = C_;  t = bid - 448; }
        else                { W = Wp;     WT = WT_p;  N = C_;  t = bid - 512; }
        const int K = C_;
        const int tw = N >> 6;
        const int n0 = (t % tw) * 64, k0 = (t / tw) * 64;
        for (int i = tid; i < 1024; i += 256) {
            int kr = i >> 4, ng = i & 15;
            float4 v = *(const float4*)&W[(size_t)(k0 + kr) * N + n0 + ng * 4];
            Ls[ng * 4 + 0][kr] = v.x; Ls[ng * 4 + 1][kr] = v.y;
            Ls[ng * 4 + 2][kr] = v.z; Ls[ng * 4 + 3][kr] = v.w;
        }
        __syncthreads();
        for (int i = tid; i < 512; i += 256) {
            int n = i >> 3, kg = i & 7;
            s8 r;
            #pragma unroll
            for (int j = 0; j < 8; ++j) r[j] = bfs(Ls[n][kg * 8 + j]);
            *(s8*)&WT[(size_t)(n0 + n) * K + k0 + kg * 8] = r;
        }
    } else if (bid < 1600) {
        int i = (bid - 576) * 2048 + tid * 8;
        s8 r;
        #pragma unroll
        for (int j = 0; j < 8; ++j) r[j] = bfs(x[i + j]);
        *(s8*)&x_bf[i] = r;
    } else {
        int i = (bid - 1600) * 2048 + tid * 8;
        s8 r;
        #pragma unroll
        for (int j = 0; j < 8; ++j) r[j] = bfs(y[i + j]);
        *(s8*)&y_bf[i] = r;
    }
}

// ---------------- merged catt1/catt2 + qw (one dispatch) ----------------
__global__ __launch_bounds__(256) void qwcatt_kernel(
    const bf16* __restrict__ qkv_x, const bf16* __restrict__ qkv_y,
    const float* __restrict__ w4x, const float* __restrict__ w4y,
    const float* __restrict__ w4xy,
    float* __restrict__ catt1b, float* __restrict__ catt2b, bf16* __restrict__ qw)
{
    const int bid = blockIdx.x;
    const int tid = threadIdx.x;
    if (bid < 160) {
        int i = bid * 256 + tid;   // 0..40959
        const bf16* row; const float* w; float* out; int oi;
        if (i < 32768) {
            int bh = i >> 10, t = i & 1023, b = bh >> 3, h = bh & 7;
            row = qkv_x + (size_t)(b * T_ + t) * C3_ + h * HD_;
            w = w4x + h * HD_; out = catt1b; oi = i;
        } else {
            int j = i - 32768;
            int bh = j >> 8, m = j & 255, b = bh >> 3, h = bh & 7;
            row = qkv_y + (size_t)(b * M_ + m) * C3_ + h * HD_;
            w = w4y + h * HD_; out = catt2b; oi = j;
        }
        float s = 0.f;
        #pragma unroll
        for (int d = 0; d < HD_; ++d) s = fmaf(__bfloat162float(row[d]), w[d], s);
        out[oi] = s;
    } else {
        int o = ((bid - 160) * 256 + tid) * 8;
        int row = o >> 9, c = o & 511;
        const bf16* src = qkv_x + (size_t)row * C3_ + c;
        s8 r;
        #pragma unroll
        for (int j = 0; j < 8; ++j) r[j] = bfs(__bfloat162float(src[j]) * w4xy[c + j]);
        *(s8*)&qw[o] = r;
    }
}

// ---------------- LDS-staged MFMA GEMM: C = A(MxK bf16) @ WT^T + bias ----------------
// Grid TRANSPOSED: x = m-tile (128 rows), y = n-tile (64 cols). Same-A blocks have
// linear ids m + gx*n (stride gx ≡ 0 mod 8) -> co-located on one XCD; the 8-24x
// A re-reads come from that XCD's L2 instead of HBM.
template <typename OT>
__global__ __launch_bounds__(256) void gemm_staged_kernel(
    const bf16* __restrict__ A, const bf16* __restrict__ WT, const float* __restrict__ bias,
    OT* __restrict__ Cmat, int N, int K)
{
    __shared__ short Asb[128][72];
    __shared__ short Bsb[64][72];
    const int tid = threadIdx.x;
    const int wave = tid >> 6, lane = tid & 63;
    const int quad = lane >> 4, l16 = lane & 15;
    const int n0 = blockIdx.y * 64, m0 = blockIdx.x * 128;
    f4 acc[2][4];
    #pragma unroll
    for (int mt = 0; mt < 2; ++mt)
        #pragma unroll
        for (int nt = 0; nt < 4; ++nt) acc[mt][nt] = (f4)0.f;

    for (int k0 = 0; k0 < K; k0 += 64) {
        #pragma unroll
        for (int tl = 0; tl < 4; ++tl) {
            int g = tid + tl * 256, row = g >> 3, grp = g & 7;
            *(s8*)&Asb[row][grp * 8] = *(const s8*)&A[(size_t)(m0 + row) * K + k0 + grp * 8];
        }
        #pragma unroll
        for (int tl = 0; tl < 2; ++tl) {
            int g = tid + tl * 256, n = g >> 3, grp = g & 7;
            *(s8*)&Bsb[n][grp * 8] = *(const s8*)&WT[(size_t)(n0 + n) * K + k0 + grp * 8];
        }
        __syncthreads();
        #pragma unroll
        for (int ks = 0; ks < 2; ++ks) {
            s8 a0 = *(const s8*)&Asb[wave * 32 + l16][ks * 32 + quad * 8];
            s8 a1 = *(const s8*)&Asb[wave * 32 + 16 + l16][ks * 32 + quad * 8];
            #pragma unroll
            for (int nt = 0; nt < 4; ++nt) {
                s8 bv = *(const s8*)&Bsb[nt * 16 + l16][ks * 32 + quad * 8];
                acc[0][nt] = MFMA16(a0, bv, acc[0][nt]);
                acc[1][nt] = MFMA16(a1, bv, acc[1][nt]);
            }
        }
        __syncthreads();
    }
    #pragma unroll
    for (int mt = 0; mt < 2; ++mt)
        #pragma unroll
        for (int nt = 0; nt < 4; ++nt) {
            int col = n0 + nt * 16 + l16;
            float bb = bias[col];
            #pragma unroll
            for (int reg = 0; reg < 4; ++reg) {
                int row = m0 + wave * 32 + mt * 16 + quad * 4 + reg;
                storeOut(&Cmat[(size_t)row * N + col], acc[mt][nt][reg] + bb);
            }
        }
}

// ---------------- catt3: logits + FUSED column partial sums ----------------
// Grid (bh, m-tile, t-tile): same-bh blocks co-located per XCD -> ky/qw slabs L2-hot.
__global__ __launch_bounds__(256) void catt3_kernel(
    const bf16* __restrict__ qw, const bf16* __restrict__ qkv_y,
    const float* __restrict__ catt1, const float* __restrict__ catt2,
    float* __restrict__ catt, float* __restrict__ psum)
{
    __shared__ float redc[4][64];
    const int tid = threadIdx.x;
    const int wave = tid >> 6, lane = tid & 63;
    const int quad = lane >> 4, l16 = lane & 15;
    const int bh = blockIdx.x, b = bh >> 3, h = bh & 7;
    const int m0 = blockIdx.y * 64, t0 = blockIdx.z * 64;
    f4 sc[4];
    #pragma unroll
    for (int nt = 0; nt < 4; ++nt) sc[nt] = (f4)0.f;
    const bf16* ap = qw + (size_t)(b * T_ + t0 + wave * 16 + l16) * C_ + h * HD_ + quad * 8;
    const bf16* bp = qkv_y + (size_t)(b * M_ + m0 + l16) * C3_ + C_ + h * HD_ + quad * 8;
    #pragma unroll
    for (int k0 = 0; k0 < 64; k0 += 32) {
        s8 a = *(const s8*)(ap + k0);
        #pragma unroll
        for (int nt = 0; nt < 4; ++nt) {
            s8 bv = *(const s8*)(bp + (size_t)nt * 16 * C3_ + k0);
            sc[nt] = MFMA16(a, bv, sc[nt]);
        }
    }
    float csloc[4];
    #pragma unroll
    for (int nt = 0; nt < 4; ++nt) {
        int m = m0 + nt * 16 + l16;
        float c2 = catt2[bh * M_ + m];
        float es = 0.f;
        #pragma unroll
        for (int reg = 0; reg < 4; ++reg) {
            int t = t0 + wave * 16 + quad * 4 + reg;
            float v = sc[nt][reg] * 0.125f + catt1[bh * T_ + t] + c2;
            catt[((size_t)bh * T_ + t) * M_ + m] = v;
            es += __expf(v);
        }
        es += __shfl_xor(es, 16);
        es += __shfl_xor(es, 32);
        csloc[nt] = es;
    }
    if (quad == 0) {
        #pragma unroll
        for (int nt = 0; nt < 4; ++nt) redc[wave][nt * 16 + l16] = csloc[nt];
    }
    __syncthreads();
    if (tid < 64) {
        float s = redc[0][tid] + redc[1][tid] + redc[2][tid] + redc[3][tid];
        psum[((size_t)bh * 16 + (t0 >> 6)) * M_ + m0 + tid] = s;
    }
}

// ---------------- merged colfin + V transposes (one dispatch) ----------------
__global__ __launch_bounds__(256) void colfin_vtrans_kernel(
    const float* __restrict__ psum, float* __restrict__ colinv,
    const bf16* __restrict__ qkv_x, const bf16* __restrict__ qkv_y,
    bf16* __restrict__ vTx, bf16* __restrict__ vTy)
{
    __shared__ short Ls[64][68];
    const int tid = threadIdx.x;
    int bid = blockIdx.x;
    if (bid < 32) {
        const int bh = bid, m = tid;
        float s = 0.f;
        #pragma unroll
        for (int ch = 0; ch < 16; ++ch) s += psum[(bh * 16 + ch) * M_ + m];
        colinv[bh * M_ + m] = 1.f / s;
        return;
    }
    bid -= 32;
    const bf16* qkv; bf16* vT; int Nrows, bh, t0;
    if (bid < 512) { qkv = qkv_x; vT = vTx; Nrows = T_; bh = bid >> 4; t0 = (bid & 15) * 64; }
    else { bid -= 512; qkv = qkv_y; vT = vTy; Nrows = M_; bh = bid >> 2; t0 = (bid & 3) * 64; }
    const int b = bh >> 3, h = bh & 7;
    for (int i = tid; i < 4096; i += 256) {
        int tl = i >> 6, d = i & 63;
        Ls[d][tl] = __builtin_bit_cast(short,
            qkv[(size_t)(b * Nrows + t0 + tl) * C3_ + 2 * C_ + h * HD_ + d]);
    }
    __syncthreads();
    for (int i = tid; i < 4096; i += 256) {
        int d = i >> 6, tl = i & 63;
        vT[((size_t)bh * 64 + d) * Nrows + t0 + tl] = __builtin_bit_cast(bf16, Ls[d][tl]);
    }
}

// ---------------- fused row softmax -> x2y bf16 AND y2x bf16 ----------------
__global__ __launch_bounds__(256) void rowsoft_kernel(
    const float* __restrict__ catt, const float* __restrict__ colinv,
    bf16* __restrict__ x2y, bf16* __restrict__ y2x)
{
    const int wave = threadIdx.x >> 6, lane = threadIdx.x & 63;
    const int row = blockIdx.x * 4 + wave;
    const int bh = row >> 10;
    const float* p = catt + (size_t)row * M_;
    float e[4];
    float s = 0.f;
    #pragma unroll
    for (int j = 0; j < 4; ++j) { e[j] = __expf(p[j * 64 + lane]); s += e[j]; }
    for (int off = 1; off < 64; off <<= 1) s += __shfl_xor(s, off);
    float inv = 1.f / s;
    #pragma unroll
    for (int j = 0; j < 4; ++j) {
        int m = j * 64 + lane;
        x2y[(size_t)row * M_ + m] = __float2bfloat16(e[j] * inv);
        y2x[(size_t)row * M_ + m] = __float2bfloat16(e[j] * colinv[bh * M_ + m]);
    }
}

// ---------------- flash6: paired-tile merged flash (512 threads, 8 waves) ----------------
// R14/R15-proven; grid (bh, p) XCD swizzle keeps per-bh y2x slab L2-resident.
__global__ __launch_bounds__(512) void flash6_kernel(
    const bf16* __restrict__ x2y, const bf16* __restrict__ y2x,
    const bf16* __restrict__ vTx, const bf16* __restrict__ vTy,
    const bf16* __restrict__ qkv_x, const float* __restrict__ x,
    float* __restrict__ cval, bf16* __restrict__ cval_bf,
    float* __restrict__ sval, bf16* __restrict__ sval_bf)
{
    __shared__ short Kc[64][264];     // chain K (64 keys x 256)
    __shared__ short Ksf[64][72];     // self K (64 keys x 64)
    __shared__ short Vb[64][72];      // V^T (64 d x 64 s)
    __shared__ short Ps[8][16][68];   // wave-private P
    const int tid = threadIdx.x;
    const int wave = tid >> 6, lane = tid & 63;
    const int quad = lane >> 4, l16 = lane & 15;
    const int bh = blockIdx.x, b = bh >> 3, h = bh & 7;   // x = bh (XCD swizzle)
    const int p = blockIdx.y;                    // pair id 0..7
    const int jt = (wave < 4) ? p : (15 - p);    // this wave's query tile
    const int rb = jt * 64 + (wave & 3) * 16;    // wave's 16-row base
    const int nst = 16 - p;                      // shared key-tile loop length

    s8 qc[8], qs[2];
    {
        const bf16* qp = x2y + (size_t)(bh * T_ + rb + l16) * M_ + quad * 8;
        #pragma unroll
        for (int f = 0; f < 8; ++f) qc[f] = *(const s8*)(qp + f * 32);
        const bf16* qsp = qkv_x + (size_t)(b * T_ + rb + l16) * C3_ + h * HD_ + quad * 8;
        qs[0] = *(const s8*)qsp;
        qs[1] = *(const s8*)(qsp + 32);
    }

    f4 ocv[4];
    #pragma unroll
    for (int dt = 0; dt < 4; ++dt) ocv[dt] = (f4)0.f;
    {
        const bf16* vb = vTy + (size_t)(bh * 64 + l16) * M_ + quad * 8;
        #pragma unroll
        for (int f = 0; f < 8; ++f)
            #pragma unroll
            for (int dt = 0; dt < 4; ++dt) {
                s8 bv = *(const s8*)(vb + (size_t)dt * 16 * M_ + f * 32);
                ocv[dt] = MFMA16(qc[f], bv, ocv[dt]);
            }
    }

    f4 oc[4], os_[4];
    float lc[4] = {0.f, 0.f, 0.f, 0.f}, ls_[4] = {0.f, 0.f, 0.f, 0.f};
    #pragma unroll
    for (int dt = 0; dt < 4; ++dt) { oc[dt] = (f4)0.f; os_[dt] = (f4)0.f; }

    #pragma unroll
    for (int tl = 0; tl < 4; ++tl) {
        int g = tid + tl * 512, row = g >> 5, grp = g & 31;
        *(s8*)&Kc[row][grp * 8] = *(const s8*)&y2x[(size_t)(bh * T_ + row) * M_ + grp * 8];
    }
    {
        int row = tid >> 3, grp = tid & 7;
        *(s8*)&Ksf[row][grp * 8] =
            *(const s8*)&qkv_x[(size_t)(b * T_ + row) * C3_ + C_ + h * HD_ + grp * 8];
        *(s8*)&Vb[row][grp * 8] = *(const s8*)&vTx[(size_t)(bh * 64 + row) * T_ + grp * 8];
    }
    __syncthreads();

    for (int st = 0; st < nst; ++st) {
        const int s0 = st * 64;
        const bool pf = (st + 1) < nst;
        s8 kcp[4], ksp, vp;
        if (pf) {
            const int sn = s0 + 64;
            #pragma unroll
            for (int tl = 0; tl < 4; ++tl) {
                int g = tid + tl * 512, row = g >> 5, grp = g & 31;
                kcp[tl] = *(const s8*)&y2x[(size_t)(bh * T_ + sn + row) * M_ + grp * 8];
            }
            int row = tid >> 3, grp = tid & 7;
            ksp = *(const s8*)&qkv_x[(size_t)(b * T_ + sn + row) * C3_ + C_ + h * HD_ + grp * 8];
            vp = *(const s8*)&vTx[(size_t)(bh * 64 + row) * T_ + sn + grp * 8];
        }
        if (st <= jt) {
            f4 sc[4];
            #pragma unroll
            for (int nt = 0; nt < 4; ++nt) sc[nt] = (f4)0.f;
            #pragma unroll
            for (int f = 0; f < 8; ++f)
                #pragma unroll
                for (int nt = 0; nt < 4; ++nt) {
                    s8 bv = *(const s8*)&Kc[nt * 16 + l16][f * 32 + quad * 8];
                    sc[nt] = MFMA16(qc[f], bv, sc[nt]);
                }
            f4 ss[4];
            #pragma unroll
            for (int nt = 0; nt < 4; ++nt) ss[nt] = (f4)0.f;
            #pragma unroll
            for (int f = 0; f < 2; ++f)
                #pragma unroll
                for (int nt = 0; nt < 4; ++nt) {
                    s8 bv = *(const s8*)&Ksf[nt * 16 + l16][f * 32 + quad * 8];
                    ss[nt] = MFMA16(qs[f], bv, ss[nt]);
                }
            #pragma unroll
            for (int reg = 0; reg < 4; ++reg) {
                const int t_g = rb + quad * 4 + reg;
                #pragma unroll
                for (int nt = 0; nt < 4; ++nt) {
                    float pv = (s0 + nt * 16 + l16 <= t_g) ? __expf(sc[nt][reg] * (1.f / 16.f)) : 0.f;
                    lc[reg] += pv;
                    Ps[wave][quad * 4 + reg][nt * 16 + l16] = bfs(pv);
                }
            }
            #pragma unroll
            for (int ks = 0; ks < 2; ++ks) {
                const short* pp = &Ps[wave][l16][ks * 32 + quad * 8];
                s4 alo = *(const s4*)pp;
                s4 ahi = *(const s4*)(pp + 4);
                s8 a;
                a[0] = alo[0]; a[1] = alo[1]; a[2] = alo[2]; a[3] = alo[3];
                a[4] = ahi[0]; a[5] = ahi[1]; a[6] = ahi[2]; a[7] = ahi[3];
                #pragma unroll
                for (int dt = 0; dt < 4; ++dt) {
                    s8 bv = *(const s8*)&Vb[dt * 16 + l16][ks * 32 + quad * 8];
                    oc[dt] = MFMA16(a, bv, oc[dt]);
                }
            }
            #pragma unroll
            for (int reg = 0; reg < 4; ++reg) {
                const int t_g = rb + quad * 4 + reg;
                #pragma unroll
                for (int nt = 0; nt < 4; ++nt) {
                    float pv = (s0 + nt * 16 + l16 <= t_g) ? __expf(ss[nt][reg] * 0.125f) : 0.f;
                    ls_[reg] += pv;
                    Ps[wave][quad * 4 + reg][nt * 16 + l16] = bfs(pv);
                }
            }
            #pragma unroll
            for (int ks = 0; ks < 2; ++ks) {
                const short* pp = &Ps[wave][l16][ks * 32 + quad * 8];
                s4 alo = *(const s4*)pp;
                s4 ahi = *(const s4*)(pp + 4);
                s8 a;
                a[0] = alo[0]; a[1] = alo[1]; a[2] = alo[2]; a[3] = alo[3];
                a[4] = ahi[0]; a[5] = ahi[1]; a[6] = ahi[2]; a[7] = ahi[3];
                #pragma unroll
                for (int dt = 0; dt < 4; ++dt) {
                    s8 bv = *(const s8*)&Vb[dt * 16 + l16][ks * 32 + quad * 8];
                    os_[dt] = MFMA16(a, bv, os_[dt]);
                }
            }
        }
        __syncthreads();
        if (pf) {
            #pragma unroll
            for (int tl = 0; tl < 4; ++tl) {
                int g = tid + tl * 512, row = g >> 5, grp = g & 31;
                *(s8*)&Kc[row][grp * 8] = kcp[tl];
            }
            int row = tid >> 3, grp = tid & 7;
            *(s8*)&Ksf[row][grp * 8] = ksp;
            *(s8*)&Vb[row][grp * 8] = vp;
        }
        __syncthreads();
    }

    #pragma unroll
    for (int reg = 0; reg < 4; ++reg) {
        float l1 = lc[reg], l2 = ls_[reg];
        l1 += __shfl_xor(l1, 1); l1 += __shfl_xor(l1, 2);
        l1 += __shfl_xor(l1, 4); l1 += __shfl_xor(l1, 8);
        l2 += __shfl_xor(l2, 1); l2 += __shfl_xor(l2, 2);
        l2 += __shfl_xor(l2, 4); l2 += __shfl_xor(l2, 8);
        const float i1 = 1.f / l1, i2 = 1.f / l2;
        const int t = rb + quad * 4 + reg;
        #pragma unroll
        for (int dt = 0; dt < 4; ++dt) {
            size_t idx = (size_t)(b * T_ + t) * C_ + h * HD_ + dt * 16 + l16;
            float cv = ocv[dt][reg] + oc[dt][reg] * i1 + x[idx];
            cval[idx] = cv;
            cval_bf[idx] = __float2bfloat16(cv);
            float sv = os_[dt][reg] * i2;
            sval[idx] = sv;
            sval_bf[idx] = __float2bfloat16(sv);
        }
    }
}

// ---------------- fused dual gate GEMM + sigmoid + combine -> gated bf16 ----------------
// Grid transposed (x = m-tile) for XCD co-location of the shared sval/cval A rows.
__global__ __launch_bounds__(256) void gatefuse_kernel(
    const bf16* __restrict__ svalb, const bf16* __restrict__ cvalb,
    const bf16* __restrict__ WTgs, const bf16* __restrict__ WTgc,
    const float* __restrict__ bgs, const float* __restrict__ bgc,
    const float* __restrict__ cval, const float* __restrict__ sval,
    bf16* __restrict__ gated)
{
    __shared__ short Sb[128][72], Cb[128][72], W1b[64][72], W2b[64][72];
    const int tid = threadIdx.x;
    const int wave = tid >> 6, lane = tid & 63;
    const int quad = lane >> 4, l16 = lane & 15;
    const int n0 = blockIdx.y * 64, m0 = blockIdx.x * 128;
    f4 aS[2][4], aC[2][4];
    #pragma unroll
    for (int mt = 0; mt < 2; ++mt)
        #pragma unroll
        for (int nt = 0; nt < 4; ++nt) { aS[mt][nt] = (f4)0.f; aC[mt][nt] = (f4)0.f; }

    for (int k0 = 0; k0 < C_; k0 += 64) {
        #pragma unroll
        for (int tl = 0; tl < 4; ++tl) {
            int g = tid + tl * 256, row = g >> 3, grp = g & 7;
            *(s8*)&Sb[row][grp * 8] = *(const s8*)&svalb[(size_t)(m0 + row) * C_ + k0 + grp * 8];
            *(s8*)&Cb[row][grp * 8] = *(const s8*)&cvalb[(size_t)(m0 + row) * C_ + k0 + grp * 8];
        }
        #pragma unroll
        for (int tl = 0; tl < 2; ++tl) {
            int g = tid + tl * 256, n = g >> 3, grp = g & 7;
            *(s8*)&W1b[n][grp * 8] = *(const s8*)&WTgs[(size_t)(n0 + n) * C_ + k0 + grp * 8];
            *(s8*)&W2b[n][grp * 8] = *(const s8*)&WTgc[(size_t)(n0 + n) * C_ + k0 + grp * 8];
        }
        __syncthreads();
        #pragma unroll
        for (int ks = 0; ks < 2; ++ks) {
            s8 s0f = *(const s8*)&Sb[wave * 32 + l16][ks * 32 + quad * 8];
            s8 s1f = *(const s8*)&Sb[wave * 32 + 16 + l16][ks * 32 + quad * 8];
            s8 c0f = *(const s8*)&Cb[wave * 32 + l16][ks * 32 + quad * 8];
            s8 c1f = *(const s8*)&Cb[wave * 32 + 16 + l16][ks * 32 + quad * 8];
            #pragma unroll
            for (int nt = 0; nt < 4; ++nt) {
                s8 w1 = *(const s8*)&W1b[nt * 16 + l16][ks * 32 + quad * 8];
                s8 w2 = *(const s8*)&W2b[nt * 16 + l16][ks * 32 + quad * 8];
                aS[0][nt] = MFMA16(s0f, w1, aS[0][nt]);
                aS[1][nt] = MFMA16(s1f, w1, aS[1][nt]);
                aC[0][nt] = MFMA16(c0f, w2, aC[0][nt]);
                aC[1][nt] = MFMA16(c1f, w2, aC[1][nt]);
            }
        }
        __syncthreads();
    }
    #pragma unroll
    for (int mt = 0; mt < 2; ++mt)
        #pragma unroll
        for (int nt = 0; nt < 4; ++nt) {
            int col = n0 + nt * 16 + l16;
            float b1 = bgs[col], b2 = bgc[col];
            #pragma unroll
            for (int reg = 0; reg < 4; ++reg) {
                int row = m0 + wave * 32 + mt * 16 + quad * 4 + reg;
                size_t idx = (size_t)row * C_ + col;
                float gs = 1.f / (1.f + __expf(-(aS[mt][nt][reg] + b1)));
                float gc = 1.f / (1.f + __expf(-(aC[mt][nt][reg] + b2)));
                gated[idx] = __float2bfloat16(gs * cval[idx] + gc * sval[idx]);
            }
        }
}

extern "C" void kernel_launch(void* const* d_in, const int* in_sizes, int n_in,
                              void* d_out, int out_size, void* d_ws, size_t ws_size,
                              hipStream_t stream)
{
    const float* x      = (const float*)d_in[0];
    const float* y      = (const float*)d_in[1];
    // d_in[2]: attn_x_mask — structurally causal tril, computed inline
    const float* Wqkv_x = (const float*)d_in[3];
    const float* bqkv_x = (const float*)d_in[4];
    const float* Wqkv_y = (const float*)d_in[5];
    const float* bqkv_y = (const float*)d_in[6];
    const float* w4x    = (const float*)d_in[7];
    const float* w4y    = (const float*)d_in[8];
    const float* w4xy   = (const float*)d_in[9];
    const float* Wgs    = (const float*)d_in[10];
    const float* bgs    = (const float*)d_in[11];
    const float* Wgc    = (const float*)d_in[12];
    const float* bgc    = (const float*)d_in[13];
    const float* Wp     = (const float*)d_in[14];
    const float* bp     = (const float*)d_in[15];

    // Workspace (f-word offsets; proven layout)
    float* ws = (float*)d_ws;
    bf16*  qkv_x_bf = (bf16*)(ws + 0);           // 6,291,456 bf16
    bf16*  qkv_y_bf = (bf16*)(ws + 3145728);     // 1,572,864 bf16
    float* catt     = ws + 3932160;              // 8,388,608 f (dead after rowsoft)
    bf16*  gated_bf = (bf16*)(ws + 3932160);     //   reuse
    bf16*  cval_bf  = (bf16*)(ws + 5242880);     //   reuse
    bf16*  x2y_bf   = (bf16*)(ws + 12320768);    // 8,388,608 bf16 (written at rowsoft)
    bf16*  x_bf     = x2y_bf;                    //   pre-QKV reuse
    bf16*  y_bf     = (bf16*)(ws + 13369344);    //   pre-QKV reuse
    bf16*  y2x_bf   = (bf16*)(ws + 16515072);    // 8,388,608 bf16
    bf16*  vTx_bf   = (bf16*)(ws + 20709376);    // 2,097,152 bf16
    bf16*  vTy_bf   = (bf16*)(ws + 21757952);    // 524,288 bf16
    float* cval     = ws + 22020096;             // 2,097,152 f
    float* psum_    = cval;                      //   pre-cval reuse (catt3 colsums)
    float* sval     = ws + 24117248;             // 2,097,152 f
    bf16*  qw_bf    = (bf16*)(ws + 26214400);    // 2,097,152 bf16 (dead after catt3)
    bf16*  sval_bf  = qw_bf;                     //   reuse
    bf16*  WT_x     = (bf16*)(ws + 27262976);    // 786,432 bf16
    bf16*  WT_y     = (bf16*)(ws + 27656192);
    bf16*  WT_gs    = (bf16*)(ws + 28049408);    // 262,144 bf16
    bf16*  WT_gc    = (bf16*)(ws + 28180480);
    bf16*  WT_p     = (bf16*)(ws + 28311552);
    float* catt1b   = ws + 28442624;             // 32,768 f
    float* catt2b   = ws + 28475392;             //  8,192 f
    float* colinv   = ws + 28483584;             //  8,192 f

    // 0: one prep dispatch (5 transposes + 2 converts)
    prep_kernel<<<1856, 256, 0, stream>>>(
        Wqkv_x, Wqkv_y, Wgs, Wgc, Wp, x, y,
        WT_x, WT_y, WT_gs, WT_gc, WT_p, x_bf, y_bf);

    // 1-2: QKV projections (grids transposed: x = m-tile for XCD A-locality)
    gemm_staged_kernel<bf16><<<dim3(32, 24), 256, 0, stream>>>(x_bf, WT_x, bqkv_x, qkv_x_bf, C3_, C_);
    gemm_staged_kernel<bf16><<<dim3(8, 24), 256, 0, stream>>>(y_bf, WT_y, bqkv_y, qkv_y_bf, C3_, C_);

    // 3-4: attention logit pieces, then catt3 + col sums (bh-major grid for XCD locality)
    qwcatt_kernel<<<1184, 256, 0, stream>>>(
        qkv_x_bf, qkv_y_bf, w4x, w4y, w4xy, catt1b, catt2b, qw_bf);
    catt3_kernel<<<dim3(32, 4, 16), 256, 0, stream>>>(qw_bf, qkv_y_bf, catt1b, catt2b, catt, psum_);

    // 5: colfin + V transposes in one dispatch
    colfin_vtrans_kernel<<<672, 256, 0, stream>>>(psum_, colinv, qkv_x_bf, qkv_y_bf, vTx_bf, vTy_bf);

    // 6: row softmax -> x2y & y2x
    rowsoft_kernel<<<8192, 256, 0, stream>>>(catt, colinv, x2y_bf, y2x_bf);

    // 7: paired-tile merged flash, XCD-swizzled grid
    flash6_kernel<<<dim3(32, 8), 512, 0, stream>>>(
        x2y_bf, y2x_bf, vTx_bf, vTy_bf, qkv_x_bf, x, cval, cval_bf, sval, sval_bf);

    // 8: fused gates -> gated bf16 (grid transposed)
    gatefuse_kernel<<<dim3(32, 8), 256, 0, stream>>>(
        sval_bf, cval_bf, WT_gs, WT_gc, bgs, bgc, cval, sval, gated_bf);

    // 9: out = gated @ Wp + bp (grid transposed)
    gemm_staged_kernel<float><<<dim3(32, 8), 256, 0, stream>>>(
        gated_bf, WT_p, bp, (float*)d_out, C_, C_);
}

// Round 17
// 226.284 us; speedup vs baseline: 1.3103x; 1.0226x over previous
//
#include <hip/hip_runtime.h>
#include <hip/hip_bf16.h>

typedef __hip_bfloat16 bf16;
using f4 = __attribute__((ext_vector_type(4))) float;
using s8 = __attribute__((ext_vector_type(8))) short;
using s4 = __attribute__((ext_vector_type(4))) short;

__device__ __forceinline__ void storeOut(float* p, float v) { *p = v; }
__device__ __forceinline__ void storeOut(bf16* p, float v) { *p = __float2bfloat16(v); }
__device__ __forceinline__ short bfs(float x) { return __builtin_bit_cast(short, __float2bfloat16(x)); }

constexpr int B_ = 4, T_ = 1024, M_ = 256, C_ = 512, H_ = 8, HD_ = 64, C3_ = 1536;

#define MFMA16(a, b, c) __builtin_amdgcn_mfma_f32_16x16x32_bf16((a), (b), (c), 0, 0, 0)

// ---------------- prep: 5 weight transposes (fp32 KxN -> bf16 NxK) + 2 converts ----------------
__global__ __launch_bounds__(256) void prep_kernel(
    const float* __restrict__ Wqkv_x, const float* __restrict__ Wqkv_y,
    const float* __restrict__ Wgs, const float* __restrict__ Wgc, const float* __restrict__ Wp,
    const float* __restrict__ x, const float* __restrict__ y,
    bf16* __restrict__ WT_x, bf16* __restrict__ WT_y, bf16* __restrict__ WT_gs,
    bf16* __restrict__ WT_gc, bf16* __restrict__ WT_p,
    bf16* __restrict__ x_bf, bf16* __restrict__ y_bf)
{
    __shared__ float Ls[64][65];
    const int tid = threadIdx.x;
    const int bid = blockIdx.x;
    if (bid < 576) {
        const float* W; bf16* WT; int N, t;
        if (bid < 192)      { W = Wqkv_x; WT = WT_x;  N = C3_; t = bid; }
        else if (bid < 384) { W = Wqkv_y; WT = WT_y;  N = C3_; t = bid - 192; }
        else if (bid < 448) { W = Wgs;    WT = WT_gs; N = C_;  t = bid - 384; }
        else if (bid < 512) { W = Wgc;    WT = WT_gc; N = C_;  t = bid - 448; }
        else                { W = Wp;     WT = WT_p;  N = C_;  t = bid - 512; }
        const int K = C_;
        const int tw = N >> 6;
        const int n0 = (t % tw) * 64, k0 = (t / tw) * 64;
        for (int i = tid; i < 1024; i += 256) {
            int kr = i >> 4, ng = i & 15;
            float4 v = *(const float4*)&W[(size_t)(k0 + kr) * N + n0 + ng * 4];
            Ls[ng * 4 + 0][kr] = v.x; Ls[ng * 4 + 1][kr] = v.y;
            Ls[ng * 4 + 2][kr] = v.z; Ls[ng * 4 + 3][kr] = v.w;
        }
        __syncthreads();
        for (int i = tid; i < 512; i += 256) {
            int n = i >> 3, kg = i & 7;
            s8 r;
            #pragma unroll
            for (int j = 0; j < 8; ++j) r[j] = bfs(Ls[n][kg * 8 + j]);
            *(s8*)&WT[(size_t)(n0 + n) * K + k0 + kg * 8] = r;
        }
    } else if (bid < 1600) {
        int i = (bid - 576) * 2048 + tid * 8;
        s8 r;
        #pragma unroll
        for (int j = 0; j < 8; ++j) r[j] = bfs(x[i + j]);
        *(s8*)&x_bf[i] = r;
    } else {
        int i = (bid - 1600) * 2048 + tid * 8;
        s8 r;
        #pragma unroll
        for (int j = 0; j < 8; ++j) r[j] = bfs(y[i + j]);
        *(s8*)&y_bf[i] = r;
    }
}

// ---------------- merged catt1/catt2 + qw (one dispatch) ----------------
__global__ __launch_bounds__(256) void qwcatt_kernel(
    const bf16* __restrict__ qkv_x, const bf16* __restrict__ qkv_y,
    const float* __restrict__ w4x, const float* __restrict__ w4y,
    const float* __restrict__ w4xy,
    float* __restrict__ catt1b, float* __restrict__ catt2b, bf16* __restrict__ qw)
{
    const int bid = blockIdx.x;
    const int tid = threadIdx.x;
    if (bid < 160) {
        int i = bid * 256 + tid;   // 0..40959
        const bf16* row; const float* w; float* out; int oi;
        if (i < 32768) {
            int bh = i >> 10, t = i & 1023, b = bh >> 3, h = bh & 7;
            row = qkv_x + (size_t)(b * T_ + t) * C3_ + h * HD_;
            w = w4x + h * HD_; out = catt1b; oi = i;
        } else {
            int j = i - 32768;
            int bh = j >> 8, m = j & 255, b = bh >> 3, h = bh & 7;
            row = qkv_y + (size_t)(b * M_ + m) * C3_ + h * HD_;
            w = w4y + h * HD_; out = catt2b; oi = j;
        }
        float s = 0.f;
        #pragma unroll
        for (int d = 0; d < HD_; ++d) s = fmaf(__bfloat162float(row[d]), w[d], s);
        out[oi] = s;
    } else {
        int o = ((bid - 160) * 256 + tid) * 8;
        int row = o >> 9, c = o & 511;
        const bf16* src = qkv_x + (size_t)row * C3_ + c;
        s8 r;
        #pragma unroll
        for (int j = 0; j < 8; ++j) r[j] = bfs(__bfloat162float(src[j]) * w4xy[c + j]);
        *(s8*)&qw[o] = r;
    }
}

// ---------------- LDS-staged MFMA GEMM (R16-proven, m-major grid) ----------------
template <typename OT>
__global__ __launch_bounds__(256) void gemm_staged_kernel(
    const bf16* __restrict__ A, const bf16* __restrict__ WT, const float* __restrict__ bias,
    OT* __restrict__ Cmat, int N, int K)
{
    __shared__ short Asb[128][72];
    __shared__ short Bsb[64][72];
    const int tid = threadIdx.x;
    const int wave = tid >> 6, lane = tid & 63;
    const int quad = lane >> 4, l16 = lane & 15;
    const int n0 = blockIdx.y * 64, m0 = blockIdx.x * 128;
    f4 acc[2][4];
    #pragma unroll
    for (int mt = 0; mt < 2; ++mt)
        #pragma unroll
        for (int nt = 0; nt < 4; ++nt) acc[mt][nt] = (f4)0.f;

    for (int k0 = 0; k0 < K; k0 += 64) {
        #pragma unroll
        for (int tl = 0; tl < 4; ++tl) {
            int g = tid + tl * 256, row = g >> 3, grp = g & 7;
            *(s8*)&Asb[row][grp * 8] = *(const s8*)&A[(size_t)(m0 + row) * K + k0 + grp * 8];
        }
        #pragma unroll
        for (int tl = 0; tl < 2; ++tl) {
            int g = tid + tl * 256, n = g >> 3, grp = g & 7;
            *(s8*)&Bsb[n][grp * 8] = *(const s8*)&WT[(size_t)(n0 + n) * K + k0 + grp * 8];
        }
        __syncthreads();
        #pragma unroll
        for (int ks = 0; ks < 2; ++ks) {
            s8 a0 = *(const s8*)&Asb[wave * 32 + l16][ks * 32 + quad * 8];
            s8 a1 = *(const s8*)&Asb[wave * 32 + 16 + l16][ks * 32 + quad * 8];
            #pragma unroll
            for (int nt = 0; nt < 4; ++nt) {
                s8 bv = *(const s8*)&Bsb[nt * 16 + l16][ks * 32 + quad * 8];
                acc[0][nt] = MFMA16(a0, bv, acc[0][nt]);
                acc[1][nt] = MFMA16(a1, bv, acc[1][nt]);
            }
        }
        __syncthreads();
    }
    #pragma unroll
    for (int mt = 0; mt < 2; ++mt)
        #pragma unroll
        for (int nt = 0; nt < 4; ++nt) {
            int col = n0 + nt * 16 + l16;
            float bb = bias[col];
            #pragma unroll
            for (int reg = 0; reg < 4; ++reg) {
                int row = m0 + wave * 32 + mt * 16 + quad * 4 + reg;
                storeOut(&Cmat[(size_t)row * N + col], acc[mt][nt][reg] + bb);
            }
        }
}

// ---------------- catt3r: logits + row softmax -> x2y bf16 + rowsum + col partial sums ----------------
// Block (bh, t-tile) owns a FULL 64x256 logit tile: fp32 catt is never materialized.
// Row sums via l16-shfl (columns live across l16); col partials via quad-shfl + LDS.
__global__ __launch_bounds__(256) void catt3r_kernel(
    const bf16* __restrict__ qw, const bf16* __restrict__ qkv_y,
    const float* __restrict__ catt1, const float* __restrict__ catt2,
    bf16* __restrict__ x2y, float* __restrict__ rowsum_, float* __restrict__ psum)
{
    __shared__ float redc[4][256];
    const int tid = threadIdx.x;
    const int wave = tid >> 6, lane = tid & 63;
    const int quad = lane >> 4, l16 = lane & 15;
    const int bh = blockIdx.x, b = bh >> 3, h = bh & 7;
    const int t0 = blockIdx.y * 64;
    f4 sc[4][4];
    #pragma unroll
    for (int mt = 0; mt < 4; ++mt)
        #pragma unroll
        for (int nt = 0; nt < 4; ++nt) sc[mt][nt] = (f4)0.f;

    const bf16* ap = qw + (size_t)(b * T_ + t0 + wave * 16 + l16) * C_ + h * HD_ + quad * 8;
    s8 a0 = *(const s8*)ap;
    s8 a1 = *(const s8*)(ap + 32);
    const bf16* bp = qkv_y + (size_t)(b * M_ + l16) * C3_ + C_ + h * HD_ + quad * 8;
    #pragma unroll
    for (int mt = 0; mt < 4; ++mt)
        #pragma unroll
        for (int nt = 0; nt < 4; ++nt) {
            const bf16* bq = bp + (size_t)(mt * 64 + nt * 16) * C3_;
            sc[mt][nt] = MFMA16(a0, *(const s8*)bq, sc[mt][nt]);
            sc[mt][nt] = MFMA16(a1, *(const s8*)(bq + 32), sc[mt][nt]);
        }

    // logits -> exp (in place)
    float c1[4];
    #pragma unroll
    for (int reg = 0; reg < 4; ++reg)
        c1[reg] = catt1[bh * T_ + t0 + wave * 16 + quad * 4 + reg];
    #pragma unroll
    for (int mt = 0; mt < 4; ++mt)
        #pragma unroll
        for (int nt = 0; nt < 4; ++nt) {
            float c2 = catt2[bh * M_ + mt * 64 + nt * 16 + l16];
            #pragma unroll
            for (int reg = 0; reg < 4; ++reg)
                sc[mt][nt][reg] = __expf(sc[mt][nt][reg] * 0.125f + c1[reg] + c2);
        }

    // row sums (reduce over l16 within quad), write rowsum_, emit x2y
    #pragma unroll
    for (int reg = 0; reg < 4; ++reg) {
        float rs = 0.f;
        #pragma unroll
        for (int mt = 0; mt < 4; ++mt)
            #pragma unroll
            for (int nt = 0; nt < 4; ++nt) rs += sc[mt][nt][reg];
        rs += __shfl_xor(rs, 1); rs += __shfl_xor(rs, 2);
        rs += __shfl_xor(rs, 4); rs += __shfl_xor(rs, 8);
        const int t = t0 + wave * 16 + quad * 4 + reg;
        if (l16 == 0) rowsum_[bh * T_ + t] = rs;
        const float ri = 1.f / rs;
        #pragma unroll
        for (int mt = 0; mt < 4; ++mt)
            #pragma unroll
            for (int nt = 0; nt < 4; ++nt)
                x2y[((size_t)bh * T_ + t) * M_ + mt * 64 + nt * 16 + l16] =
                    __float2bfloat16(sc[mt][nt][reg] * ri);
    }

    // column partial sums (reduce over reg then quads)
    #pragma unroll
    for (int mt = 0; mt < 4; ++mt)
        #pragma unroll
        for (int nt = 0; nt < 4; ++nt) {
            float es = sc[mt][nt][0] + sc[mt][nt][1] + sc[mt][nt][2] + sc[mt][nt][3];
            es += __shfl_xor(es, 16);
            es += __shfl_xor(es, 32);
            if (quad == 0) redc[wave][mt * 64 + nt * 16 + l16] = es;
        }
    __syncthreads();
    psum[((size_t)bh * 16 + blockIdx.y) * M_ + tid] =
        redc[0][tid] + redc[1][tid] + redc[2][tid] + redc[3][tid];
}

// ---------------- merged colfin + V transposes (one dispatch) ----------------
__global__ __launch_bounds__(256) void colfin_vtrans_kernel(
    const float* __restrict__ psum, float* __restrict__ colinv,
    const bf16* __restrict__ qkv_x, const bf16* __restrict__ qkv_y,
    bf16* __restrict__ vTx, bf16* __restrict__ vTy)
{
    __shared__ short Ls[64][68];
    const int tid = threadIdx.x;
    int bid = blockIdx.x;
    if (bid < 32) {
        const int bh = bid, m = tid;
        float s = 0.f;
        #pragma unroll
        for (int ch = 0; ch < 16; ++ch) s += psum[(bh * 16 + ch) * M_ + m];
        colinv[bh * M_ + m] = 1.f / s;
        return;
    }
    bid -= 32;
    const bf16* qkv; bf16* vT; int Nrows, bh, t0;
    if (bid < 512) { qkv = qkv_x; vT = vTx; Nrows = T_; bh = bid >> 4; t0 = (bid & 15) * 64; }
    else { bid -= 512; qkv = qkv_y; vT = vTy; Nrows = M_; bh = bid >> 2; t0 = (bid & 3) * 64; }
    const int b = bh >> 3, h = bh & 7;
    for (int i = tid; i < 4096; i += 256) {
        int tl = i >> 6, d = i & 63;
        Ls[d][tl] = __builtin_bit_cast(short,
            qkv[(size_t)(b * Nrows + t0 + tl) * C3_ + 2 * C_ + h * HD_ + d]);
    }
    __syncthreads();
    for (int i = tid; i < 4096; i += 256) {
        int d = i >> 6, tl = i & 63;
        vT[((size_t)bh * 64 + d) * Nrows + t0 + tl] = __builtin_bit_cast(bf16, Ls[d][tl]);
    }
}

// ---------------- y2xw: y2x = x2y * rowsum * colinv (coalesced elementwise) ----------------
__global__ __launch_bounds__(256) void y2xw_kernel(
    const bf16* __restrict__ x2y, const float* __restrict__ rowsum_,
    const float* __restrict__ colinv, bf16* __restrict__ y2x)
{
    const int i = (blockIdx.x * 256 + threadIdx.x) * 8;   // 8,388,608 elements total
    const int row = i >> 8, m = i & 255, bh = row >> 10;
    const float rs = rowsum_[row];
    s8 v = *(const s8*)&x2y[i];
    const float4 c0 = *(const float4*)&colinv[bh * M_ + m];
    const float4 c4 = *(const float4*)&colinv[bh * M_ + m + 4];
    float ci[8] = {c0.x, c0.y, c0.z, c0.w, c4.x, c4.y, c4.z, c4.w};
    s8 r;
    #pragma unroll
    for (int j = 0; j < 8; ++j)
        r[j] = bfs(__bfloat162float(__builtin_bit_cast(bf16, v[j])) * rs * ci[j]);
    *(s8*)&y2x[i] = r;
}

// ---------------- flash6: paired-tile merged flash (R14/R15/R16-proven) ----------------
__global__ __launch_bounds__(512) void flash6_kernel(
    const bf16* __restrict__ x2y, const bf16* __restrict__ y2x,
    const bf16* __restrict__ vTx, const bf16* __restrict__ vTy,
    const bf16* __restrict__ qkv_x, const float* __restrict__ x,
    float* __restrict__ cval, bf16* __restrict__ cval_bf,
    float* __restrict__ sval, bf16* __restrict__ sval_bf)
{
    __shared__ short Kc[64][264];
    __shared__ short Ksf[64][72];
    __shared__ short Vb[64][72];
    __shared__ short Ps[8][16][68];
    const int tid = threadIdx.x;
    const int wave = tid >> 6, lane = tid & 63;
    const int quad = lane >> 4, l16 = lane & 15;
    const int bh = blockIdx.x, b = bh >> 3, h = bh & 7;
    const int p = blockIdx.y;
    const int jt = (wave < 4) ? p : (15 - p);
    const int rb = jt * 64 + (wave & 3) * 16;
    const int nst = 16 - p;

    s8 qc[8], qs[2];
    {
        const bf16* qp = x2y + (size_t)(bh * T_ + rb + l16) * M_ + quad * 8;
        #pragma unroll
        for (int f = 0; f < 8; ++f) qc[f] = *(const s8*)(qp + f * 32);
        const bf16* qsp = qkv_x + (size_t)(b * T_ + rb + l16) * C3_ + h * HD_ + quad * 8;
        qs[0] = *(const s8*)qsp;
        qs[1] = *(const s8*)(qsp + 32);
    }

    f4 ocv[4];
    #pragma unroll
    for (int dt = 0; dt < 4; ++dt) ocv[dt] = (f4)0.f;
    {
        const bf16* vb = vTy + (size_t)(bh * 64 + l16) * M_ + quad * 8;
        #pragma unroll
        for (int f = 0; f < 8; ++f)
            #pragma unroll
            for (int dt = 0; dt < 4; ++dt) {
                s8 bv = *(const s8*)(vb + (size_t)dt * 16 * M_ + f * 32);
                ocv[dt] = MFMA16(qc[f], bv, ocv[dt]);
            }
    }

    f4 oc[4], os_[4];
    float lc[4] = {0.f, 0.f, 0.f, 0.f}, ls_[4] = {0.f, 0.f, 0.f, 0.f};
    #pragma unroll
    for (int dt = 0; dt < 4; ++dt) { oc[dt] = (f4)0.f; os_[dt] = (f4)0.f; }

    #pragma unroll
    for (int tl = 0; tl < 4; ++tl) {
        int g = tid + tl * 512, row = g >> 5, grp = g & 31;
        *(s8*)&Kc[row][grp * 8] = *(const s8*)&y2x[(size_t)(bh * T_ + row) * M_ + grp * 8];
    }
    {
        int row = tid >> 3, grp = tid & 7;
        *(s8*)&Ksf[row][grp * 8] =
            *(const s8*)&qkv_x[(size_t)(b * T_ + row) * C3_ + C_ + h * HD_ + grp * 8];
        *(s8*)&Vb[row][grp * 8] = *(const s8*)&vTx[(size_t)(bh * 64 + row) * T_ + grp * 8];
    }
    __syncthreads();

    for (int st = 0; st < nst; ++st) {
        const int s0 = st * 64;
        const bool pf = (st + 1) < nst;
        s8 kcp[4], ksp, vp;
        if (pf) {
            const int sn = s0 + 64;
            #pragma unroll
            for (int tl = 0; tl < 4; ++tl) {
                int g = tid + tl * 512, row = g >> 5, grp = g & 31;
                kcp[tl] = *(const s8*)&y2x[(size_t)(bh * T_ + sn + row) * M_ + grp * 8];
            }
            int row = tid >> 3, grp = tid & 7;
            ksp = *(const s8*)&qkv_x[(size_t)(b * T_ + sn + row) * C3_ + C_ + h * HD_ + grp * 8];
            vp = *(const s8*)&vTx[(size_t)(bh * 64 + row) * T_ + sn + grp * 8];
        }
        if (st <= jt) {
            f4 sc[4];
            #pragma unroll
            for (int nt = 0; nt < 4; ++nt) sc[nt] = (f4)0.f;
            #pragma unroll
            for (int f = 0; f < 8; ++f)
                #pragma unroll
                for (int nt = 0; nt < 4; ++nt) {
                    s8 bv = *(const s8*)&Kc[nt * 16 + l16][f * 32 + quad * 8];
                    sc[nt] = MFMA16(qc[f], bv, sc[nt]);
                }
            f4 ss[4];
            #pragma unroll
            for (int nt = 0; nt < 4; ++nt) ss[nt] = (f4)0.f;
            #pragma unroll
            for (int f = 0; f < 2; ++f)
                #pragma unroll
                for (int nt = 0; nt < 4; ++nt) {
                    s8 bv = *(const s8*)&Ksf[nt * 16 + l16][f * 32 + quad * 8];
                    ss[nt] = MFMA16(qs[f], bv, ss[nt]);
                }
            #pragma unroll
            for (int reg = 0; reg < 4; ++reg) {
                const int t_g = rb + quad * 4 + reg;
                #pragma unroll
                for (int nt = 0; nt < 4; ++nt) {
                    float pv = (s0 + nt * 16 + l16 <= t_g) ? __expf(sc[nt][reg] * (1.f / 16.f)) : 0.f;
                    lc[reg] += pv;
                    Ps[wave][quad * 4 + reg][nt * 16 + l16] = bfs(pv);
                }
            }
            #pragma unroll
            for (int ks = 0; ks < 2; ++ks) {
                const short* pp = &Ps[wave][l16][ks * 32 + quad * 8];
                s4 alo = *(const s4*)pp;
                s4 ahi = *(const s4*)(pp + 4);
                s8 a;
                a[0] = alo[0]; a[1] = alo[1]; a[2] = alo[2]; a[3] = alo[3];
                a[4] = ahi[0]; a[5] = ahi[1]; a[6] = ahi[2]; a[7] = ahi[3];
                #pragma unroll
                for (int dt = 0; dt < 4; ++dt) {
                    s8 bv = *(const s8*)&Vb[dt * 16 + l16][ks * 32 + quad * 8];
                    oc[dt] = MFMA16(a, bv, oc[dt]);
                }
            }
            #pragma unroll
            for (int reg = 0; reg < 4; ++reg) {
                const int t_g = rb + quad * 4 + reg;
                #pragma unroll
                for (int nt = 0; nt < 4; ++nt) {
                    float pv = (s0 + nt * 16 + l16 <= t_g) ? __expf(ss[nt][reg] * 0.125f) : 0.f;
                    ls_[reg] += pv;
                    Ps[wave][quad * 4 + reg][nt * 16 + l16] = bfs(pv);
                }
            }
            #pragma unroll
            for (int ks = 0; ks < 2; ++ks) {
                const short* pp = &Ps[wave][l16][ks * 32 + quad * 8];
                s4 alo = *(const s4*)pp;
                s4 ahi = *(const s4*)(pp + 4);
                s8 a;
                a[0] = alo[0]; a[1] = alo[1]; a[2] = alo[2]; a[3] = alo[3];
                a[4] = ahi[0]; a[5] = ahi[1]; a[6] = ahi[2]; a[7] = ahi[3];
                #pragma unroll
                for (int dt = 0; dt < 4; ++dt) {
                    s8 bv = *(const s8*)&Vb[dt * 16 + l16][ks * 32 + quad * 8];
                    os_[dt] = MFMA16(a, bv, os_[dt]);
                }
            }
        }
        __syncthreads();
        if (pf) {
            #pragma unroll
            for (int tl = 0; tl < 4; ++tl) {
                int g = tid + tl * 512, row = g >> 5, grp = g & 31;
                *(s8*)&Kc[row][grp * 8] = kcp[tl];
            }
            int row = tid >> 3, grp = tid & 7;
            *(s8*)&Ksf[row][grp * 8] = ksp;
            *(s8*)&Vb[row][grp * 8] = vp;
        }
        __syncthreads();
    }

    #pragma unroll
    for (int reg = 0; reg < 4; ++reg) {
        float l1 = lc[reg], l2 = ls_[reg];
        l1 += __shfl_xor(l1, 1); l1 += __shfl_xor(l1, 2);
        l1 += __shfl_xor(l1, 4); l1 += __shfl_xor(l1, 8);
        l2 += __shfl_xor(l2, 1); l2 += __shfl_xor(l2, 2);
        l2 += __shfl_xor(l2, 4); l2 += __shfl_xor(l2, 8);
        const float i1 = 1.f / l1, i2 = 1.f / l2;
        const int t = rb + quad * 4 + reg;
        #pragma unroll
        for (int dt = 0; dt < 4; ++dt) {
            size_t idx = (size_t)(b * T_ + t) * C_ + h * HD_ + dt * 16 + l16;
            float cv = ocv[dt][reg] + oc[dt][reg] * i1 + x[idx];
            cval[idx] = cv;
            cval_bf[idx] = __float2bfloat16(cv);
            float sv = os_[dt][reg] * i2;
            sval[idx] = sv;
            sval_bf[idx] = __float2bfloat16(sv);
        }
    }
}

// ---------------- fused dual gate GEMM + sigmoid + combine -> gated bf16 ----------------
__global__ __launch_bounds__(256) void gatefuse_kernel(
    const bf16* __restrict__ svalb, const bf16* __restrict__ cvalb,
    const bf16* __restrict__ WTgs, const bf16* __restrict__ WTgc,
    const float* __restrict__ bgs, const float* __restrict__ bgc,
    const float* __restrict__ cval, const float* __restrict__ sval,
    bf16* __restrict__ gated)
{
    __shared__ short Sb[128][72], Cb[128][72], W1b[64][72], W2b[64][72];
    const int tid = threadIdx.x;
    const int wave = tid >> 6, lane = tid & 63;
    const int quad = lane >> 4, l16 = lane & 15;
    const int n0 = blockIdx.y * 64, m0 = blockIdx.x * 128;
    f4 aS[2][4], aC[2][4];
    #pragma unroll
    for (int mt = 0; mt < 2; ++mt)
        #pragma unroll
        for (int nt = 0; nt < 4; ++nt) { aS[mt][nt] = (f4)0.f; aC[mt][nt] = (f4)0.f; }

    for (int k0 = 0; k0 < C_; k0 += 64) {
        #pragma unroll
        for (int tl = 0; tl < 4; ++tl) {
            int g = tid + tl * 256, row = g >> 3, grp = g & 7;
            *(s8*)&Sb[row][grp * 8] = *(const s8*)&svalb[(size_t)(m0 + row) * C_ + k0 + grp * 8];
            *(s8*)&Cb[row][grp * 8] = *(const s8*)&cvalb[(size_t)(m0 + row) * C_ + k0 + grp * 8];
        }
        #pragma unroll
        for (int tl = 0; tl < 2; ++tl) {
            int g = tid + tl * 256, n = g >> 3, grp = g & 7;
            *(s8*)&W1b[n][grp * 8] = *(const s8*)&WTgs[(size_t)(n0 + n) * C_ + k0 + grp * 8];
            *(s8*)&W2b[n][grp * 8] = *(const s8*)&WTgc[(size_t)(n0 + n) * C_ + k0 + grp * 8];
        }
        __syncthreads();
        #pragma unroll
        for (int ks = 0; ks < 2; ++ks) {
            s8 s0f = *(const s8*)&Sb[wave * 32 + l16][ks * 32 + quad * 8];
            s8 s1f = *(const s8*)&Sb[wave * 32 + 16 + l16][ks * 32 + quad * 8];
            s8 c0f = *(const s8*)&Cb[wave * 32 + l16][ks * 32 + quad * 8];
            s8 c1f = *(const s8*)&Cb[wave * 32 + 16 + l16][ks * 32 + quad * 8];
            #pragma unroll
            for (int nt = 0; nt < 4; ++nt) {
                s8 w1 = *(const s8*)&W1b[nt * 16 + l16][ks * 32 + quad * 8];
                s8 w2 = *(const s8*)&W2b[nt * 16 + l16][ks * 32 + quad * 8];
                aS[0][nt] = MFMA16(s0f, w1, aS[0][nt]);
                aS[1][nt] = MFMA16(s1f, w1, aS[1][nt]);
                aC[0][nt] = MFMA16(c0f, w2, aC[0][nt]);
                aC[1][nt] = MFMA16(c1f, w2, aC[1][nt]);
            }
        }
        __syncthreads();
    }
    #pragma unroll
    for (int mt = 0; mt < 2; ++mt)
        #pragma unroll
        for (int nt = 0; nt < 4; ++nt) {
            int col = n0 + nt * 16 + l16;
            float b1 = bgs[col], b2 = bgc[col];
            #pragma unroll
            for (int reg = 0; reg < 4; ++reg) {
                int row = m0 + wave * 32 + mt * 16 + quad * 4 + reg;
                size_t idx = (size_t)row * C_ + col;
                float gs = 1.f / (1.f + __expf(-(aS[mt][nt][reg] + b1)));
                float gc = 1.f / (1.f + __expf(-(aC[mt][nt][reg] + b2)));
                gated[idx] = __float2bfloat16(gs * cval[idx] + gc * sval[idx]);
            }
        }
}

extern "C" void kernel_launch(void* const* d_in, const int* in_sizes, int n_in,
                              void* d_out, int out_size, void* d_ws, size_t ws_size,
                              hipStream_t stream)
{
    const float* x      = (const float*)d_in[0];
    const float* y      = (const float*)d_in[1];
    // d_in[2]: attn_x_mask — structurally causal tril, computed inline
    const float* Wqkv_x = (const float*)d_in[3];
    const float* bqkv_x = (const float*)d_in[4];
    const float* Wqkv_y = (const float*)d_in[5];
    const float* bqkv_y = (const float*)d_in[6];
    const float* w4x    = (const float*)d_in[7];
    const float* w4y    = (const float*)d_in[8];
    const float* w4xy   = (const float*)d_in[9];
    const float* Wgs    = (const float*)d_in[10];
    const float* bgs    = (const float*)d_in[11];
    const float* Wgc    = (const float*)d_in[12];
    const float* bgc    = (const float*)d_in[13];
    const float* Wp     = (const float*)d_in[14];
    const float* bp     = (const float*)d_in[15];

    // Workspace (f-word offsets; proven layout; catt fp32 region now only holds reuses)
    float* ws = (float*)d_ws;
    bf16*  qkv_x_bf = (bf16*)(ws + 0);           // 6,291,456 bf16
    bf16*  qkv_y_bf = (bf16*)(ws + 3145728);     // 1,572,864 bf16
    bf16*  gated_bf = (bf16*)(ws + 3932160);     // (old catt region)
    bf16*  cval_bf  = (bf16*)(ws + 5242880);
    bf16*  x2y_bf   = (bf16*)(ws + 12320768);    // 8,388,608 bf16 (written by catt3r)
    bf16*  x_bf     = x2y_bf;                    //   pre-QKV reuse
    bf16*  y_bf     = (bf16*)(ws + 13369344);    //   pre-QKV reuse
    bf16*  y2x_bf   = (bf16*)(ws + 16515072);    // 8,388,608 bf16 (written by y2xw)
    bf16*  vTx_bf   = (bf16*)(ws + 20709376);    // 2,097,152 bf16
    bf16*  vTy_bf   = (bf16*)(ws + 21757952);    // 524,288 bf16
    float* cval     = ws + 22020096;             // 2,097,152 f
    float* psum_    = cval;                      //   pre-cval reuse (catt3r colsums)
    float* sval     = ws + 24117248;             // 2,097,152 f
    bf16*  qw_bf    = (bf16*)(ws + 26214400);    // 2,097,152 bf16 (dead after catt3r)
    bf16*  sval_bf  = qw_bf;                     //   reuse
    bf16*  WT_x     = (bf16*)(ws + 27262976);    // 786,432 bf16
    bf16*  WT_y     = (bf16*)(ws + 27656192);
    bf16*  WT_gs    = (bf16*)(ws + 28049408);    // 262,144 bf16
    bf16*  WT_gc    = (bf16*)(ws + 28180480);
    bf16*  WT_p     = (bf16*)(ws + 28311552);
    float* catt1b   = ws + 28442624;             // 32,768 f
    float* catt2b   = ws + 28475392;             //  8,192 f
    float* colinv   = ws + 28483584;             //  8,192 f
    float* rowsum_  = ws + 28491776;             // 32,768 f

    // 0: one prep dispatch (5 transposes + 2 converts)
    prep_kernel<<<1856, 256, 0, stream>>>(
        Wqkv_x, Wqkv_y, Wgs, Wgc, Wp, x, y,
        WT_x, WT_y, WT_gs, WT_gc, WT_p, x_bf, y_bf);

    // 1-2: QKV projections (m-major grids for XCD A-locality)
    gemm_staged_kernel<bf16><<<dim3(32, 24), 256, 0, stream>>>(x_bf, WT_x, bqkv_x, qkv_x_bf, C3_, C_);
    gemm_staged_kernel<bf16><<<dim3(8, 24), 256, 0, stream>>>(y_bf, WT_y, bqkv_y, qkv_y_bf, C3_, C_);

    // 3: catt1/catt2/qw in one dispatch
    qwcatt_kernel<<<1184, 256, 0, stream>>>(
        qkv_x_bf, qkv_y_bf, w4x, w4y, w4xy, catt1b, catt2b, qw_bf);

    // 4: fused logits + row softmax -> x2y + rowsum + col partials (no fp32 catt)
    catt3r_kernel<<<dim3(32, 16), 256, 0, stream>>>(
        qw_bf, qkv_y_bf, catt1b, catt2b, x2y_bf, rowsum_, psum_);

    // 5: colfin + V transposes in one dispatch
    colfin_vtrans_kernel<<<672, 256, 0, stream>>>(psum_, colinv, qkv_x_bf, qkv_y_bf, vTx_bf, vTy_bf);

    // 6: y2x = x2y * rowsum * colinv
    y2xw_kernel<<<4096, 256, 0, stream>>>(x2y_bf, rowsum_, colinv, y2x_bf);

    // 7: paired-tile merged flash (XCD-swizzled)
    flash6_kernel<<<dim3(32, 8), 512, 0, stream>>>(
        x2y_bf, y2x_bf, vTx_bf, vTy_bf, qkv_x_bf, x, cval, cval_bf, sval, sval_bf);

    // 8: fused gates -> gated bf16
    gatefuse_kernel<<<dim3(32, 8), 256, 0, stream>>>(
        sval_bf, cval_bf, WT_gs, WT_gc, bgs, bgc, cval, sval, gated_bf);

    // 9: out = gated @ Wp + bp
    gemm_staged_kernel<float><<<dim3(32, 8), 256, 0, stream>>>(
        gated_bf, WT_p, bp, (float*)d_out, C_, C_);
}

// Round 18
// 223.419 us; speedup vs baseline: 1.3271x; 1.0128x over previous
//
#include <hip/hip_runtime.h>
#include <hip/hip_bf16.h>

typedef __hip_bfloat16 bf16;
using f4 = __attribute__((ext_vector_type(4))) float;
using s8 = __attribute__((ext_vector_type(8))) short;
using s4 = __attribute__((ext_vector_type(4))) short;

__device__ __forceinline__ void storeOut(float* p, float v) { *p = v; }
__device__ __forceinline__ void storeOut(bf16* p, float v) { *p = __float2bfloat16(v); }
__device__ __forceinline__ short bfs(float x) { return __builtin_bit_cast(short, __float2bfloat16(x)); }
__device__ __forceinline__ float fbs(short x) { return __bfloat162float(__builtin_bit_cast(bf16, x)); }

constexpr int B_ = 4, T_ = 1024, M_ = 256, C_ = 512, H_ = 8, HD_ = 64, C3_ = 1536;

#define MFMA16(a, b, c) __builtin_amdgcn_mfma_f32_16x16x32_bf16((a), (b), (c), 0, 0, 0)

// ---------------- prep: 5 weight transposes (fp32 KxN -> bf16 NxK) + 2 converts ----------------
__global__ __launch_bounds__(256) void prep_kernel(
    const float* __restrict__ Wqkv_x, const float* __restrict__ Wqkv_y,
    const float* __restrict__ Wgs, const float* __restrict__ Wgc, const float* __restrict__ Wp,
    const float* __restrict__ x, const float* __restrict__ y,
    bf16* __restrict__ WT_x, bf16* __restrict__ WT_y, bf16* __restrict__ WT_gs,
    bf16* __restrict__ WT_gc, bf16* __restrict__ WT_p,
    bf16* __restrict__ x_bf, bf16* __restrict__ y_bf)
{
    __shared__ float Ls[64][65];
    const int tid = threadIdx.x;
    const int bid = blockIdx.x;
    if (bid < 576) {
        const float* W; bf16* WT; int N, t;
        if (bid < 192)      { W = Wqkv_x; WT = WT_x;  N = C3_; t = bid; }
        else if (bid < 384) { W = Wqkv_y; WT = WT_y;  N = C3_; t = bid - 192; }
        else if (bid < 448) { W = Wgs;    WT = WT_gs; N = C_;  t = bid - 384; }
        else if (bid < 512) { W = Wgc;    WT = WT_gc; N = C_;  t = bid - 448; }
        else                { W = Wp;     WT = WT_p;  N = C_;  t = bid - 512; }
        const int K = C_;
        const int tw = N >> 6;
        const int n0 = (t % tw) * 64, k0 = (t / tw) * 64;
        for (int i = tid; i < 1024; i += 256) {
            int kr = i >> 4, ng = i & 15;
            float4 v = *(const float4*)&W[(size_t)(k0 + kr) * N + n0 + ng * 4];
            Ls[ng * 4 + 0][kr] = v.x; Ls[ng * 4 + 1][kr] = v.y;
            Ls[ng * 4 + 2][kr] = v.z; Ls[ng * 4 + 3][kr] = v.w;
        }
        __syncthreads();
        for (int i = tid; i < 512; i += 256) {
            int n = i >> 3, kg = i & 7;
            s8 r;
            #pragma unroll
            for (int j = 0; j < 8; ++j) r[j] = bfs(Ls[n][kg * 8 + j]);
            *(s8*)&WT[(size_t)(n0 + n) * K + k0 + kg * 8] = r;
        }
    } else if (bid < 1600) {
        int i = (bid - 576) * 2048 + tid * 8;
        s8 r;
        #pragma unroll
        for (int j = 0; j < 8; ++j) r[j] = bfs(x[i + j]);
        *(s8*)&x_bf[i] = r;
    } else {
        int i = (bid - 1600) * 2048 + tid * 8;
        s8 r;
        #pragma unroll
        for (int j = 0; j < 8; ++j) r[j] = bfs(y[i + j]);
        *(s8*)&y_bf[i] = r;
    }
}

// ---------------- merged catt1/catt2 + qw (one dispatch) ----------------
__global__ __launch_bounds__(256) void qwcatt_kernel(
    const bf16* __restrict__ qkv_x, const bf16* __restrict__ qkv_y,
    const float* __restrict__ w4x, const float* __restrict__ w4y,
    const float* __restrict__ w4xy,
    float* __restrict__ catt1b, float* __restrict__ catt2b, bf16* __restrict__ qw)
{
    const int bid = blockIdx.x;
    const int tid = threadIdx.x;
    if (bid < 160) {
        int i = bid * 256 + tid;   // 0..40959
        const bf16* row; const float* w; float* out; int oi;
        if (i < 32768) {
            int bh = i >> 10, t = i & 1023, b = bh >> 3, h = bh & 7;
            row = qkv_x + (size_t)(b * T_ + t) * C3_ + h * HD_;
            w = w4x + h * HD_; out = catt1b; oi = i;
        } else {
            int j = i - 32768;
            int bh = j >> 8, m = j & 255, b = bh >> 3, h = bh & 7;
            row = qkv_y + (size_t)(b * M_ + m) * C3_ + h * HD_;
            w = w4y + h * HD_; out = catt2b; oi = j;
        }
        float s = 0.f;
        #pragma unroll
        for (int d = 0; d < HD_; ++d) s = fmaf(__bfloat162float(row[d]), w[d], s);
        out[oi] = s;
    } else {
        int o = ((bid - 160) * 256 + tid) * 8;
        int row = o >> 9, c = o & 511;
        const bf16* src = qkv_x + (size_t)row * C3_ + c;
        s8 r;
        #pragma unroll
        for (int j = 0; j < 8; ++j) r[j] = bfs(__bfloat162float(src[j]) * w4xy[c + j]);
        *(s8*)&qw[o] = r;
    }
}

// ---------------- LDS-staged MFMA GEMM (m-major grid) ----------------
template <typename OT>
__global__ __launch_bounds__(256) void gemm_staged_kernel(
    const bf16* __restrict__ A, const bf16* __restrict__ WT, const float* __restrict__ bias,
    OT* __restrict__ Cmat, int N, int K)
{
    __shared__ short Asb[128][72];
    __shared__ short Bsb[64][72];
    const int tid = threadIdx.x;
    const int wave = tid >> 6, lane = tid & 63;
    const int quad = lane >> 4, l16 = lane & 15;
    const int n0 = blockIdx.y * 64, m0 = blockIdx.x * 128;
    f4 acc[2][4];
    #pragma unroll
    for (int mt = 0; mt < 2; ++mt)
        #pragma unroll
        for (int nt = 0; nt < 4; ++nt) acc[mt][nt] = (f4)0.f;

    for (int k0 = 0; k0 < K; k0 += 64) {
        #pragma unroll
        for (int tl = 0; tl < 4; ++tl) {
            int g = tid + tl * 256, row = g >> 3, grp = g & 7;
            *(s8*)&Asb[row][grp * 8] = *(const s8*)&A[(size_t)(m0 + row) * K + k0 + grp * 8];
        }
        #pragma unroll
        for (int tl = 0; tl < 2; ++tl) {
            int g = tid + tl * 256, n = g >> 3, grp = g & 7;
            *(s8*)&Bsb[n][grp * 8] = *(const s8*)&WT[(size_t)(n0 + n) * K + k0 + grp * 8];
        }
        __syncthreads();
        #pragma unroll
        for (int ks = 0; ks < 2; ++ks) {
            s8 a0 = *(const s8*)&Asb[wave * 32 + l16][ks * 32 + quad * 8];
            s8 a1 = *(const s8*)&Asb[wave * 32 + 16 + l16][ks * 32 + quad * 8];
            #pragma unroll
            for (int nt = 0; nt < 4; ++nt) {
                s8 bv = *(const s8*)&Bsb[nt * 16 + l16][ks * 32 + quad * 8];
                acc[0][nt] = MFMA16(a0, bv, acc[0][nt]);
                acc[1][nt] = MFMA16(a1, bv, acc[1][nt]);
            }
        }
        __syncthreads();
    }
    #pragma unroll
    for (int mt = 0; mt < 2; ++mt)
        #pragma unroll
        for (int nt = 0; nt < 4; ++nt) {
            int col = n0 + nt * 16 + l16;
            float bb = bias[col];
            #pragma unroll
            for (int reg = 0; reg < 4; ++reg) {
                int row = m0 + wave * 32 + mt * 16 + quad * 4 + reg;
                storeOut(&Cmat[(size_t)row * N + col], acc[mt][nt][reg] + bb);
            }
        }
}

// ---------------- catt3r: logits + row softmax -> x2y bf16 + rowsum + col partial sums ----------------
__global__ __launch_bounds__(256) void catt3r_kernel(
    const bf16* __restrict__ qw, const bf16* __restrict__ qkv_y,
    const float* __restrict__ catt1, const float* __restrict__ catt2,
    bf16* __restrict__ x2y, float* __restrict__ rowsum_, float* __restrict__ psum)
{
    __shared__ float redc[4][256];
    const int tid = threadIdx.x;
    const int wave = tid >> 6, lane = tid & 63;
    const int quad = lane >> 4, l16 = lane & 15;
    const int bh = blockIdx.x, b = bh >> 3, h = bh & 7;
    const int t0 = blockIdx.y * 64;
    f4 sc[4][4];
    #pragma unroll
    for (int mt = 0; mt < 4; ++mt)
        #pragma unroll
        for (int nt = 0; nt < 4; ++nt) sc[mt][nt] = (f4)0.f;

    const bf16* ap = qw + (size_t)(b * T_ + t0 + wave * 16 + l16) * C_ + h * HD_ + quad * 8;
    s8 a0 = *(const s8*)ap;
    s8 a1 = *(const s8*)(ap + 32);
    const bf16* bp = qkv_y + (size_t)(b * M_ + l16) * C3_ + C_ + h * HD_ + quad * 8;
    #pragma unroll
    for (int mt = 0; mt < 4; ++mt)
        #pragma unroll
        for (int nt = 0; nt < 4; ++nt) {
            const bf16* bq = bp + (size_t)(mt * 64 + nt * 16) * C3_;
            sc[mt][nt] = MFMA16(a0, *(const s8*)bq, sc[mt][nt]);
            sc[mt][nt] = MFMA16(a1, *(const s8*)(bq + 32), sc[mt][nt]);
        }

    float c1[4];
    #pragma unroll
    for (int reg = 0; reg < 4; ++reg)
        c1[reg] = catt1[bh * T_ + t0 + wave * 16 + quad * 4 + reg];
    #pragma unroll
    for (int mt = 0; mt < 4; ++mt)
        #pragma unroll
        for (int nt = 0; nt < 4; ++nt) {
            float c2 = catt2[bh * M_ + mt * 64 + nt * 16 + l16];
            #pragma unroll
            for (int reg = 0; reg < 4; ++reg)
                sc[mt][nt][reg] = __expf(sc[mt][nt][reg] * 0.125f + c1[reg] + c2);
        }

    #pragma unroll
    for (int reg = 0; reg < 4; ++reg) {
        float rs = 0.f;
        #pragma unroll
        for (int mt = 0; mt < 4; ++mt)
            #pragma unroll
            for (int nt = 0; nt < 4; ++nt) rs += sc[mt][nt][reg];
        rs += __shfl_xor(rs, 1); rs += __shfl_xor(rs, 2);
        rs += __shfl_xor(rs, 4); rs += __shfl_xor(rs, 8);
        const int t = t0 + wave * 16 + quad * 4 + reg;
        if (l16 == 0) rowsum_[bh * T_ + t] = rs;
        const float ri = 1.f / rs;
        #pragma unroll
        for (int mt = 0; mt < 4; ++mt)
            #pragma unroll
            for (int nt = 0; nt < 4; ++nt)
                x2y[((size_t)bh * T_ + t) * M_ + mt * 64 + nt * 16 + l16] =
                    __float2bfloat16(sc[mt][nt][reg] * ri);
    }

    #pragma unroll
    for (int mt = 0; mt < 4; ++mt)
        #pragma unroll
        for (int nt = 0; nt < 4; ++nt) {
            float es = sc[mt][nt][0] + sc[mt][nt][1] + sc[mt][nt][2] + sc[mt][nt][3];
            es += __shfl_xor(es, 16);
            es += __shfl_xor(es, 32);
            if (quad == 0) redc[wave][mt * 64 + nt * 16 + l16] = es;
        }
    __syncthreads();
    psum[((size_t)bh * 16 + blockIdx.y) * M_ + tid] =
        redc[0][tid] + redc[1][tid] + redc[2][tid] + redc[3][tid];
}

// ---------------- merged colfin + V transposes (one dispatch) ----------------
__global__ __launch_bounds__(256) void colfin_vtrans_kernel(
    const float* __restrict__ psum, float* __restrict__ colinv,
    const bf16* __restrict__ qkv_x, const bf16* __restrict__ qkv_y,
    bf16* __restrict__ vTx, bf16* __restrict__ vTy)
{
    __shared__ short Ls[64][68];
    const int tid = threadIdx.x;
    int bid = blockIdx.x;
    if (bid < 32) {
        const int bh = bid, m = tid;
        float s = 0.f;
        #pragma unroll
        for (int ch = 0; ch < 16; ++ch) s += psum[(bh * 16 + ch) * M_ + m];
        colinv[bh * M_ + m] = 1.f / s;
        return;
    }
    bid -= 32;
    const bf16* qkv; bf16* vT; int Nrows, bh, t0;
    if (bid < 512) { qkv = qkv_x; vT = vTx; Nrows = T_; bh = bid >> 4; t0 = (bid & 15) * 64; }
    else { bid -= 512; qkv = qkv_y; vT = vTy; Nrows = M_; bh = bid >> 2; t0 = (bid & 3) * 64; }
    const int b = bh >> 3, h = bh & 7;
    for (int i = tid; i < 4096; i += 256) {
        int tl = i >> 6, d = i & 63;
        Ls[d][tl] = __builtin_bit_cast(short,
            qkv[(size_t)(b * Nrows + t0 + tl) * C3_ + 2 * C_ + h * HD_ + d]);
    }
    __syncthreads();
    for (int i = tid; i < 4096; i += 256) {
        int d = i >> 6, tl = i & 63;
        vT[((size_t)bh * 64 + d) * Nrows + t0 + tl] = __builtin_bit_cast(bf16, Ls[d][tl]);
    }
}

// ---------------- y2xw: y2x = x2y * rowsum * colinv ----------------
__global__ __launch_bounds__(256) void y2xw_kernel(
    const bf16* __restrict__ x2y, const float* __restrict__ rowsum_,
    const float* __restrict__ colinv, bf16* __restrict__ y2x)
{
    const int i = (blockIdx.x * 256 + threadIdx.x) * 8;
    const int row = i >> 8, m = i & 255, bh = row >> 10;
    const float rs = rowsum_[row];
    s8 v = *(const s8*)&x2y[i];
    const float4 c0 = *(const float4*)&colinv[bh * M_ + m];
    const float4 c4 = *(const float4*)&colinv[bh * M_ + m + 4];
    float ci[8] = {c0.x, c0.y, c0.z, c0.w, c4.x, c4.y, c4.z, c4.w};
    s8 r;
    #pragma unroll
    for (int j = 0; j < 8; ++j)
        r[j] = bfs(__bfloat162float(__builtin_bit_cast(bf16, v[j])) * rs * ci[j]);
    *(s8*)&y2x[i] = r;
}

// ---------------- flash7: paired-tile flash, DOUBLE-BUFFERED, one barrier/tile ----------------
// flash6 ported to R8's proven dbuf pattern: Kc/Ksf/Vb x2 (LDS 121.8 KB, still 1 block/CU
// since grid=256), prefetch lands in buf cur^1, ONE __syncthreads per iteration
// (protects both prior reads and current writes). Outputs bf16 only (fp32 dropped).
__global__ __launch_bounds__(512) void flash7_kernel(
    const bf16* __restrict__ x2y, const bf16* __restrict__ y2x,
    const bf16* __restrict__ vTx, const bf16* __restrict__ vTy,
    const bf16* __restrict__ qkv_x, const float* __restrict__ x,
    bf16* __restrict__ cval_bf, bf16* __restrict__ sval_bf)
{
    __shared__ short Kc[2][64][264];
    __shared__ short Ksf[2][64][72];
    __shared__ short Vb[2][64][72];
    __shared__ short Ps[8][16][68];
    const int tid = threadIdx.x;
    const int wave = tid >> 6, lane = tid & 63;
    const int quad = lane >> 4, l16 = lane & 15;
    const int bh = blockIdx.x, b = bh >> 3, h = bh & 7;
    const int p = blockIdx.y;
    const int jt = (wave < 4) ? p : (15 - p);
    const int rb = jt * 64 + (wave & 3) * 16;
    const int nst = 16 - p;

    s8 qc[8], qs[2];
    {
        const bf16* qp = x2y + (size_t)(bh * T_ + rb + l16) * M_ + quad * 8;
        #pragma unroll
        for (int f = 0; f < 8; ++f) qc[f] = *(const s8*)(qp + f * 32);
        const bf16* qsp = qkv_x + (size_t)(b * T_ + rb + l16) * C3_ + h * HD_ + quad * 8;
        qs[0] = *(const s8*)qsp;
        qs[1] = *(const s8*)(qsp + 32);
    }

    f4 ocv[4];
    #pragma unroll
    for (int dt = 0; dt < 4; ++dt) ocv[dt] = (f4)0.f;
    {
        const bf16* vb = vTy + (size_t)(bh * 64 + l16) * M_ + quad * 8;
        #pragma unroll
        for (int f = 0; f < 8; ++f)
            #pragma unroll
            for (int dt = 0; dt < 4; ++dt) {
                s8 bv = *(const s8*)(vb + (size_t)dt * 16 * M_ + f * 32);
                ocv[dt] = MFMA16(qc[f], bv, ocv[dt]);
            }
    }

    f4 oc[4], os_[4];
    float lc[4] = {0.f, 0.f, 0.f, 0.f}, ls_[4] = {0.f, 0.f, 0.f, 0.f};
    #pragma unroll
    for (int dt = 0; dt < 4; ++dt) { oc[dt] = (f4)0.f; os_[dt] = (f4)0.f; }

    // prologue: stage tile 0 into buffer 0
    #pragma unroll
    for (int tl = 0; tl < 4; ++tl) {
        int g = tid + tl * 512, row = g >> 5, grp = g & 31;
        *(s8*)&Kc[0][row][grp * 8] = *(const s8*)&y2x[(size_t)(bh * T_ + row) * M_ + grp * 8];
    }
    {
        int row = tid >> 3, grp = tid & 7;
        *(s8*)&Ksf[0][row][grp * 8] =
            *(const s8*)&qkv_x[(size_t)(b * T_ + row) * C3_ + C_ + h * HD_ + grp * 8];
        *(s8*)&Vb[0][row][grp * 8] = *(const s8*)&vTx[(size_t)(bh * 64 + row) * T_ + grp * 8];
    }
    __syncthreads();

    for (int st = 0; st < nst; ++st) {
        const int cur = st & 1;
        const int s0 = st * 64;
        const bool pf = (st + 1) < nst;
        s8 kcp[4], ksp, vp;
        if (pf) {
            const int sn = s0 + 64;
            #pragma unroll
            for (int tl = 0; tl < 4; ++tl) {
                int g = tid + tl * 512, row = g >> 5, grp = g & 31;
                kcp[tl] = *(const s8*)&y2x[(size_t)(bh * T_ + sn + row) * M_ + grp * 8];
            }
            int row = tid >> 3, grp = tid & 7;
            ksp = *(const s8*)&qkv_x[(size_t)(b * T_ + sn + row) * C3_ + C_ + h * HD_ + grp * 8];
            vp = *(const s8*)&vTx[(size_t)(bh * 64 + row) * T_ + sn + grp * 8];
        }
        if (st <= jt) {
            f4 sc[4];
            #pragma unroll
            for (int nt = 0; nt < 4; ++nt) sc[nt] = (f4)0.f;
            #pragma unroll
            for (int f = 0; f < 8; ++f)
                #pragma unroll
                for (int nt = 0; nt < 4; ++nt) {
                    s8 bv = *(const s8*)&Kc[cur][nt * 16 + l16][f * 32 + quad * 8];
                    sc[nt] = MFMA16(qc[f], bv, sc[nt]);
                }
            f4 ss[4];
            #pragma unroll
            for (int nt = 0; nt < 4; ++nt) ss[nt] = (f4)0.f;
            #pragma unroll
            for (int f = 0; f < 2; ++f)
                #pragma unroll
                for (int nt = 0; nt < 4; ++nt) {
                    s8 bv = *(const s8*)&Ksf[cur][nt * 16 + l16][f * 32 + quad * 8];
                    ss[nt] = MFMA16(qs[f], bv, ss[nt]);
                }
            #pragma unroll
            for (int reg = 0; reg < 4; ++reg) {
                const int t_g = rb + quad * 4 + reg;
                #pragma unroll
                for (int nt = 0; nt < 4; ++nt) {
                    float pv = (s0 + nt * 16 + l16 <= t_g) ? __expf(sc[nt][reg] * (1.f / 16.f)) : 0.f;
                    lc[reg] += pv;
                    Ps[wave][quad * 4 + reg][nt * 16 + l16] = bfs(pv);
                }
            }
            #pragma unroll
            for (int ks = 0; ks < 2; ++ks) {
                const short* pp = &Ps[wave][l16][ks * 32 + quad * 8];
                s4 alo = *(const s4*)pp;
                s4 ahi = *(const s4*)(pp + 4);
                s8 a;
                a[0] = alo[0]; a[1] = alo[1]; a[2] = alo[2]; a[3] = alo[3];
                a[4] = ahi[0]; a[5] = ahi[1]; a[6] = ahi[2]; a[7] = ahi[3];
                #pragma unroll
                for (int dt = 0; dt < 4; ++dt) {
                    s8 bv = *(const s8*)&Vb[cur][dt * 16 + l16][ks * 32 + quad * 8];
                    oc[dt] = MFMA16(a, bv, oc[dt]);
                }
            }
            #pragma unroll
            for (int reg = 0; reg < 4; ++reg) {
                const int t_g = rb + quad * 4 + reg;
                #pragma unroll
                for (int nt = 0; nt < 4; ++nt) {
                    float pv = (s0 + nt * 16 + l16 <= t_g) ? __expf(ss[nt][reg] * 0.125f) : 0.f;
                    ls_[reg] += pv;
                    Ps[wave][quad * 4 + reg][nt * 16 + l16] = bfs(pv);
                }
            }
            #pragma unroll
            for (int ks = 0; ks < 2; ++ks) {
                const short* pp = &Ps[wave][l16][ks * 32 + quad * 8];
                s4 alo = *(const s4*)pp;
                s4 ahi = *(const s4*)(pp + 4);
                s8 a;
                a[0] = alo[0]; a[1] = alo[1]; a[2] = alo[2]; a[3] = alo[3];
                a[4] = ahi[0]; a[5] = ahi[1]; a[6] = ahi[2]; a[7] = ahi[3];
                #pragma unroll
                for (int dt = 0; dt < 4; ++dt) {
                    s8 bv = *(const s8*)&Vb[cur][dt * 16 + l16][ks * 32 + quad * 8];
                    os_[dt] = MFMA16(a, bv, os_[dt]);
                }
            }
        }
        if (pf) {
            const int nxt = cur ^ 1;
            #pragma unroll
            for (int tl = 0; tl < 4; ++tl) {
                int g = tid + tl * 512, row = g >> 5, grp = g & 31;
                *(s8*)&Kc[nxt][row][grp * 8] = kcp[tl];
            }
            int row = tid >> 3, grp = tid & 7;
            *(s8*)&Ksf[nxt][row][grp * 8] = ksp;
            *(s8*)&Vb[nxt][row][grp * 8] = vp;
        }
        __syncthreads();   // single barrier: protects prior-iter reads AND this-iter writes
    }

    #pragma unroll
    for (int reg = 0; reg < 4; ++reg) {
        float l1 = lc[reg], l2 = ls_[reg];
        l1 += __shfl_xor(l1, 1); l1 += __shfl_xor(l1, 2);
        l1 += __shfl_xor(l1, 4); l1 += __shfl_xor(l1, 8);
        l2 += __shfl_xor(l2, 1); l2 += __shfl_xor(l2, 2);
        l2 += __shfl_xor(l2, 4); l2 += __shfl_xor(l2, 8);
        const float i1 = 1.f / l1, i2 = 1.f / l2;
        const int t = rb + quad * 4 + reg;
        #pragma unroll
        for (int dt = 0; dt < 4; ++dt) {
            size_t idx = (size_t)(b * T_ + t) * C_ + h * HD_ + dt * 16 + l16;
            float cv = ocv[dt][reg] + oc[dt][reg] * i1 + x[idx];
            cval_bf[idx] = __float2bfloat16(cv);
            float sv = os_[dt][reg] * i2;
            sval_bf[idx] = __float2bfloat16(sv);
        }
    }
}

// ---------------- fused dual gate GEMM + sigmoid + combine -> gated bf16 ----------------
// Elementwise combine now reads the bf16 cval/sval (fp32 copies eliminated).
__global__ __launch_bounds__(256) void gatefuse_kernel(
    const bf16* __restrict__ svalb, const bf16* __restrict__ cvalb,
    const bf16* __restrict__ WTgs, const bf16* __restrict__ WTgc,
    const float* __restrict__ bgs, const float* __restrict__ bgc,
    bf16* __restrict__ gated)
{
    __shared__ short Sb[128][72], Cb[128][72], W1b[64][72], W2b[64][72];
    const int tid = threadIdx.x;
    const int wave = tid >> 6, lane = tid & 63;
    const int quad = lane >> 4, l16 = lane & 15;
    const int n0 = blockIdx.y * 64, m0 = blockIdx.x * 128;
    f4 aS[2][4], aC[2][4];
    #pragma unroll
    for (int mt = 0; mt < 2; ++mt)
        #pragma unroll
        for (int nt = 0; nt < 4; ++nt) { aS[mt][nt] = (f4)0.f; aC[mt][nt] = (f4)0.f; }

    for (int k0 = 0; k0 < C_; k0 += 64) {
        #pragma unroll
        for (int tl = 0; tl < 4; ++tl) {
            int g = tid + tl * 256, row = g >> 3, grp = g & 7;
            *(s8*)&Sb[row][grp * 8] = *(const s8*)&svalb[(size_t)(m0 + row) * C_ + k0 + grp * 8];
            *(s8*)&Cb[row][grp * 8] = *(const s8*)&cvalb[(size_t)(m0 + row) * C_ + k0 + grp * 8];
        }
        #pragma unroll
        for (int tl = 0; tl < 2; ++tl) {
            int g = tid + tl * 256, n = g >> 3, grp = g & 7;
            *(s8*)&W1b[n][grp * 8] = *(const s8*)&WTgs[(size_t)(n0 + n) * C_ + k0 + grp * 8];
            *(s8*)&W2b[n][grp * 8] = *(const s8*)&WTgc[(size_t)(n0 + n) * C_ + k0 + grp * 8];
        }
        __syncthreads();
        #pragma unroll
        for (int ks = 0; ks < 2; ++ks) {
            s8 s0f = *(const s8*)&Sb[wave * 32 + l16][ks * 32 + quad * 8];
            s8 s1f = *(const s8*)&Sb[wave * 32 + 16 + l16][ks * 32 + quad * 8];
            s8 c0f = *(const s8*)&Cb[wave * 32 + l16][ks * 32 + quad * 8];
            s8 c1f = *(const s8*)&Cb[wave * 32 + 16 + l16][ks * 32 + quad * 8];
            #pragma unroll
            for (int nt = 0; nt < 4; ++nt) {
                s8 w1 = *(const s8*)&W1b[nt * 16 + l16][ks * 32 + quad * 8];
                s8 w2 = *(const s8*)&W2b[nt * 16 + l16][ks * 32 + quad * 8];
                aS[0][nt] = MFMA16(s0f, w1, aS[0][nt]);
                aS[1][nt] = MFMA16(s1f, w1, aS[1][nt]);
                aC[0][nt] = MFMA16(c0f, w2, aC[0][nt]);
                aC[1][nt] = MFMA16(c1f, w2, aC[1][nt]);
            }
        }
        __syncthreads();
    }
    #pragma unroll
    for (int mt = 0; mt < 2; ++mt)
        #pragma unroll
        for (int nt = 0; nt < 4; ++nt) {
            int col = n0 + nt * 16 + l16;
            float b1 = bgs[col], b2 = bgc[col];
            #pragma unroll
            for (int reg = 0; reg < 4; ++reg) {
                int row = m0 + wave * 32 + mt * 16 + quad * 4 + reg;
                size_t idx = (size_t)row * C_ + col;
                float gs = 1.f / (1.f + __expf(-(aS[mt][nt][reg] + b1)));
                float gc = 1.f / (1.f + __expf(-(aC[mt][nt][reg] + b2)));
                float cvv = __bfloat162float(cvalb[idx]);
                float svv = __bfloat162float(svalb[idx]);
                gated[idx] = __float2bfloat16(gs * cvv + gc * svv);
            }
        }
}

extern "C" void kernel_launch(void* const* d_in, const int* in_sizes, int n_in,
                              void* d_out, int out_size, void* d_ws, size_t ws_size,
                              hipStream_t stream)
{
    const float* x      = (const float*)d_in[0];
    const float* y      = (const float*)d_in[1];
    // d_in[2]: attn_x_mask — structurally causal tril, computed inline
    const float* Wqkv_x = (const float*)d_in[3];
    const float* bqkv_x = (const float*)d_in[4];
    const float* Wqkv_y = (const float*)d_in[5];
    const float* bqkv_y = (const float*)d_in[6];
    const float* w4x    = (const float*)d_in[7];
    const float* w4y    = (const float*)d_in[8];
    const float* w4xy   = (const float*)d_in[9];
    const float* Wgs    = (const float*)d_in[10];
    const float* bgs    = (const float*)d_in[11];
    const float* Wgc    = (const float*)d_in[12];
    const float* bgc    = (const float*)d_in[13];
    const float* Wp     = (const float*)d_in[14];
    const float* bp     = (const float*)d_in[15];

    // Workspace (f-word offsets; proven layout)
    float* ws = (float*)d_ws;
    bf16*  qkv_x_bf = (bf16*)(ws + 0);           // 6,291,456 bf16
    bf16*  qkv_y_bf = (bf16*)(ws + 3145728);     // 1,572,864 bf16
    bf16*  gated_bf = (bf16*)(ws + 3932160);
    bf16*  cval_bf  = (bf16*)(ws + 5242880);
    bf16*  x2y_bf   = (bf16*)(ws + 12320768);    // 8,388,608 bf16 (written by catt3r)
    bf16*  x_bf     = x2y_bf;                    //   pre-QKV reuse
    bf16*  y_bf     = (bf16*)(ws + 13369344);    //   pre-QKV reuse
    bf16*  y2x_bf   = (bf16*)(ws + 16515072);    // 8,388,608 bf16 (written by y2xw)
    bf16*  vTx_bf   = (bf16*)(ws + 20709376);    // 2,097,152 bf16
    bf16*  vTy_bf   = (bf16*)(ws + 21757952);    // 524,288 bf16
    float* psum_    = ws + 22020096;             // 131,072 f (old cval region)
    bf16*  qw_bf    = (bf16*)(ws + 26214400);    // 2,097,152 bf16 (dead after catt3r)
    bf16*  sval_bf  = qw_bf;                     //   reuse
    bf16*  WT_x     = (bf16*)(ws + 27262976);    // 786,432 bf16
    bf16*  WT_y     = (bf16*)(ws + 27656192);
    bf16*  WT_gs    = (bf16*)(ws + 28049408);    // 262,144 bf16
    bf16*  WT_gc    = (bf16*)(ws + 28180480);
    bf16*  WT_p     = (bf16*)(ws + 28311552);
    float* catt1b   = ws + 28442624;             // 32,768 f
    float* catt2b   = ws + 28475392;             //  8,192 f
    float* colinv   = ws + 28483584;             //  8,192 f
    float* rowsum_  = ws + 28491776;             // 32,768 f

    // 0: one prep dispatch
    prep_kernel<<<1856, 256, 0, stream>>>(
        Wqkv_x, Wqkv_y, Wgs, Wgc, Wp, x, y,
        WT_x, WT_y, WT_gs, WT_gc, WT_p, x_bf, y_bf);

    // 1-2: QKV projections
    gemm_staged_kernel<bf16><<<dim3(32, 24), 256, 0, stream>>>(x_bf, WT_x, bqkv_x, qkv_x_bf, C3_, C_);
    gemm_staged_kernel<bf16><<<dim3(8, 24), 256, 0, stream>>>(y_bf, WT_y, bqkv_y, qkv_y_bf, C3_, C_);

    // 3: catt1/catt2/qw
    qwcatt_kernel<<<1184, 256, 0, stream>>>(
        qkv_x_bf, qkv_y_bf, w4x, w4y, w4xy, catt1b, catt2b, qw_bf);

    // 4: fused logits + row softmax -> x2y + rowsum + col partials
    catt3r_kernel<<<dim3(32, 16), 256, 0, stream>>>(
        qw_bf, qkv_y_bf, catt1b, catt2b, x2y_bf, rowsum_, psum_);

    // 5: colfin + V transposes
    colfin_vtrans_kernel<<<672, 256, 0, stream>>>(psum_, colinv, qkv_x_bf, qkv_y_bf, vTx_bf, vTy_bf);

    // 6: y2x = x2y * rowsum * colinv
    y2xw_kernel<<<4096, 256, 0, stream>>>(x2y_bf, rowsum_, colinv, y2x_bf);

    // 7: paired-tile flash, double-buffered, bf16-only outputs
    flash7_kernel<<<dim3(32, 8), 512, 0, stream>>>(
        x2y_bf, y2x_bf, vTx_bf, vTy_bf, qkv_x_bf, x, cval_bf, sval_bf);

    // 8: fused gates (bf16 elementwise)
    gatefuse_kernel<<<dim3(32, 8), 256, 0, stream>>>(
        sval_bf, cval_bf, WT_gs, WT_gc, bgs, bgc, gated_bf);

    // 9: out = gated @ Wp + bp
    gemm_staged_kernel<float><<<dim3(32, 8), 256, 0, stream>>>(
        gated_bf, WT_p, bp, (float*)d_out, C_, C_);
}

// Round 19
// 222.105 us; speedup vs baseline: 1.3349x; 1.0059x over previous
//
#include <hip/hip_runtime.h>
#include <hip/hip_bf16.h>

typedef __hip_bfloat16 bf16;
using f4 = __attribute__((ext_vector_type(4))) float;
using s8 = __attribute__((ext_vector_type(8))) short;
using s4 = __attribute__((ext_vector_type(4))) short;

__device__ __forceinline__ void storeOut(float* p, float v) { *p = v; }
__device__ __forceinline__ void storeOut(bf16* p, float v) { *p = __float2bfloat16(v); }
__device__ __forceinline__ short bfs(float x) { return __builtin_bit_cast(short, __float2bfloat16(x)); }

constexpr int B_ = 4, T_ = 1024, M_ = 256, C_ = 512, H_ = 8, HD_ = 64, C3_ = 1536;

#define MFMA16(a, b, c) __builtin_amdgcn_mfma_f32_16x16x32_bf16((a), (b), (c), 0, 0, 0)

// ---------------- prep: 5 weight transposes (fp32 KxN -> bf16 NxK) + 2 converts ----------------
__global__ __launch_bounds__(256) void prep_kernel(
    const float* __restrict__ Wqkv_x, const float* __restrict__ Wqkv_y,
    const float* __restrict__ Wgs, const float* __restrict__ Wgc, const float* __restrict__ Wp,
    const float* __restrict__ x, const float* __restrict__ y,
    bf16* __restrict__ WT_x, bf16* __restrict__ WT_y, bf16* __restrict__ WT_gs,
    bf16* __restrict__ WT_gc, bf16* __restrict__ WT_p,
    bf16* __restrict__ x_bf, bf16* __restrict__ y_bf)
{
    __shared__ float Ls[64][65];
    const int tid = threadIdx.x;
    const int bid = blockIdx.x;
    if (bid < 576) {
        const float* W; bf16* WT; int N, t;
        if (bid < 192)      { W = Wqkv_x; WT = WT_x;  N = C3_; t = bid; }
        else if (bid < 384) { W = Wqkv_y; WT = WT_y;  N = C3_; t = bid - 192; }
        else if (bid < 448) { W = Wgs;    WT = WT_gs; N = C_;  t = bid - 384; }
        else if (bid < 512) { W = Wgc;    WT = WT_gc; N = C_;  t = bid - 448; }
        else                { W = Wp;     WT = WT_p;  N = C_;  t = bid - 512; }
        const int K = C_;
        const int tw = N >> 6;
        const int n0 = (t % tw) * 64, k0 = (t / tw) * 64;
        for (int i = tid; i < 1024; i += 256) {
            int kr = i >> 4, ng = i & 15;
            float4 v = *(const float4*)&W[(size_t)(k0 + kr) * N + n0 + ng * 4];
            Ls[ng * 4 + 0][kr] = v.x; Ls[ng * 4 + 1][kr] = v.y;
            Ls[ng * 4 + 2][kr] = v.z; Ls[ng * 4 + 3][kr] = v.w;
        }
        __syncthreads();
        for (int i = tid; i < 512; i += 256) {
            int n = i >> 3, kg = i & 7;
            s8 r;
            #pragma unroll
            for (int j = 0; j < 8; ++j) r[j] = bfs(Ls[n][kg * 8 + j]);
            *(s8*)&WT[(size_t)(n0 + n) * K + k0 + kg * 8] = r;
        }
    } else if (bid < 1600) {
        int i = (bid - 576) * 2048 + tid * 8;
        s8 r;
        #pragma unroll
        for (int j = 0; j < 8; ++j) r[j] = bfs(x[i + j]);
        *(s8*)&x_bf[i] = r;
    } else {
        int i = (bid - 1600) * 2048 + tid * 8;
        s8 r;
        #pragma unroll
        for (int j = 0; j < 8; ++j) r[j] = bfs(y[i + j]);
        *(s8*)&y_bf[i] = r;
    }
}

// ---------------- merged catt1/catt2 + qw (one dispatch) ----------------
__global__ __launch_bounds__(256) void qwcatt_kernel(
    const bf16* __restrict__ qkv_x, const bf16* __restrict__ qkv_y,
    const float* __restrict__ w4x, const float* __restrict__ w4y,
    const float* __restrict__ w4xy,
    float* __restrict__ catt1b, float* __restrict__ catt2b, bf16* __restrict__ qw)
{
    const int bid = blockIdx.x;
    const int tid = threadIdx.x;
    if (bid < 160) {
        int i = bid * 256 + tid;   // 0..40959
        const bf16* row; const float* w; float* out; int oi;
        if (i < 32768) {
            int bh = i >> 10, t = i & 1023, b = bh >> 3, h = bh & 7;
            row = qkv_x + (size_t)(b * T_ + t) * C3_ + h * HD_;
            w = w4x + h * HD_; out = catt1b; oi = i;
        } else {
            int j = i - 32768;
            int bh = j >> 8, m = j & 255, b = bh >> 3, h = bh & 7;
            row = qkv_y + (size_t)(b * M_ + m) * C3_ + h * HD_;
            w = w4y + h * HD_; out = catt2b; oi = j;
        }
        float s = 0.f;
        #pragma unroll
        for (int d = 0; d < HD_; ++d) s = fmaf(__bfloat162float(row[d]), w[d], s);
        out[oi] = s;
    } else {
        int o = ((bid - 160) * 256 + tid) * 8;
        int row = o >> 9, c = o & 511;
        const bf16* src = qkv_x + (size_t)row * C3_ + c;
        s8 r;
        #pragma unroll
        for (int j = 0; j < 8; ++j) r[j] = bfs(__bfloat162float(src[j]) * w4xy[c + j]);
        *(s8*)&qw[o] = r;
    }
}

// ---------------- LDS-staged MFMA GEMM (m-major grid) ----------------
template <typename OT>
__global__ __launch_bounds__(256) void gemm_staged_kernel(
    const bf16* __restrict__ A, const bf16* __restrict__ WT, const float* __restrict__ bias,
    OT* __restrict__ Cmat, int N, int K)
{
    __shared__ short Asb[128][72];
    __shared__ short Bsb[64][72];
    const int tid = threadIdx.x;
    const int wave = tid >> 6, lane = tid & 63;
    const int quad = lane >> 4, l16 = lane & 15;
    const int n0 = blockIdx.y * 64, m0 = blockIdx.x * 128;
    f4 acc[2][4];
    #pragma unroll
    for (int mt = 0; mt < 2; ++mt)
        #pragma unroll
        for (int nt = 0; nt < 4; ++nt) acc[mt][nt] = (f4)0.f;

    for (int k0 = 0; k0 < K; k0 += 64) {
        #pragma unroll
        for (int tl = 0; tl < 4; ++tl) {
            int g = tid + tl * 256, row = g >> 3, grp = g & 7;
            *(s8*)&Asb[row][grp * 8] = *(const s8*)&A[(size_t)(m0 + row) * K + k0 + grp * 8];
        }
        #pragma unroll
        for (int tl = 0; tl < 2; ++tl) {
            int g = tid + tl * 256, n = g >> 3, grp = g & 7;
            *(s8*)&Bsb[n][grp * 8] = *(const s8*)&WT[(size_t)(n0 + n) * K + k0 + grp * 8];
        }
        __syncthreads();
        #pragma unroll
        for (int ks = 0; ks < 2; ++ks) {
            s8 a0 = *(const s8*)&Asb[wave * 32 + l16][ks * 32 + quad * 8];
            s8 a1 = *(const s8*)&Asb[wave * 32 + 16 + l16][ks * 32 + quad * 8];
            #pragma unroll
            for (int nt = 0; nt < 4; ++nt) {
                s8 bv = *(const s8*)&Bsb[nt * 16 + l16][ks * 32 + quad * 8];
                acc[0][nt] = MFMA16(a0, bv, acc[0][nt]);
                acc[1][nt] = MFMA16(a1, bv, acc[1][nt]);
            }
        }
        __syncthreads();
    }
    #pragma unroll
    for (int mt = 0; mt < 2; ++mt)
        #pragma unroll
        for (int nt = 0; nt < 4; ++nt) {
            int col = n0 + nt * 16 + l16;
            float bb = bias[col];
            #pragma unroll
            for (int reg = 0; reg < 4; ++reg) {
                int row = m0 + wave * 32 + mt * 16 + quad * 4 + reg;
                storeOut(&Cmat[(size_t)row * N + col], acc[mt][nt][reg] + bb);
            }
        }
}

// ---------------- catt3r: logits + row softmax -> x2y bf16 + rowsum + col partial sums ----------------
__global__ __launch_bounds__(256) void catt3r_kernel(
    const bf16* __restrict__ qw, const bf16* __restrict__ qkv_y,
    const float* __restrict__ catt1, const float* __restrict__ catt2,
    bf16* __restrict__ x2y, float* __restrict__ rowsum_, float* __restrict__ psum)
{
    __shared__ float redc[4][256];
    const int tid = threadIdx.x;
    const int wave = tid >> 6, lane = tid & 63;
    const int quad = lane >> 4, l16 = lane & 15;
    const int bh = blockIdx.x, b = bh >> 3, h = bh & 7;
    const int t0 = blockIdx.y * 64;
    f4 sc[4][4];
    #pragma unroll
    for (int mt = 0; mt < 4; ++mt)
        #pragma unroll
        for (int nt = 0; nt < 4; ++nt) sc[mt][nt] = (f4)0.f;

    const bf16* ap = qw + (size_t)(b * T_ + t0 + wave * 16 + l16) * C_ + h * HD_ + quad * 8;
    s8 a0 = *(const s8*)ap;
    s8 a1 = *(const s8*)(ap + 32);
    const bf16* bp = qkv_y + (size_t)(b * M_ + l16) * C3_ + C_ + h * HD_ + quad * 8;
    #pragma unroll
    for (int mt = 0; mt < 4; ++mt)
        #pragma unroll
        for (int nt = 0; nt < 4; ++nt) {
            const bf16* bq = bp + (size_t)(mt * 64 + nt * 16) * C3_;
            sc[mt][nt] = MFMA16(a0, *(const s8*)bq, sc[mt][nt]);
            sc[mt][nt] = MFMA16(a1, *(const s8*)(bq + 32), sc[mt][nt]);
        }

    float c1[4];
    #pragma unroll
    for (int reg = 0; reg < 4; ++reg)
        c1[reg] = catt1[bh * T_ + t0 + wave * 16 + quad * 4 + reg];
    #pragma unroll
    for (int mt = 0; mt < 4; ++mt)
        #pragma unroll
        for (int nt = 0; nt < 4; ++nt) {
            float c2 = catt2[bh * M_ + mt * 64 + nt * 16 + l16];
            #pragma unroll
            for (int reg = 0; reg < 4; ++reg)
                sc[mt][nt][reg] = __expf(sc[mt][nt][reg] * 0.125f + c1[reg] + c2);
        }

    #pragma unroll
    for (int reg = 0; reg < 4; ++reg) {
        float rs = 0.f;
        #pragma unroll
        for (int mt = 0; mt < 4; ++mt)
            #pragma unroll
            for (int nt = 0; nt < 4; ++nt) rs += sc[mt][nt][reg];
        rs += __shfl_xor(rs, 1); rs += __shfl_xor(rs, 2);
        rs += __shfl_xor(rs, 4); rs += __shfl_xor(rs, 8);
        const int t = t0 + wave * 16 + quad * 4 + reg;
        if (l16 == 0) rowsum_[bh * T_ + t] = rs;
        const float ri = 1.f / rs;
        #pragma unroll
        for (int mt = 0; mt < 4; ++mt)
            #pragma unroll
            for (int nt = 0; nt < 4; ++nt)
                x2y[((size_t)bh * T_ + t) * M_ + mt * 64 + nt * 16 + l16] =
                    __float2bfloat16(sc[mt][nt][reg] * ri);
    }

    #pragma unroll
    for (int mt = 0; mt < 4; ++mt)
        #pragma unroll
        for (int nt = 0; nt < 4; ++nt) {
            float es = sc[mt][nt][0] + sc[mt][nt][1] + sc[mt][nt][2] + sc[mt][nt][3];
            es += __shfl_xor(es, 16);
            es += __shfl_xor(es, 32);
            if (quad == 0) redc[wave][mt * 64 + nt * 16 + l16] = es;
        }
    __syncthreads();
    psum[((size_t)bh * 16 + blockIdx.y) * M_ + tid] =
        redc[0][tid] + redc[1][tid] + redc[2][tid] + redc[3][tid];
}

// ---------------- merged colfin + V transposes (one dispatch) ----------------
__global__ __launch_bounds__(256) void colfin_vtrans_kernel(
    const float* __restrict__ psum, float* __restrict__ colinv,
    const bf16* __restrict__ qkv_x, const bf16* __restrict__ qkv_y,
    bf16* __restrict__ vTx, bf16* __restrict__ vTy)
{
    __shared__ short Ls[64][68];
    const int tid = threadIdx.x;
    int bid = blockIdx.x;
    if (bid < 32) {
        const int bh = bid, m = tid;
        float s = 0.f;
        #pragma unroll
        for (int ch = 0; ch < 16; ++ch) s += psum[(bh * 16 + ch) * M_ + m];
        colinv[bh * M_ + m] = 1.f / s;
        return;
    }
    bid -= 32;
    const bf16* qkv; bf16* vT; int Nrows, bh, t0;
    if (bid < 512) { qkv = qkv_x; vT = vTx; Nrows = T_; bh = bid >> 4; t0 = (bid & 15) * 64; }
    else { bid -= 512; qkv = qkv_y; vT = vTy; Nrows = M_; bh = bid >> 2; t0 = (bid & 3) * 64; }
    const int b = bh >> 3, h = bh & 7;
    for (int i = tid; i < 4096; i += 256) {
        int tl = i >> 6, d = i & 63;
        Ls[d][tl] = __builtin_bit_cast(short,
            qkv[(size_t)(b * Nrows + t0 + tl) * C3_ + 2 * C_ + h * HD_ + d]);
    }
    __syncthreads();
    for (int i = tid; i < 4096; i += 256) {
        int d = i >> 6, tl = i & 63;
        vT[((size_t)bh * 64 + d) * Nrows + t0 + tl] = __builtin_bit_cast(bf16, Ls[d][tl]);
    }
}

// ---------------- y2xw: y2x = x2y * rowsum * colinv ----------------
__global__ __launch_bounds__(256) void y2xw_kernel(
    const bf16* __restrict__ x2y, const float* __restrict__ rowsum_,
    const float* __restrict__ colinv, bf16* __restrict__ y2x)
{
    const int i = (blockIdx.x * 256 + threadIdx.x) * 8;
    const int row = i >> 8, m = i & 255, bh = row >> 10;
    const float rs = rowsum_[row];
    s8 v = *(const s8*)&x2y[i];
    const float4 c0 = *(const float4*)&colinv[bh * M_ + m];
    const float4 c4 = *(const float4*)&colinv[bh * M_ + m + 4];
    float ci[8] = {c0.x, c0.y, c0.z, c0.w, c4.x, c4.y, c4.z, c4.w};
    s8 r;
    #pragma unroll
    for (int j = 0; j < 8; ++j)
        r[j] = bfs(__bfloat162float(__builtin_bit_cast(bf16, v[j])) * rs * ci[j]);
    *(s8*)&y2x[i] = r;
}

// ---------------- flash8: flash6 structure (single-buffer, 2 barriers/tile — proven
// 53.4-53.7 us across R14-R16) + R18's bf16-only epilogue (WRITE_SIZE win kept) ----------------
__global__ __launch_bounds__(512) void flash8_kernel(
    const bf16* __restrict__ x2y, const bf16* __restrict__ y2x,
    const bf16* __restrict__ vTx, const bf16* __restrict__ vTy,
    const bf16* __restrict__ qkv_x, const float* __restrict__ x,
    bf16* __restrict__ cval_bf, bf16* __restrict__ sval_bf)
{
    __shared__ short Kc[64][264];
    __shared__ short Ksf[64][72];
    __shared__ short Vb[64][72];
    __shared__ short Ps[8][16][68];
    const int tid = threadIdx.x;
    const int wave = tid >> 6, lane = tid & 63;
    const int quad = lane >> 4, l16 = lane & 15;
    const int bh = blockIdx.x, b = bh >> 3, h = bh & 7;
    const int p = blockIdx.y;
    const int jt = (wave < 4) ? p : (15 - p);
    const int rb = jt * 64 + (wave & 3) * 16;
    const int nst = 16 - p;

    s8 qc[8], qs[2];
    {
        const bf16* qp = x2y + (size_t)(bh * T_ + rb + l16) * M_ + quad * 8;
        #pragma unroll
        for (int f = 0; f < 8; ++f) qc[f] = *(const s8*)(qp + f * 32);
        const bf16* qsp = qkv_x + (size_t)(b * T_ + rb + l16) * C3_ + h * HD_ + quad * 8;
        qs[0] = *(const s8*)qsp;
        qs[1] = *(const s8*)(qsp + 32);
    }

    f4 ocv[4];
    #pragma unroll
    for (int dt = 0; dt < 4; ++dt) ocv[dt] = (f4)0.f;
    {
        const bf16* vb = vTy + (size_t)(bh * 64 + l16) * M_ + quad * 8;
        #pragma unroll
        for (int f = 0; f < 8; ++f)
            #pragma unroll
            for (int dt = 0; dt < 4; ++dt) {
                s8 bv = *(const s8*)(vb + (size_t)dt * 16 * M_ + f * 32);
                ocv[dt] = MFMA16(qc[f], bv, ocv[dt]);
            }
    }

    f4 oc[4], os_[4];
    float lc[4] = {0.f, 0.f, 0.f, 0.f}, ls_[4] = {0.f, 0.f, 0.f, 0.f};
    #pragma unroll
    for (int dt = 0; dt < 4; ++dt) { oc[dt] = (f4)0.f; os_[dt] = (f4)0.f; }

    #pragma unroll
    for (int tl = 0; tl < 4; ++tl) {
        int g = tid + tl * 512, row = g >> 5, grp = g & 31;
        *(s8*)&Kc[row][grp * 8] = *(const s8*)&y2x[(size_t)(bh * T_ + row) * M_ + grp * 8];
    }
    {
        int row = tid >> 3, grp = tid & 7;
        *(s8*)&Ksf[row][grp * 8] =
            *(const s8*)&qkv_x[(size_t)(b * T_ + row) * C3_ + C_ + h * HD_ + grp * 8];
        *(s8*)&Vb[row][grp * 8] = *(const s8*)&vTx[(size_t)(bh * 64 + row) * T_ + grp * 8];
    }
    __syncthreads();

    for (int st = 0; st < nst; ++st) {
        const int s0 = st * 64;
        const bool pf = (st + 1) < nst;
        s8 kcp[4], ksp, vp;
        if (pf) {
            const int sn = s0 + 64;
            #pragma unroll
            for (int tl = 0; tl < 4; ++tl) {
                int g = tid + tl * 512, row = g >> 5, grp = g & 31;
                kcp[tl] = *(const s8*)&y2x[(size_t)(bh * T_ + sn + row) * M_ + grp * 8];
            }
            int row = tid >> 3, grp = tid & 7;
            ksp = *(const s8*)&qkv_x[(size_t)(b * T_ + sn + row) * C3_ + C_ + h * HD_ + grp * 8];
            vp = *(const s8*)&vTx[(size_t)(bh * 64 + row) * T_ + sn + grp * 8];
        }
        if (st <= jt) {
            f4 sc[4];
            #pragma unroll
            for (int nt = 0; nt < 4; ++nt) sc[nt] = (f4)0.f;
            #pragma unroll
            for (int f = 0; f < 8; ++f)
                #pragma unroll
                for (int nt = 0; nt < 4; ++nt) {
                    s8 bv = *(const s8*)&Kc[nt * 16 + l16][f * 32 + quad * 8];
                    sc[nt] = MFMA16(qc[f], bv, sc[nt]);
                }
            f4 ss[4];
            #pragma unroll
            for (int nt = 0; nt < 4; ++nt) ss[nt] = (f4)0.f;
            #pragma unroll
            for (int f = 0; f < 2; ++f)
                #pragma unroll
                for (int nt = 0; nt < 4; ++nt) {
                    s8 bv = *(const s8*)&Ksf[nt * 16 + l16][f * 32 + quad * 8];
                    ss[nt] = MFMA16(qs[f], bv, ss[nt]);
                }
            #pragma unroll
            for (int reg = 0; reg < 4; ++reg) {
                const int t_g = rb + quad * 4 + reg;
                #pragma unroll
                for (int nt = 0; nt < 4; ++nt) {
                    float pv = (s0 + nt * 16 + l16 <= t_g) ? __expf(sc[nt][reg] * (1.f / 16.f)) : 0.f;
                    lc[reg] += pv;
                    Ps[wave][quad * 4 + reg][nt * 16 + l16] = bfs(pv);
                }
            }
            #pragma unroll
            for (int ks = 0; ks < 2; ++ks) {
                const short* pp = &Ps[wave][l16][ks * 32 + quad * 8];
                s4 alo = *(const s4*)pp;
                s4 ahi = *(const s4*)(pp + 4);
                s8 a;
                a[0] = alo[0]; a[1] = alo[1]; a[2] = alo[2]; a[3] = alo[3];
                a[4] = ahi[0]; a[5] = ahi[1]; a[6] = ahi[2]; a[7] = ahi[3];
                #pragma unroll
                for (int dt = 0; dt < 4; ++dt) {
                    s8 bv = *(const s8*)&Vb[dt * 16 + l16][ks * 32 + quad * 8];
                    oc[dt] = MFMA16(a, bv, oc[dt]);
                }
            }
            #pragma unroll
            for (int reg = 0; reg < 4; ++reg) {
                const int t_g = rb + quad * 4 + reg;
                #pragma unroll
                for (int nt = 0; nt < 4; ++nt) {
                    float pv = (s0 + nt * 16 + l16 <= t_g) ? __expf(ss[nt][reg] * 0.125f) : 0.f;
                    ls_[reg] += pv;
                    Ps[wave][quad * 4 + reg][nt * 16 + l16] = bfs(pv);
                }
            }
            #pragma unroll
            for (int ks = 0; ks < 2; ++ks) {
                const short* pp = &Ps[wave][l16][ks * 32 + quad * 8];
                s4 alo = *(const s4*)pp;
                s4 ahi = *(const s4*)(pp + 4);
                s8 a;
                a[0] = alo[0]; a[1] = alo[1]; a[2] = alo[2]; a[3] = alo[3];
                a[4] = ahi[0]; a[5] = ahi[1]; a[6] = ahi[2]; a[7] = ahi[3];
                #pragma unroll
                for (int dt = 0; dt < 4; ++dt) {
                    s8 bv = *(const s8*)&Vb[dt * 16 + l16][ks * 32 + quad * 8];
                    os_[dt] = MFMA16(a, bv, os_[dt]);
                }
            }
        }
        __syncthreads();   // all waves done reading Kc/Ksf/Vb
        if (pf) {
            #pragma unroll
            for (int tl = 0; tl < 4; ++tl) {
                int g = tid + tl * 512, row = g >> 5, grp = g & 31;
                *(s8*)&Kc[row][grp * 8] = kcp[tl];
            }
            int row = tid >> 3, grp = tid & 7;
            *(s8*)&Ksf[row][grp * 8] = ksp;
            *(s8*)&Vb[row][grp * 8] = vp;
        }
        __syncthreads();   // new tile visible
    }

    #pragma unroll
    for (int reg = 0; reg < 4; ++reg) {
        float l1 = lc[reg], l2 = ls_[reg];
        l1 += __shfl_xor(l1, 1); l1 += __shfl_xor(l1, 2);
        l1 += __shfl_xor(l1, 4); l1 += __shfl_xor(l1, 8);
        l2 += __shfl_xor(l2, 1); l2 += __shfl_xor(l2, 2);
        l2 += __shfl_xor(l2, 4); l2 += __shfl_xor(l2, 8);
        const float i1 = 1.f / l1, i2 = 1.f / l2;
        const int t = rb + quad * 4 + reg;
        #pragma unroll
        for (int dt = 0; dt < 4; ++dt) {
            size_t idx = (size_t)(b * T_ + t) * C_ + h * HD_ + dt * 16 + l16;
            float cv = ocv[dt][reg] + oc[dt][reg] * i1 + x[idx];
            cval_bf[idx] = __float2bfloat16(cv);
            float sv = os_[dt][reg] * i2;
            sval_bf[idx] = __float2bfloat16(sv);
        }
    }
}

// ---------------- fused dual gate GEMM + sigmoid + combine -> gated bf16 ----------------
__global__ __launch_bounds__(256) void gatefuse_kernel(
    const bf16* __restrict__ svalb, const bf16* __restrict__ cvalb,
    const bf16* __restrict__ WTgs, const bf16* __restrict__ WTgc,
    const float* __restrict__ bgs, const float* __restrict__ bgc,
    bf16* __restrict__ gated)
{
    __shared__ short Sb[128][72], Cb[128][72], W1b[64][72], W2b[64][72];
    const int tid = threadIdx.x;
    const int wave = tid >> 6, lane = tid & 63;
    const int quad = lane >> 4, l16 = lane & 15;
    const int n0 = blockIdx.y * 64, m0 = blockIdx.x * 128;
    f4 aS[2][4], aC[2][4];
    #pragma unroll
    for (int mt = 0; mt < 2; ++mt)
        #pragma unroll
        for (int nt = 0; nt < 4; ++nt) { aS[mt][nt] = (f4)0.f; aC[mt][nt] = (f4)0.f; }

    for (int k0 = 0; k0 < C_; k0 += 64) {
        #pragma unroll
        for (int tl = 0; tl < 4; ++tl) {
            int g = tid + tl * 256, row = g >> 3, grp = g & 7;
            *(s8*)&Sb[row][grp * 8] = *(const s8*)&svalb[(size_t)(m0 + row) * C_ + k0 + grp * 8];
            *(s8*)&Cb[row][grp * 8] = *(const s8*)&cvalb[(size_t)(m0 + row) * C_ + k0 + grp * 8];
        }
        #pragma unroll
        for (int tl = 0; tl < 2; ++tl) {
            int g = tid + tl * 256, n = g >> 3, grp = g & 7;
            *(s8*)&W1b[n][grp * 8] = *(const s8*)&WTgs[(size_t)(n0 + n) * C_ + k0 + grp * 8];
            *(s8*)&W2b[n][grp * 8] = *(const s8*)&WTgc[(size_t)(n0 + n) * C_ + k0 + grp * 8];
        }
        __syncthreads();
        #pragma unroll
        for (int ks = 0; ks < 2; ++ks) {
            s8 s0f = *(const s8*)&Sb[wave * 32 + l16][ks * 32 + quad * 8];
            s8 s1f = *(const s8*)&Sb[wave * 32 + 16 + l16][ks * 32 + quad * 8];
            s8 c0f = *(const s8*)&Cb[wave * 32 + l16][ks * 32 + quad * 8];
            s8 c1f = *(const s8*)&Cb[wave * 32 + 16 + l16][ks * 32 + quad * 8];
            #pragma unroll
            for (int nt = 0; nt < 4; ++nt) {
                s8 w1 = *(const s8*)&W1b[nt * 16 + l16][ks * 32 + quad * 8];
                s8 w2 = *(const s8*)&W2b[nt * 16 + l16][ks * 32 + quad * 8];
                aS[0][nt] = MFMA16(s0f, w1, aS[0][nt]);
                aS[1][nt] = MFMA16(s1f, w1, aS[1][nt]);
                aC[0][nt] = MFMA16(c0f, w2, aC[0][nt]);
                aC[1][nt] = MFMA16(c1f, w2, aC[1][nt]);
            }
        }
        __syncthreads();
    }
    #pragma unroll
    for (int mt = 0; mt < 2; ++mt)
        #pragma unroll
        for (int nt = 0; nt < 4; ++nt) {
            int col = n0 + nt * 16 + l16;
            float b1 = bgs[col], b2 = bgc[col];
            #pragma unroll
            for (int reg = 0; reg < 4; ++reg) {
                int row = m0 + wave * 32 + mt * 16 + quad * 4 + reg;
                size_t idx = (size_t)row * C_ + col;
                float gs = 1.f / (1.f + __expf(-(aS[mt][nt][reg] + b1)));
                float gc = 1.f / (1.f + __expf(-(aC[mt][nt][reg] + b2)));
                float cvv = __bfloat162float(cvalb[idx]);
                float svv = __bfloat162float(svalb[idx]);
                gated[idx] = __float2bfloat16(gs * cvv + gc * svv);
            }
        }
}

extern "C" void kernel_launch(void* const* d_in, const int* in_sizes, int n_in,
                              void* d_out, int out_size, void* d_ws, size_t ws_size,
                              hipStream_t stream)
{
    const float* x      = (const float*)d_in[0];
    const float* y      = (const float*)d_in[1];
    // d_in[2]: attn_x_mask — structurally causal tril, computed inline
    const float* Wqkv_x = (const float*)d_in[3];
    const float* bqkv_x = (const float*)d_in[4];
    const float* Wqkv_y = (const float*)d_in[5];
    const float* bqkv_y = (const float*)d_in[6];
    const float* w4x    = (const float*)d_in[7];
    const float* w4y    = (const float*)d_in[8];
    const float* w4xy   = (const float*)d_in[9];
    const float* Wgs    = (const float*)d_in[10];
    const float* bgs    = (const float*)d_in[11];
    const float* Wgc    = (const float*)d_in[12];
    const float* bgc    = (const float*)d_in[13];
    const float* Wp     = (const float*)d_in[14];
    const float* bp     = (const float*)d_in[15];

    // Workspace (f-word offsets; proven layout)
    float* ws = (float*)d_ws;
    bf16*  qkv_x_bf = (bf16*)(ws + 0);           // 6,291,456 bf16
    bf16*  qkv_y_bf = (bf16*)(ws + 3145728);     // 1,572,864 bf16
    bf16*  gated_bf = (bf16*)(ws + 3932160);
    bf16*  cval_bf  = (bf16*)(ws + 5242880);
    bf16*  x2y_bf   = (bf16*)(ws + 12320768);    // 8,388,608 bf16 (written by catt3r)
    bf16*  x_bf     = x2y_bf;                    //   pre-QKV reuse
    bf16*  y_bf     = (bf16*)(ws + 13369344);    //   pre-QKV reuse
    bf16*  y2x_bf   = (bf16*)(ws + 16515072);    // 8,388,608 bf16 (written by y2xw)
    bf16*  vTx_bf   = (bf16*)(ws + 20709376);    // 2,097,152 bf16
    bf16*  vTy_bf   = (bf16*)(ws + 21757952);    // 524,288 bf16
    float* psum_    = ws + 22020096;             // 131,072 f
    bf16*  qw_bf    = (bf16*)(ws + 26214400);    // 2,097,152 bf16 (dead after catt3r)
    bf16*  sval_bf  = qw_bf;                     //   reuse
    bf16*  WT_x     = (bf16*)(ws + 27262976);    // 786,432 bf16
    bf16*  WT_y     = (bf16*)(ws + 27656192);
    bf16*  WT_gs    = (bf16*)(ws + 28049408);    // 262,144 bf16
    bf16*  WT_gc    = (bf16*)(ws + 28180480);
    bf16*  WT_p     = (bf16*)(ws + 28311552);
    float* catt1b   = ws + 28442624;             // 32,768 f
    float* catt2b   = ws + 28475392;             //  8,192 f
    float* colinv   = ws + 28483584;             //  8,192 f
    float* rowsum_  = ws + 28491776;             // 32,768 f

    // 0: one prep dispatch
    prep_kernel<<<1856, 256, 0, stream>>>(
        Wqkv_x, Wqkv_y, Wgs, Wgc, Wp, x, y,
        WT_x, WT_y, WT_gs, WT_gc, WT_p, x_bf, y_bf);

    // 1-2: QKV projections
    gemm_staged_kernel<bf16><<<dim3(32, 24), 256, 0, stream>>>(x_bf, WT_x, bqkv_x, qkv_x_bf, C3_, C_);
    gemm_staged_kernel<bf16><<<dim3(8, 24), 256, 0, stream>>>(y_bf, WT_y, bqkv_y, qkv_y_bf, C3_, C_);

    // 3: catt1/catt2/qw
    qwcatt_kernel<<<1184, 256, 0, stream>>>(
        qkv_x_bf, qkv_y_bf, w4x, w4y, w4xy, catt1b, catt2b, qw_bf);

    // 4: fused logits + row softmax -> x2y + rowsum + col partials
    catt3r_kernel<<<dim3(32, 16), 256, 0, stream>>>(
        qw_bf, qkv_y_bf, catt1b, catt2b, x2y_bf, rowsum_, psum_);

    // 5: colfin + V transposes
    colfin_vtrans_kernel<<<672, 256, 0, stream>>>(psum_, colinv, qkv_x_bf, qkv_y_bf, vTx_bf, vTy_bf);

    // 6: y2x = x2y * rowsum * colinv
    y2xw_kernel<<<4096, 256, 0, stream>>>(x2y_bf, rowsum_, colinv, y2x_bf);

    // 7: paired-tile flash (proven flash6 structure, bf16-only outputs)
    flash8_kernel<<<dim3(32, 8), 512, 0, stream>>>(
        x2y_bf, y2x_bf, vTx_bf, vTy_bf, qkv_x_bf, x, cval_bf, sval_bf);

    // 8: fused gates (bf16 elementwise)
    gatefuse_kernel<<<dim3(32, 8), 256, 0, stream>>>(
        sval_bf, cval_bf, WT_gs, WT_gc, bgs, bgc, gated_bf);

    // 9: out = gated @ Wp + bp
    gemm_staged_kernel<float><<<dim3(32, 8), 256, 0, stream>>>(
        gated_bf, WT_p, bp, (float*)d_out, C_, C_);
}